// Round 4
// baseline (950.073 us; speedup 1.0000x reference)
//
#include <hip/hip_runtime.h>

typedef unsigned int u32;

// =============== binned CSR build (counting sort by dst) ===============
// bucket = dst >> 6 (64 nodes/bucket). NB = ceil(N/64) <= 1024 (N <= 65536).

__global__ __launch_bounds__(256) void hist_k(const int* __restrict__ dst, int* __restrict__ bcount,
                                              int E, int N, int NB){
  __shared__ int h[1024];
  for(int i=threadIdx.x; i<1024; i+=256) h[i]=0;
  __syncthreads();
  int e0 = blockIdx.x*4096;
  int e1 = min(e0+4096, E);
  for(int i=e0+threadIdx.x; i<e1; i+=256){
    int d = dst[i];
    if((u32)d >= (u32)N) d = 0;
    atomicAdd(&h[d>>6], 1);
  }
  __syncthreads();
  for(int i=threadIdx.x; i<NB; i+=256){
    int v = h[i];
    if(v) atomicAdd(&bcount[i], v);
  }
}

// single block: exclusive scan of bcount[NB] -> bstart, zero bcursor, offs[N]=E
__global__ __launch_bounds__(256) void bucket_scan(const int* __restrict__ bcount, int* __restrict__ bstart,
                                                   int* __restrict__ bcursor, int* __restrict__ offs,
                                                   int NB, int N, int E){
  __shared__ int tsum[256];
  int t = threadIdx.x;
  int base = t*4;
  int a0 = (base+0<NB)?bcount[base+0]:0;
  int a1 = (base+1<NB)?bcount[base+1]:0;
  int a2 = (base+2<NB)?bcount[base+2]:0;
  int a3 = (base+3<NB)?bcount[base+3]:0;
  int s0=a0, s1=s0+a1, s2=s1+a2, s3=s2+a3;
  tsum[t]=s3; __syncthreads();
  #pragma unroll
  for(int d=1; d<256; d<<=1){
    int v = (t>=d)?tsum[t-d]:0;
    __syncthreads();
    tsum[t]+=v;
    __syncthreads();
  }
  int prev = (t>0)?tsum[t-1]:0;
  if(base+0<NB){ bstart[base+0]=prev;    bcursor[base+0]=0; }
  if(base+1<NB){ bstart[base+1]=prev+s0; bcursor[base+1]=0; }
  if(base+2<NB){ bstart[base+2]=prev+s1; bcursor[base+2]=0; }
  if(base+3<NB){ bstart[base+3]=prev+s2; bcursor[base+3]=0; }
  if(t==255){ bstart[NB]=prev+s3; offs[N]=E; }
}

// scatter packed (src | (dst&63)<<17) into bucket regions (bump-allocated -> line-local writes)
__global__ __launch_bounds__(256) void binscatter(const int* __restrict__ src, const int* __restrict__ dst,
                                                  const int* __restrict__ bstart, int* __restrict__ bcursor,
                                                  u32* __restrict__ pairs, int E, int N){
  int e = blockIdx.x*256 + threadIdx.x;
  if(e >= E) return;
  int d = dst[e]; if((u32)d >= (u32)N) d = 0;
  int s = src[e]; if((u32)s >= (u32)N) s = 0;
  int b = d>>6;
  int p = atomicAdd(&bcursor[b], 1);
  pairs[bstart[b]+p] = (u32)s | (((u32)(d & 63))<<17);
}

// per-bucket: count 64 node degrees in LDS, serial scan, write offs, scatter src into elist (L2-hot)
__global__ __launch_bounds__(256) void bucket_csr(const u32* __restrict__ pairs, const int* __restrict__ bstart,
                                                  int* __restrict__ offs, int* __restrict__ elist, int N){
  __shared__ int dcnt[64];
  __shared__ int dcur[64];
  int b = blockIdx.x;
  int p0 = bstart[b], p1 = bstart[b+1];
  if(threadIdx.x < 64) dcnt[threadIdx.x] = 0;
  __syncthreads();
  for(int i=p0+threadIdx.x; i<p1; i+=256){
    u32 u = pairs[i];
    atomicAdd(&dcnt[u>>17], 1);
  }
  __syncthreads();
  if(threadIdx.x == 0){
    int running = p0;
    #pragma unroll
    for(int j=0;j<64;j++){
      dcur[j] = running;
      int node = b*64 + j;
      if(node < N) offs[node] = running;
      running += dcnt[j];
    }
  }
  __syncthreads();
  for(int i=p0+threadIdx.x; i<p1; i+=256){
    u32 u = pairs[i];
    int pos = atomicAdd(&dcur[u>>17], 1);
    elist[pos] = (int)(u & 0x1FFFFu);
  }
}

// h0[i] = x[i] + sum_{j->i} x[j]   (fp32). 32 lanes per 128-wide node row.
__global__ __launch_bounds__(256) void gather_sum(const float* __restrict__ x, const int* __restrict__ offs,
                                                  const int* __restrict__ elist, float* __restrict__ h0,
                                                  int N, int E){
  int slot = threadIdx.x >> 5;
  int c = threadIdx.x & 31;
  int i = blockIdx.x*8 + slot;
  if(i >= N) return;
  const float4* xr = (const float4*)x;
  float4 acc = xr[(size_t)i*32 + c];
  int e0 = offs[i], e1 = offs[i+1];
  e0 = max(0, min(e0, E));
  e1 = max(e0, min(e1, E));
  for(int j=e0; j<e1; j++){
    int s = elist[j];
    if((u32)s >= (u32)N) s = 0;
    float4 v = xr[(size_t)s*32 + c];
    acc.x += v.x; acc.y += v.y; acc.z += v.z; acc.w += v.w;
  }
  ((float4*)h0)[(size_t)i*32 + c] = acc;
}

// =============== fp32 tiled GEMM: C[M,256] = op(A[M,K]) @ B[K,256] + bias ===============
// tile 64x256, 256 threads, 8x8 micro-tile. Optional fused BN+ReLU on A, ReLU on out,
// and fused gate = (C_row . Wg) + bg written per row.
template<int K, bool BNA, bool RELUOUT, bool GATE>
__global__ __launch_bounds__(256) void gemm_k(const float* __restrict__ A, const float* __restrict__ B,
                                              const float* __restrict__ bias,
                                              const float* __restrict__ scale, const float* __restrict__ shift,
                                              float* __restrict__ C, int M,
                                              const float* __restrict__ Wg, const float* __restrict__ bg,
                                              float* __restrict__ gate){
  __shared__ float As[16][64];
  __shared__ float Bs[16][256];
  const int tid = threadIdx.x;
  const int tn = tid & 31, tm = tid >> 5;
  const int m0 = blockIdx.x * 64;
  float acc[8][8];
  #pragma unroll
  for(int i=0;i<8;i++){
    #pragma unroll
    for(int j=0;j<8;j++) acc[i][j]=0.f;
  }
  const int arow = tid >> 2;          // 0..63
  const int akk  = (tid & 3)*4;       // 0,4,8,12
  const int brow = tid >> 6;          // 0..3
  const int bn4  = (tid & 63)*4;      // 0..252

  for(int k0=0; k0<K; k0+=16){
    float4 a4 = make_float4(0.f,0.f,0.f,0.f);
    if(m0 + arow < M) a4 = *(const float4*)(A + (size_t)(m0+arow)*K + k0 + akk);
    if(BNA){
      float4 s4 = *(const float4*)(scale + k0 + akk);
      float4 t4 = *(const float4*)(shift + k0 + akk);
      a4.x = fmaxf(fmaf(s4.x, a4.x, t4.x), 0.f);
      a4.y = fmaxf(fmaf(s4.y, a4.y, t4.y), 0.f);
      a4.z = fmaxf(fmaf(s4.z, a4.z, t4.z), 0.f);
      a4.w = fmaxf(fmaf(s4.w, a4.w, t4.w), 0.f);
    }
    As[akk+0][arow]=a4.x; As[akk+1][arow]=a4.y; As[akk+2][arow]=a4.z; As[akk+3][arow]=a4.w;
    #pragma unroll
    for(int p=0;p<4;p++){
      int kr = brow + p*4;
      *(float4*)&Bs[kr][bn4] = *(const float4*)(B + (size_t)(k0+kr)*256 + bn4);
    }
    __syncthreads();
    #pragma unroll
    for(int k=0;k<16;k++){
      float4 a0 = *(const float4*)&As[k][tm*4];
      float4 a1 = *(const float4*)&As[k][32 + tm*4];
      float4 b0 = *(const float4*)&Bs[k][tn*4];
      float4 b1 = *(const float4*)&Bs[k][128 + tn*4];
      float ar[8] = {a0.x,a0.y,a0.z,a0.w,a1.x,a1.y,a1.z,a1.w};
      float br[8] = {b0.x,b0.y,b0.z,b0.w,b1.x,b1.y,b1.z,b1.w};
      #pragma unroll
      for(int i=0;i<8;i++){
        #pragma unroll
        for(int j=0;j<8;j++) acc[i][j] = fmaf(ar[i], br[j], acc[i][j]);
      }
    }
    __syncthreads();
  }
  float bb[8];
  {
    float4 t0 = *(const float4*)(bias + tn*4);
    float4 t1 = *(const float4*)(bias + 128 + tn*4);
    bb[0]=t0.x; bb[1]=t0.y; bb[2]=t0.z; bb[3]=t0.w;
    bb[4]=t1.x; bb[5]=t1.y; bb[6]=t1.z; bb[7]=t1.w;
  }
  float wg[8];
  float bg0 = 0.f;
  if(GATE){
    float4 w0 = *(const float4*)(Wg + tn*4);
    float4 w1 = *(const float4*)(Wg + 128 + tn*4);
    wg[0]=w0.x; wg[1]=w0.y; wg[2]=w0.z; wg[3]=w0.w;
    wg[4]=w1.x; wg[5]=w1.y; wg[6]=w1.z; wg[7]=w1.w;
    bg0 = bg[0];
  }
  #pragma unroll
  for(int i=0;i<8;i++){
    int row = m0 + ((i<4) ? (tm*4+i) : (32 + tm*4 + (i-4)));
    if(row < M){
      float o[8];
      #pragma unroll
      for(int j=0;j<8;j++){
        o[j] = acc[i][j] + bb[j];
        if(RELUOUT) o[j] = fmaxf(o[j], 0.f);
      }
      float4 o0 = make_float4(o[0],o[1],o[2],o[3]);
      float4 o1 = make_float4(o[4],o[5],o[6],o[7]);
      *(float4*)(C + (size_t)row*256 + tn*4)       = o0;
      *(float4*)(C + (size_t)row*256 + 128 + tn*4) = o1;
      if(GATE){
        float p = 0.f;
        #pragma unroll
        for(int j=0;j<8;j++) p = fmaf(o[j], wg[j], p);
        #pragma unroll
        for(int d=16; d>0; d>>=1) p += __shfl_down(p, d, 32);
        if(tn==0) gate[row] = p + bg0;
      }
    }
  }
}

// =============== BN column stats (atomic partials) ===============
__global__ __launch_bounds__(256) void col_stats(const float* __restrict__ h, float* __restrict__ sums,
                                                 int M, int rowsPerBlock){
  int t = threadIdx.x;
  int r0 = blockIdx.x * rowsPerBlock;
  int r1 = min(r0 + rowsPerBlock, M);
  float s=0.f, q=0.f;
  for(int r=r0; r<r1; r++){
    float v = h[(size_t)r*256 + t];
    s += v; q = fmaf(v, v, q);
  }
  atomicAdd(&sums[t], s);
  atomicAdd(&sums[256+t], q);
}

__global__ void bn_fin(const float* __restrict__ sums, const float* __restrict__ gamma,
                       const float* __restrict__ beta, float* __restrict__ scale,
                       float* __restrict__ shift, float invM){
  int t = threadIdx.x;
  float mu  = sums[t]*invM;
  float var = fmaxf(sums[256+t]*invM - mu*mu, 0.f);
  float sc  = gamma[t] * rsqrtf(var + 1e-5f);
  scale[t] = sc;
  shift[t] = fmaf(-mu, sc, beta[t]);
}

// =============== attentional pool: one block per graph (batch sorted) ===============
__global__ __launch_bounds__(256) void pool_k(const float* __restrict__ h2, const float* __restrict__ gate,
                                              const int* __restrict__ batch, float* __restrict__ pooled, int N){
  int g = blockIdx.x;
  __shared__ int sb[2];
  __shared__ float red[4];
  __shared__ float s_m, s_inv;
  if(threadIdx.x < 2){
    int target = g + threadIdx.x;
    int lo=0, hi=N;
    while(lo<hi){ int mid=(lo+hi)>>1; if(batch[mid] < target) lo=mid+1; else hi=mid; }
    sb[threadIdx.x] = lo;
  }
  __syncthreads();
  int beg = sb[0], end = sb[1];
  float mx = -1e30f;
  for(int i=beg+threadIdx.x; i<end; i+=256) mx = fmaxf(mx, gate[i]);
  #pragma unroll
  for(int d=32; d>0; d>>=1) mx = fmaxf(mx, __shfl_down(mx, d, 64));
  if((threadIdx.x&63)==0) red[threadIdx.x>>6] = mx;
  __syncthreads();
  if(threadIdx.x==0) s_m = fmaxf(fmaxf(red[0],red[1]), fmaxf(red[2],red[3]));
  __syncthreads();
  float m = s_m;
  float s = 0.f;
  for(int i=beg+threadIdx.x; i<end; i+=256) s += expf(gate[i]-m);
  #pragma unroll
  for(int d=32; d>0; d>>=1) s += __shfl_down(s, d, 64);
  if((threadIdx.x&63)==0) red[threadIdx.x>>6] = s;
  __syncthreads();
  if(threadIdx.x==0){
    float tot = red[0]+red[1]+red[2]+red[3];
    s_inv = (tot > 0.f) ? 1.f/tot : 0.f;
  }
  __syncthreads();
  float inv = s_inv;
  int t = threadIdx.x;
  float acc = 0.f;
  for(int i=beg; i<end; i++){
    float a = expf(gate[i]-m) * inv;
    acc = fmaf(a, h2[(size_t)i*256 + t], acc);
  }
  pooled[g*256 + t] = acc;
}

// =============== head linear + log_softmax: one wave per graph ===============
__global__ __launch_bounds__(256) void head_k(const float* __restrict__ pooled,
                                              const float* __restrict__ sc2, const float* __restrict__ sh2,
                                              const float* __restrict__ Wh, const float* __restrict__ bh,
                                              float* __restrict__ out, int G){
  int w = (blockIdx.x*256 + threadIdx.x) >> 6;
  int l = threadIdx.x & 63;
  if(w >= G) return;
  float4 v  = *(const float4*)(pooled + (size_t)w*256 + l*4);
  float4 sc = *(const float4*)(sc2 + l*4);
  float4 sh = *(const float4*)(sh2 + l*4);
  float vv[4] = { fmaf(sc.x,v.x,sh.x), fmaf(sc.y,v.y,sh.y), fmaf(sc.z,v.z,sh.z), fmaf(sc.w,v.w,sh.w) };
  float4 w0 = *(const float4*)(Wh + (size_t)l*8);
  float4 w1 = *(const float4*)(Wh + (size_t)l*8 + 4);
  float a0 = vv[0]*w0.x + vv[1]*w0.z + vv[2]*w1.x + vv[3]*w1.z;
  float a1 = vv[0]*w0.y + vv[1]*w0.w + vv[2]*w1.y + vv[3]*w1.w;
  #pragma unroll
  for(int d=32; d>0; d>>=1){ a0 += __shfl_down(a0,d,64); a1 += __shfl_down(a1,d,64); }
  if(l==0){
    float z0 = a0 + bh[0];
    float z1 = a1 + bh[1];
    float mz = fmaxf(z0,z1);
    float lse = mz + logf(expf(z0-mz) + expf(z1-mz));
    out[w*2]   = z0 - lse;
    out[w*2+1] = z1 - lse;
  }
}

extern "C" void kernel_launch(void* const* d_in, const int* in_sizes, int n_in,
                              void* d_out, int out_size, void* d_ws, size_t ws_size,
                              hipStream_t stream){
  const float* x   = (const float*)d_in[0];
  const int*   ei  = (const int*)d_in[1];
  const int*   bat = (const int*)d_in[2];
  const float* W1  = (const float*)d_in[3];
  const float* b1  = (const float*)d_in[4];
  const float* g1  = (const float*)d_in[5];
  const float* be1 = (const float*)d_in[6];
  const float* W2  = (const float*)d_in[7];
  const float* b2  = (const float*)d_in[8];
  const float* Wg  = (const float*)d_in[9];
  const float* bg  = (const float*)d_in[10];
  const float* g2  = (const float*)d_in[11];
  const float* be2 = (const float*)d_in[12];
  const float* Wh  = (const float*)d_in[13];
  const float* bh  = (const float*)d_in[14];

  const int N = in_sizes[0] / 128;   // 50000
  const int E = in_sizes[1] / 2;     // 1600000
  const int G = out_size / 2;        // 512
  const int NB = (N + 63) >> 6;      // 782 buckets

  // ---- workspace layout (~103 MB) ----
  // region A [0, 51.2MB): phase1 {h0 25.6MB, elist 6.4MB, pairs 6.4MB, offs, bins}
  //                       phase2 {h2 51.2MB} (phase-1 data dead by then)
  char* ws = (char*)d_ws;
  float* h0     = (float*)ws;                        // 25,600,000 B
  int*   elist  = (int*)(ws + 25600000);             //  6,400,000 B
  u32*   pairs  = (u32*)(ws + 32000000);             //  6,400,000 B
  int*   offs   = (int*)(ws + 38400000);             //    200,004 B
  int*   bcount = (int*)(ws + 38600192);             //      4,096 B
  int*   bstart = (int*)(ws + 38604288);             //      4,100 B
  int*   bcursor= (int*)(ws + 38608640);             //      4,096 B
  float* h2     = (float*)ws;                        // 51,200,000 B (phase2)
  float* h1     = (float*)(ws + 51200000);           // 51,200,000 B
  char*  p2 = ws + 102400000;
  float* sums1 = (float*)p2;          p2 += 2048;
  float* sums2 = (float*)p2;          p2 += 2048;
  float* sc1   = (float*)p2;          p2 += 1024;
  float* sh1   = (float*)p2;          p2 += 1024;
  float* gate  = (float*)p2;          p2 += (size_t)N*4 + 256;
  float* pooled= (float*)p2;          p2 += (size_t)G*256*4;
  float* sc2   = (float*)p2;          p2 += 1024;
  float* sh2   = (float*)p2;          p2 += 1024;

  const int* src = ei;
  const int* dst = ei + E;

  hipMemsetAsync(bcount, 0, (size_t)NB*4, stream);
  hipMemsetAsync(sums1, 0, 512*4, stream);
  hipMemsetAsync(sums2, 0, 512*4, stream);

  // CSR build via binned counting sort
  hist_k     <<<(E+4095)/4096, 256, 0, stream>>>(dst, bcount, E, N, NB);
  bucket_scan<<<1, 256, 0, stream>>>(bcount, bstart, bcursor, offs, NB, N, E);
  binscatter <<<(E+255)/256, 256, 0, stream>>>(src, dst, bstart, bcursor, pairs, E, N);
  bucket_csr <<<NB, 256, 0, stream>>>(pairs, bstart, offs, elist, N);
  gather_sum <<<(N+7)/8, 256, 0, stream>>>(x, offs, elist, h0, N, E);

  // MLP: gemm1 -> BN stats -> gemm2 (fused BN+ReLU on input, ReLU + gate on output)
  gemm_k<128,false,false,false><<<(N+63)/64, 256, 0, stream>>>(h0, W1, b1, nullptr, nullptr, h1, N, nullptr, nullptr, nullptr);
  col_stats  <<<100, 256, 0, stream>>>(h1, sums1, N, (N+99)/100);
  bn_fin     <<<1, 256, 0, stream>>>(sums1, g1, be1, sc1, sh1, 1.0f/(float)N);
  gemm_k<256,true,true,true><<<(N+63)/64, 256, 0, stream>>>(h1, W2, b2, sc1, sh1, h2, N, Wg, bg, gate);

  // pooling + head
  pool_k <<<G, 256, 0, stream>>>(h2, gate, bat, pooled, N);
  col_stats <<<(G+15)/16, 256, 0, stream>>>(pooled, sums2, G, 16);
  bn_fin    <<<1, 256, 0, stream>>>(sums2, g2, be2, sc2, sh2, 1.0f/(float)G);
  head_k <<<(G+3)/4, 256, 0, stream>>>(pooled, sc2, sh2, Wh, bh, (float*)d_out, G);
}

// Round 5
// 600.216 us; speedup vs baseline: 1.5829x; 1.5829x over previous
//
#include <hip/hip_runtime.h>

typedef unsigned int u32;

// =============== binned CSR build (counting sort by dst) ===============
// bucket = dst >> 6 (64 nodes/bucket). NB = ceil(N/64) <= 1024.

__global__ __launch_bounds__(256) void hist_k(const int* __restrict__ dst, int* __restrict__ bcount,
                                              int E, int N, int NB){
  __shared__ int h[1024];
  for(int i=threadIdx.x; i<1024; i+=256) h[i]=0;
  __syncthreads();
  int e0 = blockIdx.x*8192;
  int e1 = min(e0+8192, E);
  for(int i=e0+threadIdx.x; i<e1; i+=256){
    int d = dst[i];
    if((u32)d >= (u32)N) d = 0;
    atomicAdd(&h[d>>6], 1);
  }
  __syncthreads();
  for(int i=threadIdx.x; i<NB; i+=256){
    int v = h[i];
    if(v) atomicAdd(&bcount[i], v);
  }
}

// single block: exclusive scan of bcount[NB] -> bstart, zero padded bcursor, offs[N]=E
__global__ __launch_bounds__(256) void bucket_scan(const int* __restrict__ bcount, int* __restrict__ bstart,
                                                   int* __restrict__ bcursor, int* __restrict__ offs,
                                                   int NB, int N, int E){
  __shared__ int tsum[256];
  int t = threadIdx.x;
  int base = t*4;
  int a0 = (base+0<NB)?bcount[base+0]:0;
  int a1 = (base+1<NB)?bcount[base+1]:0;
  int a2 = (base+2<NB)?bcount[base+2]:0;
  int a3 = (base+3<NB)?bcount[base+3]:0;
  int s0=a0, s1=s0+a1, s2=s1+a2, s3=s2+a3;
  tsum[t]=s3; __syncthreads();
  #pragma unroll
  for(int d=1; d<256; d<<=1){
    int v = (t>=d)?tsum[t-d]:0;
    __syncthreads();
    tsum[t]+=v;
    __syncthreads();
  }
  int prev = (t>0)?tsum[t-1]:0;
  if(base+0<NB){ bstart[base+0]=prev;    bcursor[(base+0)*16]=0; }
  if(base+1<NB){ bstart[base+1]=prev+s0; bcursor[(base+1)*16]=0; }
  if(base+2<NB){ bstart[base+2]=prev+s1; bcursor[(base+2)*16]=0; }
  if(base+3<NB){ bstart[base+3]=prev+s2; bcursor[(base+3)*16]=0; }
  if(t==255){ bstart[NB]=prev+s3; offs[N]=E; }
}

// block-aggregated two-pass binning: LDS hist -> 1 reservation atomic per (block,bucket)
// (bcursor padded 64B/counter) -> LDS-cursor scatter. Writes per (block,bucket) contiguous.
__global__ __launch_bounds__(256) void binscatter2(const int* __restrict__ src, const int* __restrict__ dst,
                                                   const int* __restrict__ bstart, int* __restrict__ bcursor,
                                                   u32* __restrict__ pairs, int E, int N, int NB){
  __shared__ int hist[1024];
  __shared__ int base[1024];
  int e0 = blockIdx.x*8192;
  int e1 = min(e0+8192, E);
  for(int i=threadIdx.x; i<NB; i+=256) hist[i]=0;
  __syncthreads();
  for(int i=e0+threadIdx.x; i<e1; i+=256){
    int d = dst[i];
    if((u32)d >= (u32)N) d = 0;
    atomicAdd(&hist[d>>6], 1);
  }
  __syncthreads();
  for(int i=threadIdx.x; i<NB; i+=256){
    int c = hist[i];
    base[i] = c ? (bstart[i] + atomicAdd(&bcursor[i*16], c)) : 0;
    hist[i] = 0;                       // reuse as local cursor
  }
  __syncthreads();
  for(int i=e0+threadIdx.x; i<e1; i+=256){
    int d = dst[i]; if((u32)d >= (u32)N) d = 0;
    int s = src[i]; if((u32)s >= (u32)N) s = 0;
    int b = d>>6;
    int loc = atomicAdd(&hist[b], 1);
    pairs[base[b]+loc] = (u32)s | (((u32)(d & 63))<<17);
  }
}

// per-bucket: count 64 node degrees in LDS, serial scan, write offs, scatter src into elist (L2-hot)
__global__ __launch_bounds__(256) void bucket_csr(const u32* __restrict__ pairs, const int* __restrict__ bstart,
                                                  int* __restrict__ offs, int* __restrict__ elist, int N){
  __shared__ int dcnt[64];
  __shared__ int dcur[64];
  int b = blockIdx.x;
  int p0 = bstart[b], p1 = bstart[b+1];
  if(threadIdx.x < 64) dcnt[threadIdx.x] = 0;
  __syncthreads();
  for(int i=p0+threadIdx.x; i<p1; i+=256){
    u32 u = pairs[i];
    atomicAdd(&dcnt[u>>17], 1);
  }
  __syncthreads();
  if(threadIdx.x == 0){
    int running = p0;
    #pragma unroll
    for(int j=0;j<64;j++){
      dcur[j] = running;
      int node = b*64 + j;
      if(node < N) offs[node] = running;
      running += dcnt[j];
    }
  }
  __syncthreads();
  for(int i=p0+threadIdx.x; i<p1; i+=256){
    u32 u = pairs[i];
    int pos = atomicAdd(&dcur[u>>17], 1);
    elist[pos] = (int)(u & 0x1FFFFu);
  }
}

// h0[i] = x[i] + sum_{j->i} x[j]   (fp32). 32 lanes per 128-wide node row.
__global__ __launch_bounds__(256) void gather_sum(const float* __restrict__ x, const int* __restrict__ offs,
                                                  const int* __restrict__ elist, float* __restrict__ h0,
                                                  int N, int E){
  int slot = threadIdx.x >> 5;
  int c = threadIdx.x & 31;
  int i = blockIdx.x*8 + slot;
  if(i >= N) return;
  const float4* xr = (const float4*)x;
  float4 acc = xr[(size_t)i*32 + c];
  int e0 = offs[i], e1 = offs[i+1];
  e0 = max(0, min(e0, E));
  e1 = max(e0, min(e1, E));
  for(int j=e0; j<e1; j++){
    int s = elist[j];
    if((u32)s >= (u32)N) s = 0;
    float4 v = xr[(size_t)s*32 + c];
    acc.x += v.x; acc.y += v.y; acc.z += v.z; acc.w += v.w;
  }
  ((float4*)h0)[(size_t)i*32 + c] = acc;
}

// =============== fp32 tiled GEMM: C[M,256] = op(A[M,K]) @ B[K,256] + bias ===============
// tile 64x256, 256 threads, 8x8 micro-tile. Optional fused BN+ReLU on A, ReLU on out,
// and fused gate = (C_row . Wg) + bg written per row.
template<int K, bool BNA, bool RELUOUT, bool GATE>
__global__ __launch_bounds__(256) void gemm_k(const float* __restrict__ A, const float* __restrict__ B,
                                              const float* __restrict__ bias,
                                              const float* __restrict__ scale, const float* __restrict__ shift,
                                              float* __restrict__ C, int M,
                                              const float* __restrict__ Wg, const float* __restrict__ bg,
                                              float* __restrict__ gate){
  __shared__ float As[16][64];
  __shared__ float Bs[16][256];
  const int tid = threadIdx.x;
  const int tn = tid & 31, tm = tid >> 5;
  const int m0 = blockIdx.x * 64;
  float acc[8][8];
  #pragma unroll
  for(int i=0;i<8;i++){
    #pragma unroll
    for(int j=0;j<8;j++) acc[i][j]=0.f;
  }
  const int arow = tid >> 2;          // 0..63
  const int akk  = (tid & 3)*4;       // 0,4,8,12
  const int brow = tid >> 6;          // 0..3
  const int bn4  = (tid & 63)*4;      // 0..252

  for(int k0=0; k0<K; k0+=16){
    float4 a4 = make_float4(0.f,0.f,0.f,0.f);
    if(m0 + arow < M) a4 = *(const float4*)(A + (size_t)(m0+arow)*K + k0 + akk);
    if(BNA){
      float4 s4 = *(const float4*)(scale + k0 + akk);
      float4 t4 = *(const float4*)(shift + k0 + akk);
      a4.x = fmaxf(fmaf(s4.x, a4.x, t4.x), 0.f);
      a4.y = fmaxf(fmaf(s4.y, a4.y, t4.y), 0.f);
      a4.z = fmaxf(fmaf(s4.z, a4.z, t4.z), 0.f);
      a4.w = fmaxf(fmaf(s4.w, a4.w, t4.w), 0.f);
    }
    As[akk+0][arow]=a4.x; As[akk+1][arow]=a4.y; As[akk+2][arow]=a4.z; As[akk+3][arow]=a4.w;
    #pragma unroll
    for(int p=0;p<4;p++){
      int kr = brow + p*4;
      *(float4*)&Bs[kr][bn4] = *(const float4*)(B + (size_t)(k0+kr)*256 + bn4);
    }
    __syncthreads();
    #pragma unroll
    for(int k=0;k<16;k++){
      float4 a0 = *(const float4*)&As[k][tm*4];
      float4 a1 = *(const float4*)&As[k][32 + tm*4];
      float4 b0 = *(const float4*)&Bs[k][tn*4];
      float4 b1 = *(const float4*)&Bs[k][128 + tn*4];
      float ar[8] = {a0.x,a0.y,a0.z,a0.w,a1.x,a1.y,a1.z,a1.w};
      float br[8] = {b0.x,b0.y,b0.z,b0.w,b1.x,b1.y,b1.z,b1.w};
      #pragma unroll
      for(int i=0;i<8;i++){
        #pragma unroll
        for(int j=0;j<8;j++) acc[i][j] = fmaf(ar[i], br[j], acc[i][j]);
      }
    }
    __syncthreads();
  }
  float bb[8];
  {
    float4 t0 = *(const float4*)(bias + tn*4);
    float4 t1 = *(const float4*)(bias + 128 + tn*4);
    bb[0]=t0.x; bb[1]=t0.y; bb[2]=t0.z; bb[3]=t0.w;
    bb[4]=t1.x; bb[5]=t1.y; bb[6]=t1.z; bb[7]=t1.w;
  }
  float wg[8];
  float bg0 = 0.f;
  if(GATE){
    float4 w0 = *(const float4*)(Wg + tn*4);
    float4 w1 = *(const float4*)(Wg + 128 + tn*4);
    wg[0]=w0.x; wg[1]=w0.y; wg[2]=w0.z; wg[3]=w0.w;
    wg[4]=w1.x; wg[5]=w1.y; wg[6]=w1.z; wg[7]=w1.w;
    bg0 = bg[0];
  }
  #pragma unroll
  for(int i=0;i<8;i++){
    int row = m0 + ((i<4) ? (tm*4+i) : (32 + tm*4 + (i-4)));
    if(row < M){
      float o[8];
      #pragma unroll
      for(int j=0;j<8;j++){
        o[j] = acc[i][j] + bb[j];
        if(RELUOUT) o[j] = fmaxf(o[j], 0.f);
      }
      float4 o0 = make_float4(o[0],o[1],o[2],o[3]);
      float4 o1 = make_float4(o[4],o[5],o[6],o[7]);
      *(float4*)(C + (size_t)row*256 + tn*4)       = o0;
      *(float4*)(C + (size_t)row*256 + 128 + tn*4) = o1;
      if(GATE){
        float p = 0.f;
        #pragma unroll
        for(int j=0;j<8;j++) p = fmaf(o[j], wg[j], p);
        #pragma unroll
        for(int d=16; d>0; d>>=1) p += __shfl_down(p, d, 32);
        if(tn==0) gate[row] = p + bg0;
      }
    }
  }
}

// =============== BN column stats (atomic partials) ===============
__global__ __launch_bounds__(256) void col_stats(const float* __restrict__ h, float* __restrict__ sums,
                                                 int M, int rowsPerBlock){
  int t = threadIdx.x;
  int r0 = blockIdx.x * rowsPerBlock;
  int r1 = min(r0 + rowsPerBlock, M);
  float s=0.f, q=0.f;
  for(int r=r0; r<r1; r++){
    float v = h[(size_t)r*256 + t];
    s += v; q = fmaf(v, v, q);
  }
  atomicAdd(&sums[t], s);
  atomicAdd(&sums[256+t], q);
}

__global__ void bn_fin(const float* __restrict__ sums, const float* __restrict__ gamma,
                       const float* __restrict__ beta, float* __restrict__ scale,
                       float* __restrict__ shift, float invM){
  int t = threadIdx.x;
  float mu  = sums[t]*invM;
  float var = fmaxf(sums[256+t]*invM - mu*mu, 0.f);
  float sc  = gamma[t] * rsqrtf(var + 1e-5f);
  scale[t] = sc;
  shift[t] = fmaf(-mu, sc, beta[t]);
}

// =============== attentional pool: one block per graph (batch sorted) ===============
__global__ __launch_bounds__(256) void pool_k(const float* __restrict__ h2, const float* __restrict__ gate,
                                              const int* __restrict__ batch, float* __restrict__ pooled, int N){
  int g = blockIdx.x;
  __shared__ int sb[2];
  __shared__ float red[4];
  __shared__ float s_m, s_inv;
  if(threadIdx.x < 2){
    int target = g + threadIdx.x;
    int lo=0, hi=N;
    while(lo<hi){ int mid=(lo+hi)>>1; if(batch[mid] < target) lo=mid+1; else hi=mid; }
    sb[threadIdx.x] = lo;
  }
  __syncthreads();
  int beg = sb[0], end = sb[1];
  float mx = -1e30f;
  for(int i=beg+threadIdx.x; i<end; i+=256) mx = fmaxf(mx, gate[i]);
  #pragma unroll
  for(int d=32; d>0; d>>=1) mx = fmaxf(mx, __shfl_down(mx, d, 64));
  if((threadIdx.x&63)==0) red[threadIdx.x>>6] = mx;
  __syncthreads();
  if(threadIdx.x==0) s_m = fmaxf(fmaxf(red[0],red[1]), fmaxf(red[2],red[3]));
  __syncthreads();
  float m = s_m;
  float s = 0.f;
  for(int i=beg+threadIdx.x; i<end; i+=256) s += expf(gate[i]-m);
  #pragma unroll
  for(int d=32; d>0; d>>=1) s += __shfl_down(s, d, 64);
  if((threadIdx.x&63)==0) red[threadIdx.x>>6] = s;
  __syncthreads();
  if(threadIdx.x==0){
    float tot = red[0]+red[1]+red[2]+red[3];
    s_inv = (tot > 0.f) ? 1.f/tot : 0.f;
  }
  __syncthreads();
  float inv = s_inv;
  int t = threadIdx.x;
  float acc = 0.f;
  for(int i=beg; i<end; i++){
    float a = expf(gate[i]-m) * inv;
    acc = fmaf(a, h2[(size_t)i*256 + t], acc);
  }
  pooled[g*256 + t] = acc;
}

// =============== head linear + log_softmax: one wave per graph ===============
__global__ __launch_bounds__(256) void head_k(const float* __restrict__ pooled,
                                              const float* __restrict__ sc2, const float* __restrict__ sh2,
                                              const float* __restrict__ Wh, const float* __restrict__ bh,
                                              float* __restrict__ out, int G){
  int w = (blockIdx.x*256 + threadIdx.x) >> 6;
  int l = threadIdx.x & 63;
  if(w >= G) return;
  float4 v  = *(const float4*)(pooled + (size_t)w*256 + l*4);
  float4 sc = *(const float4*)(sc2 + l*4);
  float4 sh = *(const float4*)(sh2 + l*4);
  float vv[4] = { fmaf(sc.x,v.x,sh.x), fmaf(sc.y,v.y,sh.y), fmaf(sc.z,v.z,sh.z), fmaf(sc.w,v.w,sh.w) };
  float4 w0 = *(const float4*)(Wh + (size_t)l*8);
  float4 w1 = *(const float4*)(Wh + (size_t)l*8 + 4);
  float a0 = vv[0]*w0.x + vv[1]*w0.z + vv[2]*w1.x + vv[3]*w1.z;
  float a1 = vv[0]*w0.y + vv[1]*w0.w + vv[2]*w1.y + vv[3]*w1.w;
  #pragma unroll
  for(int d=32; d>0; d>>=1){ a0 += __shfl_down(a0,d,64); a1 += __shfl_down(a1,d,64); }
  if(l==0){
    float z0 = a0 + bh[0];
    float z1 = a1 + bh[1];
    float mz = fmaxf(z0,z1);
    float lse = mz + logf(expf(z0-mz) + expf(z1-mz));
    out[w*2]   = z0 - lse;
    out[w*2+1] = z1 - lse;
  }
}

extern "C" void kernel_launch(void* const* d_in, const int* in_sizes, int n_in,
                              void* d_out, int out_size, void* d_ws, size_t ws_size,
                              hipStream_t stream){
  const float* x   = (const float*)d_in[0];
  const int*   ei  = (const int*)d_in[1];
  const int*   bat = (const int*)d_in[2];
  const float* W1  = (const float*)d_in[3];
  const float* b1  = (const float*)d_in[4];
  const float* g1  = (const float*)d_in[5];
  const float* be1 = (const float*)d_in[6];
  const float* W2  = (const float*)d_in[7];
  const float* b2  = (const float*)d_in[8];
  const float* Wg  = (const float*)d_in[9];
  const float* bg  = (const float*)d_in[10];
  const float* g2  = (const float*)d_in[11];
  const float* be2 = (const float*)d_in[12];
  const float* Wh  = (const float*)d_in[13];
  const float* bh  = (const float*)d_in[14];

  const int N = in_sizes[0] / 128;   // 50000
  const int E = in_sizes[1] / 2;     // 1600000
  const int G = out_size / 2;        // 512
  const int NB = (N + 63) >> 6;      // 782 buckets

  // ---- workspace layout (~103 MB) ----
  char* ws = (char*)d_ws;
  float* h0     = (float*)ws;                        // 25,600,000 B
  int*   elist  = (int*)(ws + 25600000);             //  6,400,000 B
  u32*   pairs  = (u32*)(ws + 32000000);             //  6,400,000 B
  int*   offs   = (int*)(ws + 38400000);             //    200,004 B
  int*   bcount = (int*)(ws + 38600192);             //      4,096 B
  int*   bstart = (int*)(ws + 38604288);             //      4,100 B
  int*   bcursor= (int*)(ws + 38608640);             //     65,536 B (1024 counters, 64B stride)
  float* h2     = (float*)ws;                        // 51,200,000 B (phase2)
  float* h1     = (float*)(ws + 51200000);           // 51,200,000 B
  char*  p2 = ws + 102400000;
  float* sums1 = (float*)p2;          p2 += 2048;
  float* sums2 = (float*)p2;          p2 += 2048;
  float* sc1   = (float*)p2;          p2 += 1024;
  float* sh1   = (float*)p2;          p2 += 1024;
  float* gate  = (float*)p2;          p2 += (size_t)N*4 + 256;
  float* pooled= (float*)p2;          p2 += (size_t)G*256*4;
  float* sc2   = (float*)p2;          p2 += 1024;
  float* sh2   = (float*)p2;          p2 += 1024;

  const int* src = ei;
  const int* dst = ei + E;

  hipMemsetAsync(bcount, 0, (size_t)NB*4, stream);
  hipMemsetAsync(sums1, 0, 512*4, stream);
  hipMemsetAsync(sums2, 0, 512*4, stream);

  // CSR build via block-aggregated binned counting sort
  int nchunk = (E + 8191)/8192;
  hist_k     <<<nchunk, 256, 0, stream>>>(dst, bcount, E, N, NB);
  bucket_scan<<<1, 256, 0, stream>>>(bcount, bstart, bcursor, offs, NB, N, E);
  binscatter2<<<nchunk, 256, 0, stream>>>(src, dst, bstart, bcursor, pairs, E, N, NB);
  bucket_csr <<<NB, 256, 0, stream>>>(pairs, bstart, offs, elist, N);
  gather_sum <<<(N+7)/8, 256, 0, stream>>>(x, offs, elist, h0, N, E);

  // MLP: gemm1 -> BN stats -> gemm2 (fused BN+ReLU on input, ReLU + gate on output)
  gemm_k<128,false,false,false><<<(N+63)/64, 256, 0, stream>>>(h0, W1, b1, nullptr, nullptr, h1, N, nullptr, nullptr, nullptr);
  col_stats  <<<100, 256, 0, stream>>>(h1, sums1, N, (N+99)/100);
  bn_fin     <<<1, 256, 0, stream>>>(sums1, g1, be1, sc1, sh1, 1.0f/(float)N);
  gemm_k<256,true,true,true><<<(N+63)/64, 256, 0, stream>>>(h1, W2, b2, sc1, sh1, h2, N, Wg, bg, gate);

  // pooling + head
  pool_k <<<G, 256, 0, stream>>>(h2, gate, bat, pooled, N);
  col_stats <<<(G+15)/16, 256, 0, stream>>>(pooled, sums2, G, 16);
  bn_fin    <<<1, 256, 0, stream>>>(sums2, g2, be2, sc2, sh2, 1.0f/(float)G);
  head_k <<<(G+3)/4, 256, 0, stream>>>(pooled, sc2, sh2, Wh, bh, (float*)d_out, G);
}

// Round 6
// 520.369 us; speedup vs baseline: 1.8258x; 1.1534x over previous
//
#include <hip/hip_runtime.h>

typedef unsigned int u32;

// =============== binned CSR build (counting sort by dst) ===============
// bucket = dst >> 6 (64 nodes/bucket). NB = ceil(N/64) <= 1024.

__global__ __launch_bounds__(256) void hist_k(const int* __restrict__ dst, int* __restrict__ bcount,
                                              int E, int N, int NB){
  __shared__ int h[1024];
  for(int i=threadIdx.x; i<1024; i+=256) h[i]=0;
  __syncthreads();
  int e0 = blockIdx.x*8192;
  int e1 = min(e0+8192, E);
  for(int i=e0+threadIdx.x; i<e1; i+=256){
    int d = dst[i];
    if((u32)d >= (u32)N) d = 0;
    atomicAdd(&h[d>>6], 1);
  }
  __syncthreads();
  for(int i=threadIdx.x; i<NB; i+=256){
    int v = h[i];
    if(v) atomicAdd(&bcount[i], v);
  }
}

// single block: exclusive scan of bcount[NB] -> bstart, zero padded bcursor, offs[N]=E
__global__ __launch_bounds__(256) void bucket_scan(const int* __restrict__ bcount, int* __restrict__ bstart,
                                                   int* __restrict__ bcursor, int* __restrict__ offs,
                                                   int NB, int N, int E){
  __shared__ int tsum[256];
  int t = threadIdx.x;
  int base = t*4;
  int a0 = (base+0<NB)?bcount[base+0]:0;
  int a1 = (base+1<NB)?bcount[base+1]:0;
  int a2 = (base+2<NB)?bcount[base+2]:0;
  int a3 = (base+3<NB)?bcount[base+3]:0;
  int s0=a0, s1=s0+a1, s2=s1+a2, s3=s2+a3;
  tsum[t]=s3; __syncthreads();
  #pragma unroll
  for(int d=1; d<256; d<<=1){
    int v = (t>=d)?tsum[t-d]:0;
    __syncthreads();
    tsum[t]+=v;
    __syncthreads();
  }
  int prev = (t>0)?tsum[t-1]:0;
  if(base+0<NB){ bstart[base+0]=prev;    bcursor[(base+0)*16]=0; }
  if(base+1<NB){ bstart[base+1]=prev+s0; bcursor[(base+1)*16]=0; }
  if(base+2<NB){ bstart[base+2]=prev+s1; bcursor[(base+2)*16]=0; }
  if(base+3<NB){ bstart[base+3]=prev+s2; bcursor[(base+3)*16]=0; }
  if(t==255){ bstart[NB]=prev+s3; offs[N]=E; }
}

// block-aggregated two-pass binning: LDS hist -> 1 reservation atomic per (block,bucket)
// (bcursor padded 64B/counter) -> LDS-cursor scatter. Writes per (block,bucket) contiguous.
__global__ __launch_bounds__(256) void binscatter2(const int* __restrict__ src, const int* __restrict__ dst,
                                                   const int* __restrict__ bstart, int* __restrict__ bcursor,
                                                   u32* __restrict__ pairs, int E, int N, int NB){
  __shared__ int hist[1024];
  __shared__ int base[1024];
  int e0 = blockIdx.x*8192;
  int e1 = min(e0+8192, E);
  for(int i=threadIdx.x; i<NB; i+=256) hist[i]=0;
  __syncthreads();
  for(int i=e0+threadIdx.x; i<e1; i+=256){
    int d = dst[i];
    if((u32)d >= (u32)N) d = 0;
    atomicAdd(&hist[d>>6], 1);
  }
  __syncthreads();
  for(int i=threadIdx.x; i<NB; i+=256){
    int c = hist[i];
    base[i] = c ? (bstart[i] + atomicAdd(&bcursor[i*16], c)) : 0;
    hist[i] = 0;                       // reuse as local cursor
  }
  __syncthreads();
  for(int i=e0+threadIdx.x; i<e1; i+=256){
    int d = dst[i]; if((u32)d >= (u32)N) d = 0;
    int s = src[i]; if((u32)s >= (u32)N) s = 0;
    int b = d>>6;
    int loc = atomicAdd(&hist[b], 1);
    pairs[base[b]+loc] = (u32)s | (((u32)(d & 63))<<17);
  }
}

// per-bucket: count 64 node degrees in LDS, serial scan, write offs, scatter src into elist (L2-hot)
__global__ __launch_bounds__(256) void bucket_csr(const u32* __restrict__ pairs, const int* __restrict__ bstart,
                                                  int* __restrict__ offs, int* __restrict__ elist, int N){
  __shared__ int dcnt[64];
  __shared__ int dcur[64];
  int b = blockIdx.x;
  int p0 = bstart[b], p1 = bstart[b+1];
  if(threadIdx.x < 64) dcnt[threadIdx.x] = 0;
  __syncthreads();
  for(int i=p0+threadIdx.x; i<p1; i+=256){
    u32 u = pairs[i];
    atomicAdd(&dcnt[u>>17], 1);
  }
  __syncthreads();
  if(threadIdx.x == 0){
    int running = p0;
    #pragma unroll
    for(int j=0;j<64;j++){
      dcur[j] = running;
      int node = b*64 + j;
      if(node < N) offs[node] = running;
      running += dcnt[j];
    }
  }
  __syncthreads();
  for(int i=p0+threadIdx.x; i<p1; i+=256){
    u32 u = pairs[i];
    int pos = atomicAdd(&dcur[u>>17], 1);
    elist[pos] = (int)(u & 0x1FFFFu);
  }
}

// h0[i] = x[i] + sum_{j->i} x[j]   (fp32). 32 lanes per 128-wide node row.
__global__ __launch_bounds__(256) void gather_sum(const float* __restrict__ x, const int* __restrict__ offs,
                                                  const int* __restrict__ elist, float* __restrict__ h0,
                                                  int N, int E){
  int slot = threadIdx.x >> 5;
  int c = threadIdx.x & 31;
  int i = blockIdx.x*8 + slot;
  if(i >= N) return;
  const float4* xr = (const float4*)x;
  float4 acc = xr[(size_t)i*32 + c];
  int e0 = offs[i], e1 = offs[i+1];
  e0 = max(0, min(e0, E));
  e1 = max(e0, min(e1, E));
  for(int j=e0; j<e1; j++){
    int s = elist[j];
    if((u32)s >= (u32)N) s = 0;
    float4 v = xr[(size_t)s*32 + c];
    acc.x += v.x; acc.y += v.y; acc.z += v.z; acc.w += v.w;
  }
  ((float4*)h0)[(size_t)i*32 + c] = acc;
}

// =============== fp32 tiled GEMM: C[M,256] = op(A[M,K]) @ B[K,256] + bias ===============
// tile 64x256, 256 threads, 8x8 micro-tile. Optional fused BN+ReLU on A, ReLU on out,
// and fused gate = (C_row . Wg) + bg written per row.
template<int K, bool BNA, bool RELUOUT, bool GATE>
__global__ __launch_bounds__(256) void gemm_k(const float* __restrict__ A, const float* __restrict__ B,
                                              const float* __restrict__ bias,
                                              const float* __restrict__ scale, const float* __restrict__ shift,
                                              float* __restrict__ C, int M,
                                              const float* __restrict__ Wg, const float* __restrict__ bg,
                                              float* __restrict__ gate){
  __shared__ float As[16][64];
  __shared__ float Bs[16][256];
  const int tid = threadIdx.x;
  const int tn = tid & 31, tm = tid >> 5;
  const int m0 = blockIdx.x * 64;
  float acc[8][8];
  #pragma unroll
  for(int i=0;i<8;i++){
    #pragma unroll
    for(int j=0;j<8;j++) acc[i][j]=0.f;
  }
  const int arow = tid >> 2;          // 0..63
  const int akk  = (tid & 3)*4;       // 0,4,8,12
  const int brow = tid >> 6;          // 0..3
  const int bn4  = (tid & 63)*4;      // 0..252

  for(int k0=0; k0<K; k0+=16){
    float4 a4 = make_float4(0.f,0.f,0.f,0.f);
    if(m0 + arow < M) a4 = *(const float4*)(A + (size_t)(m0+arow)*K + k0 + akk);
    if(BNA){
      float4 s4 = *(const float4*)(scale + k0 + akk);
      float4 t4 = *(const float4*)(shift + k0 + akk);
      a4.x = fmaxf(fmaf(s4.x, a4.x, t4.x), 0.f);
      a4.y = fmaxf(fmaf(s4.y, a4.y, t4.y), 0.f);
      a4.z = fmaxf(fmaf(s4.z, a4.z, t4.z), 0.f);
      a4.w = fmaxf(fmaf(s4.w, a4.w, t4.w), 0.f);
    }
    As[akk+0][arow]=a4.x; As[akk+1][arow]=a4.y; As[akk+2][arow]=a4.z; As[akk+3][arow]=a4.w;
    #pragma unroll
    for(int p=0;p<4;p++){
      int kr = brow + p*4;
      *(float4*)&Bs[kr][bn4] = *(const float4*)(B + (size_t)(k0+kr)*256 + bn4);
    }
    __syncthreads();
    #pragma unroll
    for(int k=0;k<16;k++){
      float4 a0 = *(const float4*)&As[k][tm*4];
      float4 a1 = *(const float4*)&As[k][32 + tm*4];
      float4 b0 = *(const float4*)&Bs[k][tn*4];
      float4 b1 = *(const float4*)&Bs[k][128 + tn*4];
      float ar[8] = {a0.x,a0.y,a0.z,a0.w,a1.x,a1.y,a1.z,a1.w};
      float br[8] = {b0.x,b0.y,b0.z,b0.w,b1.x,b1.y,b1.z,b1.w};
      #pragma unroll
      for(int i=0;i<8;i++){
        #pragma unroll
        for(int j=0;j<8;j++) acc[i][j] = fmaf(ar[i], br[j], acc[i][j]);
      }
    }
    __syncthreads();
  }
  float bb[8];
  {
    float4 t0 = *(const float4*)(bias + tn*4);
    float4 t1 = *(const float4*)(bias + 128 + tn*4);
    bb[0]=t0.x; bb[1]=t0.y; bb[2]=t0.z; bb[3]=t0.w;
    bb[4]=t1.x; bb[5]=t1.y; bb[6]=t1.z; bb[7]=t1.w;
  }
  float wg[8];
  float bg0 = 0.f;
  if(GATE){
    float4 w0 = *(const float4*)(Wg + tn*4);
    float4 w1 = *(const float4*)(Wg + 128 + tn*4);
    wg[0]=w0.x; wg[1]=w0.y; wg[2]=w0.z; wg[3]=w0.w;
    wg[4]=w1.x; wg[5]=w1.y; wg[6]=w1.z; wg[7]=w1.w;
    bg0 = bg[0];
  }
  #pragma unroll
  for(int i=0;i<8;i++){
    int row = m0 + ((i<4) ? (tm*4+i) : (32 + tm*4 + (i-4)));
    if(row < M){
      float o[8];
      #pragma unroll
      for(int j=0;j<8;j++){
        o[j] = acc[i][j] + bb[j];
        if(RELUOUT) o[j] = fmaxf(o[j], 0.f);
      }
      float4 o0 = make_float4(o[0],o[1],o[2],o[3]);
      float4 o1 = make_float4(o[4],o[5],o[6],o[7]);
      *(float4*)(C + (size_t)row*256 + tn*4)       = o0;
      *(float4*)(C + (size_t)row*256 + 128 + tn*4) = o1;
      if(GATE){
        float p = 0.f;
        #pragma unroll
        for(int j=0;j<8;j++) p = fmaf(o[j], wg[j], p);
        #pragma unroll
        for(int d=16; d>0; d>>=1) p += __shfl_down(p, d, 32);
        if(tn==0) gate[row] = p + bg0;
      }
    }
  }
}

// =============== BN column stats v2: parallel partials (no atomics) ===============
// grid nblk blocks x 256 threads (4 row-groups x 64 lanes), float4 loads.
// partials layout column-major: psum[c*nblk + b] so stats_fin reads contiguous runs.
__global__ __launch_bounds__(256) void col_stats2(const float* __restrict__ h, float* __restrict__ psum,
                                                  float* __restrict__ pq, int M, int rpb, int nblk){
  int b = blockIdx.x;
  int g = threadIdx.x >> 6;
  int lane = threadIdx.x & 63;
  int c0 = lane*4;
  int r0 = b*rpb;
  int r1 = min(r0+rpb, M);
  float4 s4 = make_float4(0.f,0.f,0.f,0.f);
  float4 q4 = make_float4(0.f,0.f,0.f,0.f);
  for(int r=r0+g; r<r1; r+=4){
    float4 v = *(const float4*)(h + (size_t)r*256 + c0);
    s4.x+=v.x; s4.y+=v.y; s4.z+=v.z; s4.w+=v.w;
    q4.x=fmaf(v.x,v.x,q4.x); q4.y=fmaf(v.y,v.y,q4.y);
    q4.z=fmaf(v.z,v.z,q4.z); q4.w=fmaf(v.w,v.w,q4.w);
  }
  __shared__ float ls[1024];
  __shared__ float lq[1024];
  *(float4*)&ls[g*256+c0] = s4;
  *(float4*)&lq[g*256+c0] = q4;
  __syncthreads();
  if(threadIdx.x < 64){
    #pragma unroll
    for(int j=0;j<4;j++){
      int c = c0+j;
      float s = ls[c]+ls[256+c]+ls[512+c]+ls[768+c];
      float q = lq[c]+lq[256+c]+lq[512+c]+lq[768+c];
      psum[(size_t)c*nblk + b] = s;
      pq[(size_t)c*nblk + b]   = q;
    }
  }
}

// single block, 512 threads: reduce partials (contiguous float4 runs) + BN finalize.
__global__ __launch_bounds__(512) void stats_fin(const float* __restrict__ psum, const float* __restrict__ pq,
                                                 const float* __restrict__ gamma, const float* __restrict__ beta,
                                                 float* __restrict__ scale, float* __restrict__ shift,
                                                 int nblk, float invM){
  __shared__ float red[512];
  int t = threadIdx.x;
  const float* src = (t<256) ? (psum + (size_t)t*nblk) : (pq + (size_t)(t-256)*nblk);
  float s = 0.f;
  for(int i=0;i<nblk;i+=4){
    float4 v = *(const float4*)(src+i);
    s += v.x+v.y+v.z+v.w;
  }
  red[t]=s; __syncthreads();
  if(t<256){
    float mu  = red[t]*invM;
    float var = fmaxf(red[256+t]*invM - mu*mu, 0.f);
    float sc  = gamma[t] * rsqrtf(var + 1e-5f);
    scale[t]=sc; shift[t]=fmaf(-mu, sc, beta[t]);
  }
}

// =============== attentional pool: one block per graph (batch sorted) ===============
__global__ __launch_bounds__(256) void pool_k(const float* __restrict__ h2, const float* __restrict__ gate,
                                              const int* __restrict__ batch, float* __restrict__ pooled, int N){
  int g = blockIdx.x;
  __shared__ int sb[2];
  __shared__ float red[4];
  __shared__ float s_m, s_inv;
  if(threadIdx.x < 2){
    int target = g + threadIdx.x;
    int lo=0, hi=N;
    while(lo<hi){ int mid=(lo+hi)>>1; if(batch[mid] < target) lo=mid+1; else hi=mid; }
    sb[threadIdx.x] = lo;
  }
  __syncthreads();
  int beg = sb[0], end = sb[1];
  float mx = -1e30f;
  for(int i=beg+threadIdx.x; i<end; i+=256) mx = fmaxf(mx, gate[i]);
  #pragma unroll
  for(int d=32; d>0; d>>=1) mx = fmaxf(mx, __shfl_down(mx, d, 64));
  if((threadIdx.x&63)==0) red[threadIdx.x>>6] = mx;
  __syncthreads();
  if(threadIdx.x==0) s_m = fmaxf(fmaxf(red[0],red[1]), fmaxf(red[2],red[3]));
  __syncthreads();
  float m = s_m;
  float s = 0.f;
  for(int i=beg+threadIdx.x; i<end; i+=256) s += expf(gate[i]-m);
  #pragma unroll
  for(int d=32; d>0; d>>=1) s += __shfl_down(s, d, 64);
  if((threadIdx.x&63)==0) red[threadIdx.x>>6] = s;
  __syncthreads();
  if(threadIdx.x==0){
    float tot = red[0]+red[1]+red[2]+red[3];
    s_inv = (tot > 0.f) ? 1.f/tot : 0.f;
  }
  __syncthreads();
  float inv = s_inv;
  int t = threadIdx.x;
  float acc = 0.f;
  for(int i=beg; i<end; i++){
    float a = expf(gate[i]-m) * inv;
    acc = fmaf(a, h2[(size_t)i*256 + t], acc);
  }
  pooled[g*256 + t] = acc;
}

// =============== head linear + log_softmax: one wave per graph ===============
__global__ __launch_bounds__(256) void head_k(const float* __restrict__ pooled,
                                              const float* __restrict__ sc2, const float* __restrict__ sh2,
                                              const float* __restrict__ Wh, const float* __restrict__ bh,
                                              float* __restrict__ out, int G){
  int w = (blockIdx.x*256 + threadIdx.x) >> 6;
  int l = threadIdx.x & 63;
  if(w >= G) return;
  float4 v  = *(const float4*)(pooled + (size_t)w*256 + l*4);
  float4 sc = *(const float4*)(sc2 + l*4);
  float4 sh = *(const float4*)(sh2 + l*4);
  float vv[4] = { fmaf(sc.x,v.x,sh.x), fmaf(sc.y,v.y,sh.y), fmaf(sc.z,v.z,sh.z), fmaf(sc.w,v.w,sh.w) };
  float4 w0 = *(const float4*)(Wh + (size_t)l*8);
  float4 w1 = *(const float4*)(Wh + (size_t)l*8 + 4);
  float a0 = vv[0]*w0.x + vv[1]*w0.z + vv[2]*w1.x + vv[3]*w1.z;
  float a1 = vv[0]*w0.y + vv[1]*w0.w + vv[2]*w1.y + vv[3]*w1.w;
  #pragma unroll
  for(int d=32; d>0; d>>=1){ a0 += __shfl_down(a0,d,64); a1 += __shfl_down(a1,d,64); }
  if(l==0){
    float z0 = a0 + bh[0];
    float z1 = a1 + bh[1];
    float mz = fmaxf(z0,z1);
    float lse = mz + logf(expf(z0-mz) + expf(z1-mz));
    out[w*2]   = z0 - lse;
    out[w*2+1] = z1 - lse;
  }
}

extern "C" void kernel_launch(void* const* d_in, const int* in_sizes, int n_in,
                              void* d_out, int out_size, void* d_ws, size_t ws_size,
                              hipStream_t stream){
  const float* x   = (const float*)d_in[0];
  const int*   ei  = (const int*)d_in[1];
  const int*   bat = (const int*)d_in[2];
  const float* W1  = (const float*)d_in[3];
  const float* b1  = (const float*)d_in[4];
  const float* g1  = (const float*)d_in[5];
  const float* be1 = (const float*)d_in[6];
  const float* W2  = (const float*)d_in[7];
  const float* b2  = (const float*)d_in[8];
  const float* Wg  = (const float*)d_in[9];
  const float* bg  = (const float*)d_in[10];
  const float* g2  = (const float*)d_in[11];
  const float* be2 = (const float*)d_in[12];
  const float* Wh  = (const float*)d_in[13];
  const float* bh  = (const float*)d_in[14];

  const int N = in_sizes[0] / 128;   // 50000
  const int E = in_sizes[1] / 2;     // 1600000
  const int G = out_size / 2;        // 512
  const int NB = (N + 63) >> 6;      // 782 buckets
  const int NBLK1 = 512;             // col-stats partial blocks for h1
  const int NBLK2 = 64;              // for pooled

  // ---- workspace layout (~105 MB) ----
  char* ws = (char*)d_ws;
  float* h0     = (float*)ws;                        // 25,600,000 B
  int*   elist  = (int*)(ws + 25600000);             //  6,400,000 B
  u32*   pairs  = (u32*)(ws + 32000000);             //  6,400,000 B
  int*   offs   = (int*)(ws + 38400000);             //    200,004 B
  int*   bcount = (int*)(ws + 38600192);             //      4,096 B
  int*   bstart = (int*)(ws + 38604288);             //      4,100 B
  int*   bcursor= (int*)(ws + 38608640);             //     65,536 B (1024 counters, 64B stride)
  float* h2     = (float*)ws;                        // 51,200,000 B (phase2)
  float* h1     = (float*)(ws + 51200000);           // 51,200,000 B
  char*  p2 = ws + 102400000;
  float* psum1 = (float*)p2;          p2 += 256*NBLK1*4;   // 512 KB
  float* pq1   = (float*)p2;          p2 += 256*NBLK1*4;   // 512 KB
  float* psum2 = (float*)p2;          p2 += 256*NBLK2*4;   // 64 KB
  float* pq2   = (float*)p2;          p2 += 256*NBLK2*4;   // 64 KB
  float* sc1   = (float*)p2;          p2 += 1024;
  float* sh1   = (float*)p2;          p2 += 1024;
  float* gate  = (float*)p2;          p2 += (size_t)N*4 + 256;
  float* pooled= (float*)p2;          p2 += (size_t)G*256*4;
  float* sc2   = (float*)p2;          p2 += 1024;
  float* sh2   = (float*)p2;          p2 += 1024;

  const int* src = ei;
  const int* dst = ei + E;

  hipMemsetAsync(bcount, 0, (size_t)NB*4, stream);

  // CSR build via block-aggregated binned counting sort
  int nchunk = (E + 8191)/8192;
  hist_k     <<<nchunk, 256, 0, stream>>>(dst, bcount, E, N, NB);
  bucket_scan<<<1, 256, 0, stream>>>(bcount, bstart, bcursor, offs, NB, N, E);
  binscatter2<<<nchunk, 256, 0, stream>>>(src, dst, bstart, bcursor, pairs, E, N, NB);
  bucket_csr <<<NB, 256, 0, stream>>>(pairs, bstart, offs, elist, N);
  gather_sum <<<(N+7)/8, 256, 0, stream>>>(x, offs, elist, h0, N, E);

  // MLP: gemm1 -> BN stats -> gemm2 (fused BN+ReLU on input, ReLU + gate on output)
  gemm_k<128,false,false,false><<<(N+63)/64, 256, 0, stream>>>(h0, W1, b1, nullptr, nullptr, h1, N, nullptr, nullptr, nullptr);
  int rpb1 = (N + NBLK1 - 1)/NBLK1;
  col_stats2 <<<NBLK1, 256, 0, stream>>>(h1, psum1, pq1, N, rpb1, NBLK1);
  stats_fin  <<<1, 512, 0, stream>>>(psum1, pq1, g1, be1, sc1, sh1, NBLK1, 1.0f/(float)N);
  gemm_k<256,true,true,true><<<(N+63)/64, 256, 0, stream>>>(h1, W2, b2, sc1, sh1, h2, N, Wg, bg, gate);

  // pooling + head
  pool_k <<<G, 256, 0, stream>>>(h2, gate, bat, pooled, N);
  int rpb2 = (G + NBLK2 - 1)/NBLK2;
  col_stats2 <<<NBLK2, 256, 0, stream>>>(pooled, psum2, pq2, G, rpb2, NBLK2);
  stats_fin  <<<1, 512, 0, stream>>>(psum2, pq2, g2, be2, sc2, sh2, NBLK2, 1.0f/(float)G);
  head_k <<<(G+3)/4, 256, 0, stream>>>(pooled, sc2, sh2, Wh, bh, (float*)d_out, G);
}

// Round 7
// 480.456 us; speedup vs baseline: 1.9774x; 1.0831x over previous
//
#include <hip/hip_runtime.h>

typedef unsigned int u32;

__device__ __forceinline__ float bf2f_lo(u32 u){
  union{u32 i; float f;} v; v.i = u<<16; return v.f;
}
__device__ __forceinline__ float bf2f_hi(u32 u){
  union{u32 i; float f;} v; v.i = u & 0xFFFF0000u; return v.f;
}
__device__ __forceinline__ u32 pack2bf(float a, float b){
  union{float f; u32 i;} va, vb; va.f=a; vb.f=b;
  u32 ra = (va.i + 0x7FFF + ((va.i>>16)&1)) >> 16;          // RNE
  u32 rb = (vb.i + 0x7FFF + ((vb.i>>16)&1)) & 0xFFFF0000u;
  return ra | rb;
}

// =============== x fp32 -> bf16 (RNE) ===============
__global__ __launch_bounds__(256) void to_bf16(const float* __restrict__ x, u32* __restrict__ xb, long n4){
  long i = (long)blockIdx.x*256 + threadIdx.x;   // one float4 -> one uint2
  if(i*4 >= n4*4) return;
  float4 v = ((const float4*)x)[i];
  uint2 o; o.x = pack2bf(v.x, v.y); o.y = pack2bf(v.z, v.w);
  ((uint2*)xb)[i] = o;
}

// =============== binned CSR build (counting sort by dst) ===============
__global__ __launch_bounds__(256) void hist_k(const int* __restrict__ dst, int* __restrict__ bcount,
                                              int E, int N, int NB){
  __shared__ int h[1024];
  for(int i=threadIdx.x; i<1024; i+=256) h[i]=0;
  __syncthreads();
  int e0 = blockIdx.x*8192;
  int e1 = min(e0+8192, E);
  for(int i=e0+threadIdx.x; i<e1; i+=256){
    int d = dst[i];
    if((u32)d >= (u32)N) d = 0;
    atomicAdd(&h[d>>6], 1);
  }
  __syncthreads();
  for(int i=threadIdx.x; i<NB; i+=256){
    int v = h[i];
    if(v) atomicAdd(&bcount[i], v);
  }
}

__global__ __launch_bounds__(256) void bucket_scan(const int* __restrict__ bcount, int* __restrict__ bstart,
                                                   int* __restrict__ bcursor, int* __restrict__ offs,
                                                   int NB, int N, int E){
  __shared__ int tsum[256];
  int t = threadIdx.x;
  int base = t*4;
  int a0 = (base+0<NB)?bcount[base+0]:0;
  int a1 = (base+1<NB)?bcount[base+1]:0;
  int a2 = (base+2<NB)?bcount[base+2]:0;
  int a3 = (base+3<NB)?bcount[base+3]:0;
  int s0=a0, s1=s0+a1, s2=s1+a2, s3=s2+a3;
  tsum[t]=s3; __syncthreads();
  #pragma unroll
  for(int d=1; d<256; d<<=1){
    int v = (t>=d)?tsum[t-d]:0;
    __syncthreads();
    tsum[t]+=v;
    __syncthreads();
  }
  int prev = (t>0)?tsum[t-1]:0;
  if(base+0<NB){ bstart[base+0]=prev;    bcursor[(base+0)*16]=0; }
  if(base+1<NB){ bstart[base+1]=prev+s0; bcursor[(base+1)*16]=0; }
  if(base+2<NB){ bstart[base+2]=prev+s1; bcursor[(base+2)*16]=0; }
  if(base+3<NB){ bstart[base+3]=prev+s2; bcursor[(base+3)*16]=0; }
  if(t==255){ bstart[NB]=prev+s3; offs[N]=E; }
}

__global__ __launch_bounds__(256) void binscatter2(const int* __restrict__ src, const int* __restrict__ dst,
                                                   const int* __restrict__ bstart, int* __restrict__ bcursor,
                                                   u32* __restrict__ pairs, int E, int N, int NB){
  __shared__ int hist[1024];
  __shared__ int base[1024];
  int e0 = blockIdx.x*8192;
  int e1 = min(e0+8192, E);
  for(int i=threadIdx.x; i<NB; i+=256) hist[i]=0;
  __syncthreads();
  for(int i=e0+threadIdx.x; i<e1; i+=256){
    int d = dst[i];
    if((u32)d >= (u32)N) d = 0;
    atomicAdd(&hist[d>>6], 1);
  }
  __syncthreads();
  for(int i=threadIdx.x; i<NB; i+=256){
    int c = hist[i];
    base[i] = c ? (bstart[i] + atomicAdd(&bcursor[i*16], c)) : 0;
    hist[i] = 0;
  }
  __syncthreads();
  for(int i=e0+threadIdx.x; i<e1; i+=256){
    int d = dst[i]; if((u32)d >= (u32)N) d = 0;
    int s = src[i]; if((u32)s >= (u32)N) s = 0;
    int b = d>>6;
    int loc = atomicAdd(&hist[b], 1);
    pairs[base[b]+loc] = (u32)s | (((u32)(d & 63))<<17);
  }
}

__global__ __launch_bounds__(256) void bucket_csr(const u32* __restrict__ pairs, const int* __restrict__ bstart,
                                                  int* __restrict__ offs, int* __restrict__ elist, int N){
  __shared__ int dcnt[64];
  __shared__ int dcur[64];
  int b = blockIdx.x;
  int p0 = bstart[b], p1 = bstart[b+1];
  if(threadIdx.x < 64) dcnt[threadIdx.x] = 0;
  __syncthreads();
  for(int i=p0+threadIdx.x; i<p1; i+=256){
    u32 u = pairs[i];
    atomicAdd(&dcnt[u>>17], 1);
  }
  __syncthreads();
  if(threadIdx.x == 0){
    int running = p0;
    #pragma unroll
    for(int j=0;j<64;j++){
      dcur[j] = running;
      int node = b*64 + j;
      if(node < N) offs[node] = running;
      running += dcnt[j];
    }
  }
  __syncthreads();
  for(int i=p0+threadIdx.x; i<p1; i+=256){
    u32 u = pairs[i];
    int pos = atomicAdd(&dcur[u>>17], 1);
    elist[pos] = (int)(u & 0x1FFFFu);
  }
}

// h0[i] = x[i] + sum_{j->i} x[j]  — bf16 gather, fp32 accumulate, bf16 out.
// 16 lanes per node row: lane chunk = 8 bf16 = 16 B. 16 rows per block.
__global__ __launch_bounds__(256) void gather_sum_bf(const u32* __restrict__ xb, const int* __restrict__ offs,
                                                     const int* __restrict__ elist, u32* __restrict__ h0b,
                                                     int N, int E){
  int slot = threadIdx.x >> 4;          // 0..15
  int c = threadIdx.x & 15;             // 16 B chunk of 256 B row
  int i = blockIdx.x*16 + slot;
  if(i >= N) return;
  const uint4* xr = (const uint4*)xb;   // row = 16 uint4s (128 bf16 = 64 u32)
  uint4 xv = xr[(size_t)i*16 + c];
  float acc[8] = {
    bf2f_lo(xv.x), bf2f_hi(xv.x), bf2f_lo(xv.y), bf2f_hi(xv.y),
    bf2f_lo(xv.z), bf2f_hi(xv.z), bf2f_lo(xv.w), bf2f_hi(xv.w) };
  int e0 = offs[i], e1 = offs[i+1];
  e0 = max(0, min(e0, E));
  e1 = max(e0, min(e1, E));
  for(int j=e0; j<e1; j++){
    int s = elist[j];
    if((u32)s >= (u32)N) s = 0;
    uint4 v = xr[(size_t)s*16 + c];
    acc[0]+=bf2f_lo(v.x); acc[1]+=bf2f_hi(v.x);
    acc[2]+=bf2f_lo(v.y); acc[3]+=bf2f_hi(v.y);
    acc[4]+=bf2f_lo(v.z); acc[5]+=bf2f_hi(v.z);
    acc[6]+=bf2f_lo(v.w); acc[7]+=bf2f_hi(v.w);
  }
  uint4 o;
  o.x = pack2bf(acc[0],acc[1]); o.y = pack2bf(acc[2],acc[3]);
  o.z = pack2bf(acc[4],acc[5]); o.w = pack2bf(acc[6],acc[7]);
  ((uint4*)h0b)[(size_t)i*16 + c] = o;
}

// =============== tiled GEMM: C[M,256] = op(A[M,K]) @ B[K,256] + bias ===============
// A fp32 or bf16 (ABF16), B/bias fp32, fp32 accumulate. tile 64x256, 8x8 micro-tile.
template<int K, bool BNA, bool RELUOUT, bool GATE, bool ABF16>
__global__ __launch_bounds__(256) void gemm_k(const void* __restrict__ Ap, const float* __restrict__ B,
                                              const float* __restrict__ bias,
                                              const float* __restrict__ scale, const float* __restrict__ shift,
                                              float* __restrict__ C, int M,
                                              const float* __restrict__ Wg, const float* __restrict__ bg,
                                              float* __restrict__ gate){
  __shared__ float As[16][64];
  __shared__ float Bs[16][256];
  const int tid = threadIdx.x;
  const int tn = tid & 31, tm = tid >> 5;
  const int m0 = blockIdx.x * 64;
  float acc[8][8];
  #pragma unroll
  for(int i=0;i<8;i++){
    #pragma unroll
    for(int j=0;j<8;j++) acc[i][j]=0.f;
  }
  const int arow = tid >> 2;          // 0..63
  const int akk  = (tid & 3)*4;       // 0,4,8,12
  const int brow = tid >> 6;          // 0..3
  const int bn4  = (tid & 63)*4;      // 0..252

  for(int k0=0; k0<K; k0+=16){
    float ax=0.f, ay=0.f, az=0.f, aw=0.f;
    if(m0 + arow < M){
      if(ABF16){
        uint2 a2 = *(const uint2*)((const u32*)Ap + ((size_t)(m0+arow)*K + k0 + akk)/2);
        ax=bf2f_lo(a2.x); ay=bf2f_hi(a2.x); az=bf2f_lo(a2.y); aw=bf2f_hi(a2.y);
      } else {
        float4 a4 = *(const float4*)((const float*)Ap + (size_t)(m0+arow)*K + k0 + akk);
        ax=a4.x; ay=a4.y; az=a4.z; aw=a4.w;
      }
    }
    if(BNA){
      float4 s4 = *(const float4*)(scale + k0 + akk);
      float4 t4 = *(const float4*)(shift + k0 + akk);
      ax = fmaxf(fmaf(s4.x, ax, t4.x), 0.f);
      ay = fmaxf(fmaf(s4.y, ay, t4.y), 0.f);
      az = fmaxf(fmaf(s4.z, az, t4.z), 0.f);
      aw = fmaxf(fmaf(s4.w, aw, t4.w), 0.f);
    }
    As[akk+0][arow]=ax; As[akk+1][arow]=ay; As[akk+2][arow]=az; As[akk+3][arow]=aw;
    #pragma unroll
    for(int p=0;p<4;p++){
      int kr = brow + p*4;
      *(float4*)&Bs[kr][bn4] = *(const float4*)(B + (size_t)(k0+kr)*256 + bn4);
    }
    __syncthreads();
    #pragma unroll
    for(int k=0;k<16;k++){
      float4 a0 = *(const float4*)&As[k][tm*4];
      float4 a1 = *(const float4*)&As[k][32 + tm*4];
      float4 b0 = *(const float4*)&Bs[k][tn*4];
      float4 b1 = *(const float4*)&Bs[k][128 + tn*4];
      float ar[8] = {a0.x,a0.y,a0.z,a0.w,a1.x,a1.y,a1.z,a1.w};
      float br[8] = {b0.x,b0.y,b0.z,b0.w,b1.x,b1.y,b1.z,b1.w};
      #pragma unroll
      for(int i=0;i<8;i++){
        #pragma unroll
        for(int j=0;j<8;j++) acc[i][j] = fmaf(ar[i], br[j], acc[i][j]);
      }
    }
    __syncthreads();
  }
  float bb[8];
  {
    float4 t0 = *(const float4*)(bias + tn*4);
    float4 t1 = *(const float4*)(bias + 128 + tn*4);
    bb[0]=t0.x; bb[1]=t0.y; bb[2]=t0.z; bb[3]=t0.w;
    bb[4]=t1.x; bb[5]=t1.y; bb[6]=t1.z; bb[7]=t1.w;
  }
  float wg[8];
  float bg0 = 0.f;
  if(GATE){
    float4 w0 = *(const float4*)(Wg + tn*4);
    float4 w1 = *(const float4*)(Wg + 128 + tn*4);
    wg[0]=w0.x; wg[1]=w0.y; wg[2]=w0.z; wg[3]=w0.w;
    wg[4]=w1.x; wg[5]=w1.y; wg[6]=w1.z; wg[7]=w1.w;
    bg0 = bg[0];
  }
  #pragma unroll
  for(int i=0;i<8;i++){
    int row = m0 + ((i<4) ? (tm*4+i) : (32 + tm*4 + (i-4)));
    if(row < M){
      float o[8];
      #pragma unroll
      for(int j=0;j<8;j++){
        o[j] = acc[i][j] + bb[j];
        if(RELUOUT) o[j] = fmaxf(o[j], 0.f);
      }
      float4 o0 = make_float4(o[0],o[1],o[2],o[3]);
      float4 o1 = make_float4(o[4],o[5],o[6],o[7]);
      *(float4*)(C + (size_t)row*256 + tn*4)       = o0;
      *(float4*)(C + (size_t)row*256 + 128 + tn*4) = o1;
      if(GATE){
        float p = 0.f;
        #pragma unroll
        for(int j=0;j<8;j++) p = fmaf(o[j], wg[j], p);
        #pragma unroll
        for(int d=16; d>0; d>>=1) p += __shfl_down(p, d, 32);
        if(tn==0) gate[row] = p + bg0;
      }
    }
  }
}

// =============== BN column stats: parallel partials ===============
__global__ __launch_bounds__(256) void col_stats2(const float* __restrict__ h, float* __restrict__ psum,
                                                  float* __restrict__ pq, int M, int rpb, int nblk){
  int b = blockIdx.x;
  int g = threadIdx.x >> 6;
  int lane = threadIdx.x & 63;
  int c0 = lane*4;
  int r0 = b*rpb;
  int r1 = min(r0+rpb, M);
  float4 s4 = make_float4(0.f,0.f,0.f,0.f);
  float4 q4 = make_float4(0.f,0.f,0.f,0.f);
  for(int r=r0+g; r<r1; r+=4){
    float4 v = *(const float4*)(h + (size_t)r*256 + c0);
    s4.x+=v.x; s4.y+=v.y; s4.z+=v.z; s4.w+=v.w;
    q4.x=fmaf(v.x,v.x,q4.x); q4.y=fmaf(v.y,v.y,q4.y);
    q4.z=fmaf(v.z,v.z,q4.z); q4.w=fmaf(v.w,v.w,q4.w);
  }
  __shared__ float ls[1024];
  __shared__ float lq[1024];
  *(float4*)&ls[g*256+c0] = s4;
  *(float4*)&lq[g*256+c0] = q4;
  __syncthreads();
  if(threadIdx.x < 64){
    #pragma unroll
    for(int j=0;j<4;j++){
      int c = c0+j;
      float s = ls[c]+ls[256+c]+ls[512+c]+ls[768+c];
      float q = lq[c]+lq[256+c]+lq[512+c]+lq[768+c];
      psum[(size_t)c*nblk + b] = s;
      pq[(size_t)c*nblk + b]   = q;
    }
  }
}

__global__ __launch_bounds__(512) void stats_fin(const float* __restrict__ psum, const float* __restrict__ pq,
                                                 const float* __restrict__ gamma, const float* __restrict__ beta,
                                                 float* __restrict__ scale, float* __restrict__ shift,
                                                 int nblk, float invM){
  __shared__ float red[512];
  int t = threadIdx.x;
  const float* src = (t<256) ? (psum + (size_t)t*nblk) : (pq + (size_t)(t-256)*nblk);
  float s = 0.f;
  for(int i=0;i<nblk;i+=4){
    float4 v = *(const float4*)(src+i);
    s += v.x+v.y+v.z+v.w;
  }
  red[t]=s; __syncthreads();
  if(t<256){
    float mu  = red[t]*invM;
    float var = fmaxf(red[256+t]*invM - mu*mu, 0.f);
    float sc  = gamma[t] * rsqrtf(var + 1e-5f);
    scale[t]=sc; shift[t]=fmaf(-mu, sc, beta[t]);
  }
}

// =============== attentional pool: one block per graph (batch sorted) ===============
__global__ __launch_bounds__(256) void pool_k(const float* __restrict__ h2, const float* __restrict__ gate,
                                              const int* __restrict__ batch, float* __restrict__ pooled, int N){
  int g = blockIdx.x;
  __shared__ int sb[2];
  __shared__ float red[4];
  __shared__ float s_m, s_inv;
  if(threadIdx.x < 2){
    int target = g + threadIdx.x;
    int lo=0, hi=N;
    while(lo<hi){ int mid=(lo+hi)>>1; if(batch[mid] < target) lo=mid+1; else hi=mid; }
    sb[threadIdx.x] = lo;
  }
  __syncthreads();
  int beg = sb[0], end = sb[1];
  float mx = -1e30f;
  for(int i=beg+threadIdx.x; i<end; i+=256) mx = fmaxf(mx, gate[i]);
  #pragma unroll
  for(int d=32; d>0; d>>=1) mx = fmaxf(mx, __shfl_down(mx, d, 64));
  if((threadIdx.x&63)==0) red[threadIdx.x>>6] = mx;
  __syncthreads();
  if(threadIdx.x==0) s_m = fmaxf(fmaxf(red[0],red[1]), fmaxf(red[2],red[3]));
  __syncthreads();
  float m = s_m;
  float s = 0.f;
  for(int i=beg+threadIdx.x; i<end; i+=256) s += expf(gate[i]-m);
  #pragma unroll
  for(int d=32; d>0; d>>=1) s += __shfl_down(s, d, 64);
  if((threadIdx.x&63)==0) red[threadIdx.x>>6] = s;
  __syncthreads();
  if(threadIdx.x==0){
    float tot = red[0]+red[1]+red[2]+red[3];
    s_inv = (tot > 0.f) ? 1.f/tot : 0.f;
  }
  __syncthreads();
  float inv = s_inv;
  int t = threadIdx.x;
  float acc = 0.f;
  for(int i=beg; i<end; i++){
    float a = expf(gate[i]-m) * inv;
    acc = fmaf(a, h2[(size_t)i*256 + t], acc);
  }
  pooled[g*256 + t] = acc;
}

// =============== head linear + log_softmax: one wave per graph ===============
__global__ __launch_bounds__(256) void head_k(const float* __restrict__ pooled,
                                              const float* __restrict__ sc2, const float* __restrict__ sh2,
                                              const float* __restrict__ Wh, const float* __restrict__ bh,
                                              float* __restrict__ out, int G){
  int w = (blockIdx.x*256 + threadIdx.x) >> 6;
  int l = threadIdx.x & 63;
  if(w >= G) return;
  float4 v  = *(const float4*)(pooled + (size_t)w*256 + l*4);
  float4 sc = *(const float4*)(sc2 + l*4);
  float4 sh = *(const float4*)(sh2 + l*4);
  float vv[4] = { fmaf(sc.x,v.x,sh.x), fmaf(sc.y,v.y,sh.y), fmaf(sc.z,v.z,sh.z), fmaf(sc.w,v.w,sh.w) };
  float4 w0 = *(const float4*)(Wh + (size_t)l*8);
  float4 w1 = *(const float4*)(Wh + (size_t)l*8 + 4);
  float a0 = vv[0]*w0.x + vv[1]*w0.z + vv[2]*w1.x + vv[3]*w1.z;
  float a1 = vv[0]*w0.y + vv[1]*w0.w + vv[2]*w1.y + vv[3]*w1.w;
  #pragma unroll
  for(int d=32; d>0; d>>=1){ a0 += __shfl_down(a0,d,64); a1 += __shfl_down(a1,d,64); }
  if(l==0){
    float z0 = a0 + bh[0];
    float z1 = a1 + bh[1];
    float mz = fmaxf(z0,z1);
    float lse = mz + logf(expf(z0-mz) + expf(z1-mz));
    out[w*2]   = z0 - lse;
    out[w*2+1] = z1 - lse;
  }
}

extern "C" void kernel_launch(void* const* d_in, const int* in_sizes, int n_in,
                              void* d_out, int out_size, void* d_ws, size_t ws_size,
                              hipStream_t stream){
  const float* x   = (const float*)d_in[0];
  const int*   ei  = (const int*)d_in[1];
  const int*   bat = (const int*)d_in[2];
  const float* W1  = (const float*)d_in[3];
  const float* b1  = (const float*)d_in[4];
  const float* g1  = (const float*)d_in[5];
  const float* be1 = (const float*)d_in[6];
  const float* W2  = (const float*)d_in[7];
  const float* b2  = (const float*)d_in[8];
  const float* Wg  = (const float*)d_in[9];
  const float* bg  = (const float*)d_in[10];
  const float* g2  = (const float*)d_in[11];
  const float* be2 = (const float*)d_in[12];
  const float* Wh  = (const float*)d_in[13];
  const float* bh  = (const float*)d_in[14];

  const int N = in_sizes[0] / 128;   // 50000
  const int E = in_sizes[1] / 2;     // 1600000
  const int G = out_size / 2;        // 512
  const int NB = (N + 63) >> 6;      // 782 buckets
  const int NBLK1 = 512;
  const int NBLK2 = 64;

  // ---- workspace layout ----
  // phase1 region [0, 51.2MB): h0b 12.8MB | xb 12.8MB | elist 6.4 | pairs 6.4 | offs | bins
  // phase2: h2 fp32 51.2MB overlays it. h1 fp32 at [51.2, 102.4).
  char* ws = (char*)d_ws;
  u32*   h0b    = (u32*)ws;                          // N*128*2 = 12,800,000 B (as u32 pairs)
  u32*   xb     = (u32*)(ws + 12800000);             // 12,800,000 B
  int*   elist  = (int*)(ws + 25600000);             //  6,400,000 B
  u32*   pairs  = (u32*)(ws + 32000000);             //  6,400,000 B
  int*   offs   = (int*)(ws + 38400000);             //    200,004 B
  int*   bcount = (int*)(ws + 38600192);             //      4,096 B
  int*   bstart = (int*)(ws + 38604288);             //      4,100 B
  int*   bcursor= (int*)(ws + 38608640);             //     65,536 B
  float* h2     = (float*)ws;                        // 51,200,000 B (phase2)
  float* h1     = (float*)(ws + 51200000);           // 51,200,000 B
  char*  p2 = ws + 102400000;
  float* psum1 = (float*)p2;          p2 += 256*NBLK1*4;
  float* pq1   = (float*)p2;          p2 += 256*NBLK1*4;
  float* psum2 = (float*)p2;          p2 += 256*NBLK2*4;
  float* pq2   = (float*)p2;          p2 += 256*NBLK2*4;
  float* sc1   = (float*)p2;          p2 += 1024;
  float* sh1   = (float*)p2;          p2 += 1024;
  float* gate  = (float*)p2;          p2 += (size_t)N*4 + 256;
  float* pooled= (float*)p2;          p2 += (size_t)G*256*4;
  float* sc2   = (float*)p2;          p2 += 1024;
  float* sh2   = (float*)p2;          p2 += 1024;

  const int* src = ei;
  const int* dst = ei + E;

  hipMemsetAsync(bcount, 0, (size_t)NB*4, stream);

  // CSR build + bf16 conversion (independent; conversion overlaps CSR kernels)
  int nchunk = (E + 8191)/8192;
  long n4 = (long)N*128/4;
  to_bf16    <<<(int)((n4+255)/256), 256, 0, stream>>>(x, xb, n4);
  hist_k     <<<nchunk, 256, 0, stream>>>(dst, bcount, E, N, NB);
  bucket_scan<<<1, 256, 0, stream>>>(bcount, bstart, bcursor, offs, NB, N, E);
  binscatter2<<<nchunk, 256, 0, stream>>>(src, dst, bstart, bcursor, pairs, E, N, NB);
  bucket_csr <<<NB, 256, 0, stream>>>(pairs, bstart, offs, elist, N);
  gather_sum_bf<<<(N+15)/16, 256, 0, stream>>>(xb, offs, elist, h0b, N, E);

  // MLP: gemm1 (bf16 A) -> BN stats -> gemm2 (fused BN+ReLU in, ReLU+gate out)
  gemm_k<128,false,false,false,true><<<(N+63)/64, 256, 0, stream>>>(h0b, W1, b1, nullptr, nullptr, h1, N, nullptr, nullptr, nullptr);
  int rpb1 = (N + NBLK1 - 1)/NBLK1;
  col_stats2 <<<NBLK1, 256, 0, stream>>>(h1, psum1, pq1, N, rpb1, NBLK1);
  stats_fin  <<<1, 512, 0, stream>>>(psum1, pq1, g1, be1, sc1, sh1, NBLK1, 1.0f/(float)N);
  gemm_k<256,true,true,true,false><<<(N+63)/64, 256, 0, stream>>>(h1, W2, b2, sc1, sh1, h2, N, Wg, bg, gate);

  // pooling + head
  pool_k <<<G, 256, 0, stream>>>(h2, gate, bat, pooled, N);
  int rpb2 = (G + NBLK2 - 1)/NBLK2;
  col_stats2 <<<NBLK2, 256, 0, stream>>>(pooled, psum2, pq2, G, rpb2, NBLK2);
  stats_fin  <<<1, 512, 0, stream>>>(psum2, pq2, g2, be2, sc2, sh2, NBLK2, 1.0f/(float)G);
  head_k <<<(G+3)/4, 256, 0, stream>>>(pooled, sc2, sh2, Wh, bh, (float*)d_out, G);
}

// Round 8
// 399.638 us; speedup vs baseline: 2.3773x; 1.2022x over previous
//
#include <hip/hip_runtime.h>

typedef unsigned int u32;
typedef unsigned short ushort_t;
typedef __attribute__((ext_vector_type(8))) short bf16x8;
typedef __attribute__((ext_vector_type(4))) float f32x4;

__device__ __forceinline__ float bf2f_lo(u32 u){
  union{u32 i; float f;} v; v.i = u<<16; return v.f;
}
__device__ __forceinline__ float bf2f_hi(u32 u){
  union{u32 i; float f;} v; v.i = u & 0xFFFF0000u; return v.f;
}
__device__ __forceinline__ u32 pack2bf(float a, float b){
  union{float f; u32 i;} va, vb; va.f=a; vb.f=b;
  u32 ra = (va.i + 0x7FFF + ((va.i>>16)&1)) >> 16;          // RNE
  u32 rb = (vb.i + 0x7FFF + ((vb.i>>16)&1)) & 0xFFFF0000u;
  return ra | rb;
}
__device__ __forceinline__ ushort_t f2bf1(float f){
  union{float f; u32 i;} v; v.f=f;
  u32 r = v.i + 0x7FFF + ((v.i>>16)&1);
  return (ushort_t)(r>>16);
}

// =============== x fp32 -> bf16 (RNE) ===============
__global__ __launch_bounds__(256) void to_bf16(const float* __restrict__ x, u32* __restrict__ xb, long n4){
  long i = (long)blockIdx.x*256 + threadIdx.x;
  if(i*4 >= n4*4) return;
  float4 v = ((const float4*)x)[i];
  uint2 o; o.x = pack2bf(v.x, v.y); o.y = pack2bf(v.z, v.w);
  ((uint2*)xb)[i] = o;
}

// =============== W[K x 256] fp32 -> Wt[256 x K] bf16 ===============
__global__ __launch_bounds__(256) void transpose_w(const float* __restrict__ W, ushort_t* __restrict__ Wt, int K){
  int n = blockIdx.x;  // 0..255
  for(int k = threadIdx.x; k < K; k += 256){
    Wt[(size_t)n*K + k] = f2bf1(W[(size_t)k*256 + n]);
  }
}

// =============== binned CSR build (counting sort by dst) ===============
__global__ __launch_bounds__(256) void hist_k(const int* __restrict__ dst, int* __restrict__ bcount,
                                              int E, int N, int NB){
  __shared__ int h[1024];
  for(int i=threadIdx.x; i<1024; i+=256) h[i]=0;
  __syncthreads();
  int e0 = blockIdx.x*8192;
  int e1 = min(e0+8192, E);
  for(int i=e0+threadIdx.x; i<e1; i+=256){
    int d = dst[i];
    if((u32)d >= (u32)N) d = 0;
    atomicAdd(&h[d>>6], 1);
  }
  __syncthreads();
  for(int i=threadIdx.x; i<NB; i+=256){
    int v = h[i];
    if(v) atomicAdd(&bcount[i], v);
  }
}

__global__ __launch_bounds__(256) void bucket_scan(const int* __restrict__ bcount, int* __restrict__ bstart,
                                                   int* __restrict__ bcursor, int* __restrict__ offs,
                                                   int NB, int N, int E){
  __shared__ int tsum[256];
  int t = threadIdx.x;
  int base = t*4;
  int a0 = (base+0<NB)?bcount[base+0]:0;
  int a1 = (base+1<NB)?bcount[base+1]:0;
  int a2 = (base+2<NB)?bcount[base+2]:0;
  int a3 = (base+3<NB)?bcount[base+3]:0;
  int s0=a0, s1=s0+a1, s2=s1+a2, s3=s2+a3;
  tsum[t]=s3; __syncthreads();
  #pragma unroll
  for(int d=1; d<256; d<<=1){
    int v = (t>=d)?tsum[t-d]:0;
    __syncthreads();
    tsum[t]+=v;
    __syncthreads();
  }
  int prev = (t>0)?tsum[t-1]:0;
  if(base+0<NB){ bstart[base+0]=prev;    bcursor[(base+0)*16]=0; }
  if(base+1<NB){ bstart[base+1]=prev+s0; bcursor[(base+1)*16]=0; }
  if(base+2<NB){ bstart[base+2]=prev+s1; bcursor[(base+2)*16]=0; }
  if(base+3<NB){ bstart[base+3]=prev+s2; bcursor[(base+3)*16]=0; }
  if(t==255){ bstart[NB]=prev+s3; offs[N]=E; }
}

__global__ __launch_bounds__(256) void binscatter2(const int* __restrict__ src, const int* __restrict__ dst,
                                                   const int* __restrict__ bstart, int* __restrict__ bcursor,
                                                   u32* __restrict__ pairs, int E, int N, int NB){
  __shared__ int hist[1024];
  __shared__ int base[1024];
  int e0 = blockIdx.x*8192;
  int e1 = min(e0+8192, E);
  for(int i=threadIdx.x; i<NB; i+=256) hist[i]=0;
  __syncthreads();
  for(int i=e0+threadIdx.x; i<e1; i+=256){
    int d = dst[i];
    if((u32)d >= (u32)N) d = 0;
    atomicAdd(&hist[d>>6], 1);
  }
  __syncthreads();
  for(int i=threadIdx.x; i<NB; i+=256){
    int c = hist[i];
    base[i] = c ? (bstart[i] + atomicAdd(&bcursor[i*16], c)) : 0;
    hist[i] = 0;
  }
  __syncthreads();
  for(int i=e0+threadIdx.x; i<e1; i+=256){
    int d = dst[i]; if((u32)d >= (u32)N) d = 0;
    int s = src[i]; if((u32)s >= (u32)N) s = 0;
    int b = d>>6;
    int loc = atomicAdd(&hist[b], 1);
    pairs[base[b]+loc] = (u32)s | (((u32)(d & 63))<<17);
  }
}

__global__ __launch_bounds__(256) void bucket_csr(const u32* __restrict__ pairs, const int* __restrict__ bstart,
                                                  int* __restrict__ offs, int* __restrict__ elist, int N){
  __shared__ int dcnt[64];
  __shared__ int dcur[64];
  int b = blockIdx.x;
  int p0 = bstart[b], p1 = bstart[b+1];
  if(threadIdx.x < 64) dcnt[threadIdx.x] = 0;
  __syncthreads();
  for(int i=p0+threadIdx.x; i<p1; i+=256){
    u32 u = pairs[i];
    atomicAdd(&dcnt[u>>17], 1);
  }
  __syncthreads();
  if(threadIdx.x == 0){
    int running = p0;
    #pragma unroll
    for(int j=0;j<64;j++){
      dcur[j] = running;
      int node = b*64 + j;
      if(node < N) offs[node] = running;
      running += dcnt[j];
    }
  }
  __syncthreads();
  for(int i=p0+threadIdx.x; i<p1; i+=256){
    u32 u = pairs[i];
    int pos = atomicAdd(&dcur[u>>17], 1);
    elist[pos] = (int)(u & 0x1FFFFu);
  }
}

// h0[i] = x[i] + sum_{j->i} x[j]  — bf16 gather, fp32 accumulate, bf16 out.
__global__ __launch_bounds__(256) void gather_sum_bf(const u32* __restrict__ xb, const int* __restrict__ offs,
                                                     const int* __restrict__ elist, u32* __restrict__ h0b,
                                                     int N, int E){
  int slot = threadIdx.x >> 4;
  int c = threadIdx.x & 15;
  int i = blockIdx.x*16 + slot;
  if(i >= N) return;
  const uint4* xr = (const uint4*)xb;
  uint4 xv = xr[(size_t)i*16 + c];
  float acc[8] = {
    bf2f_lo(xv.x), bf2f_hi(xv.x), bf2f_lo(xv.y), bf2f_hi(xv.y),
    bf2f_lo(xv.z), bf2f_hi(xv.z), bf2f_lo(xv.w), bf2f_hi(xv.w) };
  int e0 = offs[i], e1 = offs[i+1];
  e0 = max(0, min(e0, E));
  e1 = max(e0, min(e1, E));
  for(int j=e0; j<e1; j++){
    int s = elist[j];
    if((u32)s >= (u32)N) s = 0;
    uint4 v = xr[(size_t)s*16 + c];
    acc[0]+=bf2f_lo(v.x); acc[1]+=bf2f_hi(v.x);
    acc[2]+=bf2f_lo(v.y); acc[3]+=bf2f_hi(v.y);
    acc[4]+=bf2f_lo(v.z); acc[5]+=bf2f_hi(v.z);
    acc[6]+=bf2f_lo(v.w); acc[7]+=bf2f_hi(v.w);
  }
  uint4 o;
  o.x = pack2bf(acc[0],acc[1]); o.y = pack2bf(acc[2],acc[3]);
  o.z = pack2bf(acc[4],acc[5]); o.w = pack2bf(acc[6],acc[7]);
  ((uint4*)h0b)[(size_t)i*16 + c] = o;
}

// =============== MFMA bf16 GEMM: C[M,256] = op(A[M,K]) @ Wt^T + bias ===============
// Wt is [256][K] bf16 (B^T, k-contiguous). 512 threads = 8 waves; tile 128m x 256n, BK=64.
// Wave w: mhalf=w>>2, nq=w&3 -> 64x64 quadrant = 4x4 mfma_f32_16x16x32_bf16 tiles.
// LDS layout: 16B k-chunks [chunk][row] -> ds_read_b128 is 64 consecutive dwords (2-way, free).
template<int K, bool BNA, bool RELUOUT, bool GATE, bool ABF16>
__global__ __launch_bounds__(512) void gemm_mfma(const void* __restrict__ Ap, const ushort_t* __restrict__ Wt,
                                                 const float* __restrict__ bias,
                                                 const float* __restrict__ scale, const float* __restrict__ shift,
                                                 float* __restrict__ C, int M,
                                                 const float* __restrict__ Wg, const float* __restrict__ bg,
                                                 float* __restrict__ gate){
  __shared__ uint4 Al[8*128];   // 16 KB
  __shared__ uint4 Bl[8*256];   // 32 KB
  __shared__ float gacc[128];
  const int tid  = threadIdx.x;
  const int lane = tid & 63;
  const int wave = tid >> 6;
  const int lm   = lane & 15;
  const int q    = lane >> 4;          // 0..3
  const int mhalf= wave >> 2;          // 0..1
  const int nq   = wave & 3;           // 0..3
  const int m0   = blockIdx.x * 128;

  if(GATE && tid < 128) gacc[tid] = 0.f;

  f32x4 acc[4][4];
  #pragma unroll
  for(int i=0;i<4;i++)
    #pragma unroll
    for(int j=0;j<4;j++) acc[i][j] = (f32x4){0.f,0.f,0.f,0.f};

  for(int k0=0; k0<K; k0+=64){
    // ---- stage A: 1024 chunks (128 rows x 8 chunks of 8 bf16) ----
    #pragma unroll
    for(int i=0;i<2;i++){
      int idx = tid*2 + i;
      int m = idx >> 3, c = idx & 7;
      int grow = m0 + m;
      int kk = k0 + c*8;
      uint4 v = make_uint4(0,0,0,0);
      if(ABF16){
        if(grow < M) v = *(const uint4*)((const ushort_t*)Ap + (size_t)grow*K + kk);
      } else {
        float4 u0 = make_float4(0,0,0,0), u1 = make_float4(0,0,0,0);
        if(grow < M){
          u0 = *(const float4*)((const float*)Ap + (size_t)grow*K + kk);
          u1 = *(const float4*)((const float*)Ap + (size_t)grow*K + kk + 4);
        }
        if(BNA){
          float4 s0 = *(const float4*)(scale+kk),  s1 = *(const float4*)(scale+kk+4);
          float4 t0 = *(const float4*)(shift+kk),  t1 = *(const float4*)(shift+kk+4);
          u0.x=fmaxf(fmaf(s0.x,u0.x,t0.x),0.f); u0.y=fmaxf(fmaf(s0.y,u0.y,t0.y),0.f);
          u0.z=fmaxf(fmaf(s0.z,u0.z,t0.z),0.f); u0.w=fmaxf(fmaf(s0.w,u0.w,t0.w),0.f);
          u1.x=fmaxf(fmaf(s1.x,u1.x,t1.x),0.f); u1.y=fmaxf(fmaf(s1.y,u1.y,t1.y),0.f);
          u1.z=fmaxf(fmaf(s1.z,u1.z,t1.z),0.f); u1.w=fmaxf(fmaf(s1.w,u1.w,t1.w),0.f);
        }
        v.x = pack2bf(u0.x,u0.y); v.y = pack2bf(u0.z,u0.w);
        v.z = pack2bf(u1.x,u1.y); v.w = pack2bf(u1.z,u1.w);
      }
      Al[c*128 + m] = v;
    }
    // ---- stage B: 2048 chunks (256 n-rows x 8 chunks) ----
    #pragma unroll
    for(int i=0;i<4;i++){
      int idx = tid*4 + i;
      int n = idx >> 3, c = idx & 7;
      Bl[c*256 + n] = *(const uint4*)(Wt + (size_t)n*K + k0 + c*8);
    }
    __syncthreads();
    #pragma unroll
    for(int ks=0; ks<2; ks++){
      int cc = ks*4 + q;
      bf16x8 af[4], bfr[4];
      #pragma unroll
      for(int mi=0; mi<4; mi++)
        af[mi] = *((const bf16x8*)&Al[cc*128 + mhalf*64 + mi*16 + lm]);
      #pragma unroll
      for(int ni=0; ni<4; ni++)
        bfr[ni] = *((const bf16x8*)&Bl[cc*256 + nq*64 + ni*16 + lm]);
      #pragma unroll
      for(int mi=0; mi<4; mi++)
        #pragma unroll
        for(int ni=0; ni<4; ni++)
          acc[mi][ni] = __builtin_amdgcn_mfma_f32_16x16x32_bf16(af[mi], bfr[ni], acc[mi][ni], 0, 0, 0);
    }
    __syncthreads();
  }

  // ---- epilogue ----
  float bb[4], wgv[4];
  #pragma unroll
  for(int ni=0; ni<4; ni++){
    int col = nq*64 + ni*16 + lm;
    bb[ni] = bias[col];
    if(GATE) wgv[ni] = Wg[col];
  }
  #pragma unroll
  for(int mi=0; mi<4; mi++){
    int rowloc0 = mhalf*64 + mi*16 + q*4;
    float gp[4] = {0.f,0.f,0.f,0.f};
    #pragma unroll
    for(int ni=0; ni<4; ni++){
      int col = nq*64 + ni*16 + lm;
      f32x4 o = acc[mi][ni];
      #pragma unroll
      for(int r=0; r<4; r++){
        float v = o[r] + bb[ni];
        if(RELUOUT) v = fmaxf(v, 0.f);
        int row = m0 + rowloc0 + r;
        if(row < M) C[(size_t)row*256 + col] = v;
        if(GATE) gp[r] = fmaf(v, wgv[ni], gp[r]);
      }
    }
    if(GATE){
      #pragma unroll
      for(int r=0; r<4; r++){
        if(m0 + rowloc0 + r < M) atomicAdd(&gacc[rowloc0 + r], gp[r]);
      }
    }
  }
  if(GATE){
    __syncthreads();
    if(tid < 128){
      int row = m0 + tid;
      if(row < M) gate[row] = gacc[tid] + bg[0];
    }
  }
}

// =============== BN column stats: parallel partials ===============
__global__ __launch_bounds__(256) void col_stats2(const float* __restrict__ h, float* __restrict__ psum,
                                                  float* __restrict__ pq, int M, int rpb, int nblk){
  int b = blockIdx.x;
  int g = threadIdx.x >> 6;
  int lane = threadIdx.x & 63;
  int c0 = lane*4;
  int r0 = b*rpb;
  int r1 = min(r0+rpb, M);
  float4 s4 = make_float4(0.f,0.f,0.f,0.f);
  float4 q4 = make_float4(0.f,0.f,0.f,0.f);
  for(int r=r0+g; r<r1; r+=4){
    float4 v = *(const float4*)(h + (size_t)r*256 + c0);
    s4.x+=v.x; s4.y+=v.y; s4.z+=v.z; s4.w+=v.w;
    q4.x=fmaf(v.x,v.x,q4.x); q4.y=fmaf(v.y,v.y,q4.y);
    q4.z=fmaf(v.z,v.z,q4.z); q4.w=fmaf(v.w,v.w,q4.w);
  }
  __shared__ float ls[1024];
  __shared__ float lq[1024];
  *(float4*)&ls[g*256+c0] = s4;
  *(float4*)&lq[g*256+c0] = q4;
  __syncthreads();
  if(threadIdx.x < 64){
    #pragma unroll
    for(int j=0;j<4;j++){
      int c = c0+j;
      float s = ls[c]+ls[256+c]+ls[512+c]+ls[768+c];
      float q = lq[c]+lq[256+c]+lq[512+c]+lq[768+c];
      psum[(size_t)c*nblk + b] = s;
      pq[(size_t)c*nblk + b]   = q;
    }
  }
}

__global__ __launch_bounds__(512) void stats_fin(const float* __restrict__ psum, const float* __restrict__ pq,
                                                 const float* __restrict__ gamma, const float* __restrict__ beta,
                                                 float* __restrict__ scale, float* __restrict__ shift,
                                                 int nblk, float invM){
  __shared__ float red[512];
  int t = threadIdx.x;
  const float* src = (t<256) ? (psum + (size_t)t*nblk) : (pq + (size_t)(t-256)*nblk);
  float s = 0.f;
  for(int i=0;i<nblk;i+=4){
    float4 v = *(const float4*)(src+i);
    s += v.x+v.y+v.z+v.w;
  }
  red[t]=s; __syncthreads();
  if(t<256){
    float mu  = red[t]*invM;
    float var = fmaxf(red[256+t]*invM - mu*mu, 0.f);
    float sc  = gamma[t] * rsqrtf(var + 1e-5f);
    scale[t]=sc; shift[t]=fmaf(-mu, sc, beta[t]);
  }
}

// =============== attentional pool: one block per graph (batch sorted) ===============
__global__ __launch_bounds__(256) void pool_k(const float* __restrict__ h2, const float* __restrict__ gate,
                                              const int* __restrict__ batch, float* __restrict__ pooled, int N){
  int g = blockIdx.x;
  __shared__ int sb[2];
  __shared__ float red[4];
  __shared__ float s_m, s_inv;
  if(threadIdx.x < 2){
    int target = g + threadIdx.x;
    int lo=0, hi=N;
    while(lo<hi){ int mid=(lo+hi)>>1; if(batch[mid] < target) lo=mid+1; else hi=mid; }
    sb[threadIdx.x] = lo;
  }
  __syncthreads();
  int beg = sb[0], end = sb[1];
  float mx = -1e30f;
  for(int i=beg+threadIdx.x; i<end; i+=256) mx = fmaxf(mx, gate[i]);
  #pragma unroll
  for(int d=32; d>0; d>>=1) mx = fmaxf(mx, __shfl_down(mx, d, 64));
  if((threadIdx.x&63)==0) red[threadIdx.x>>6] = mx;
  __syncthreads();
  if(threadIdx.x==0) s_m = fmaxf(fmaxf(red[0],red[1]), fmaxf(red[2],red[3]));
  __syncthreads();
  float m = s_m;
  float s = 0.f;
  for(int i=beg+threadIdx.x; i<end; i+=256) s += expf(gate[i]-m);
  #pragma unroll
  for(int d=32; d>0; d>>=1) s += __shfl_down(s, d, 64);
  if((threadIdx.x&63)==0) red[threadIdx.x>>6] = s;
  __syncthreads();
  if(threadIdx.x==0){
    float tot = red[0]+red[1]+red[2]+red[3];
    s_inv = (tot > 0.f) ? 1.f/tot : 0.f;
  }
  __syncthreads();
  float inv = s_inv;
  int t = threadIdx.x;
  float acc = 0.f;
  for(int i=beg; i<end; i++){
    float a = expf(gate[i]-m) * inv;
    acc = fmaf(a, h2[(size_t)i*256 + t], acc);
  }
  pooled[g*256 + t] = acc;
}

// =============== head linear + log_softmax: one wave per graph ===============
__global__ __launch_bounds__(256) void head_k(const float* __restrict__ pooled,
                                              const float* __restrict__ sc2, const float* __restrict__ sh2,
                                              const float* __restrict__ Wh, const float* __restrict__ bh,
                                              float* __restrict__ out, int G){
  int w = (blockIdx.x*256 + threadIdx.x) >> 6;
  int l = threadIdx.x & 63;
  if(w >= G) return;
  float4 v  = *(const float4*)(pooled + (size_t)w*256 + l*4);
  float4 sc = *(const float4*)(sc2 + l*4);
  float4 sh = *(const float4*)(sh2 + l*4);
  float vv[4] = { fmaf(sc.x,v.x,sh.x), fmaf(sc.y,v.y,sh.y), fmaf(sc.z,v.z,sh.z), fmaf(sc.w,v.w,sh.w) };
  float4 w0 = *(const float4*)(Wh + (size_t)l*8);
  float4 w1 = *(const float4*)(Wh + (size_t)l*8 + 4);
  float a0 = vv[0]*w0.x + vv[1]*w0.z + vv[2]*w1.x + vv[3]*w1.z;
  float a1 = vv[0]*w0.y + vv[1]*w0.w + vv[2]*w1.y + vv[3]*w1.w;
  #pragma unroll
  for(int d=32; d>0; d>>=1){ a0 += __shfl_down(a0,d,64); a1 += __shfl_down(a1,d,64); }
  if(l==0){
    float z0 = a0 + bh[0];
    float z1 = a1 + bh[1];
    float mz = fmaxf(z0,z1);
    float lse = mz + logf(expf(z0-mz) + expf(z1-mz));
    out[w*2]   = z0 - lse;
    out[w*2+1] = z1 - lse;
  }
}

extern "C" void kernel_launch(void* const* d_in, const int* in_sizes, int n_in,
                              void* d_out, int out_size, void* d_ws, size_t ws_size,
                              hipStream_t stream){
  const float* x   = (const float*)d_in[0];
  const int*   ei  = (const int*)d_in[1];
  const int*   bat = (const int*)d_in[2];
  const float* W1  = (const float*)d_in[3];
  const float* b1  = (const float*)d_in[4];
  const float* g1  = (const float*)d_in[5];
  const float* be1 = (const float*)d_in[6];
  const float* W2  = (const float*)d_in[7];
  const float* b2  = (const float*)d_in[8];
  const float* Wg  = (const float*)d_in[9];
  const float* bg  = (const float*)d_in[10];
  const float* g2  = (const float*)d_in[11];
  const float* be2 = (const float*)d_in[12];
  const float* Wh  = (const float*)d_in[13];
  const float* bh  = (const float*)d_in[14];

  const int N = in_sizes[0] / 128;   // 50000
  const int E = in_sizes[1] / 2;     // 1600000
  const int G = out_size / 2;        // 512
  const int NB = (N + 63) >> 6;
  const int NBLK1 = 512;
  const int NBLK2 = 64;

  // ---- workspace layout ----
  char* ws = (char*)d_ws;
  u32*   h0b    = (u32*)ws;                          // 12,800,000 B
  u32*   xb     = (u32*)(ws + 12800000);             // 12,800,000 B
  int*   elist  = (int*)(ws + 25600000);             //  6,400,000 B
  u32*   pairs  = (u32*)(ws + 32000000);             //  6,400,000 B
  int*   offs   = (int*)(ws + 38400000);             //    200,004 B
  int*   bcount = (int*)(ws + 38600192);             //      4,096 B
  int*   bstart = (int*)(ws + 38604288);             //      4,100 B
  int*   bcursor= (int*)(ws + 38608640);             //     65,536 B
  float* h2     = (float*)ws;                        // 51,200,000 B (phase2)
  float* h1     = (float*)(ws + 51200000);           // 51,200,000 B
  char*  p2 = ws + 102400000;
  float* psum1 = (float*)p2;          p2 += 256*NBLK1*4;
  float* pq1   = (float*)p2;          p2 += 256*NBLK1*4;
  float* psum2 = (float*)p2;          p2 += 256*NBLK2*4;
  float* pq2   = (float*)p2;          p2 += 256*NBLK2*4;
  float* sc1   = (float*)p2;          p2 += 1024;
  float* sh1   = (float*)p2;          p2 += 1024;
  float* gate  = (float*)p2;          p2 += (size_t)N*4 + 256;
  float* pooled= (float*)p2;          p2 += (size_t)G*256*4;
  float* sc2   = (float*)p2;          p2 += 1024;
  float* sh2   = (float*)p2;          p2 += 1024;
  ushort_t* W1t = (ushort_t*)p2;      p2 += 256*128*2;   // 64 KB
  ushort_t* W2t = (ushort_t*)p2;      p2 += 256*256*2;   // 128 KB

  const int* src = ei;
  const int* dst = ei + E;

  hipMemsetAsync(bcount, 0, (size_t)NB*4, stream);

  // weight transposes + x conversion (independent of CSR chain)
  transpose_w<<<256, 256, 0, stream>>>(W1, W1t, 128);
  transpose_w<<<256, 256, 0, stream>>>(W2, W2t, 256);
  long n4 = (long)N*128/4;
  to_bf16    <<<(int)((n4+255)/256), 256, 0, stream>>>(x, xb, n4);

  // CSR build via block-aggregated binned counting sort
  int nchunk = (E + 8191)/8192;
  hist_k     <<<nchunk, 256, 0, stream>>>(dst, bcount, E, N, NB);
  bucket_scan<<<1, 256, 0, stream>>>(bcount, bstart, bcursor, offs, NB, N, E);
  binscatter2<<<nchunk, 256, 0, stream>>>(src, dst, bstart, bcursor, pairs, E, N, NB);
  bucket_csr <<<NB, 256, 0, stream>>>(pairs, bstart, offs, elist, N);
  gather_sum_bf<<<(N+15)/16, 256, 0, stream>>>(xb, offs, elist, h0b, N, E);

  // MLP: gemm1 (bf16 A, MFMA) -> BN stats -> gemm2 (BN+ReLU staged, MFMA, gate fused)
  int gblocks = (N + 127)/128;
  gemm_mfma<128,false,false,false,true><<<gblocks, 512, 0, stream>>>(
      h0b, W1t, b1, nullptr, nullptr, h1, N, nullptr, nullptr, nullptr);
  int rpb1 = (N + NBLK1 - 1)/NBLK1;
  col_stats2 <<<NBLK1, 256, 0, stream>>>(h1, psum1, pq1, N, rpb1, NBLK1);
  stats_fin  <<<1, 512, 0, stream>>>(psum1, pq1, g1, be1, sc1, sh1, NBLK1, 1.0f/(float)N);
  gemm_mfma<256,true,true,true,false><<<gblocks, 512, 0, stream>>>(
      h1, W2t, b2, sc1, sh1, h2, N, Wg, bg, gate);

  // pooling + head
  pool_k <<<G, 256, 0, stream>>>(h2, gate, bat, pooled, N);
  int rpb2 = (G + NBLK2 - 1)/NBLK2;
  col_stats2 <<<NBLK2, 256, 0, stream>>>(pooled, psum2, pq2, G, rpb2, NBLK2);
  stats_fin  <<<1, 512, 0, stream>>>(psum2, pq2, g2, be2, sc2, sh2, NBLK2, 1.0f/(float)G);
  head_k <<<(G+3)/4, 256, 0, stream>>>(pooled, sc2, sh2, Wh, bh, (float*)d_out, G);
}

// Round 9
// 371.897 us; speedup vs baseline: 2.5547x; 1.0746x over previous
//
#include <hip/hip_runtime.h>

typedef unsigned int u32;
typedef unsigned short ushort_t;
typedef __attribute__((ext_vector_type(8))) short bf16x8;
typedef __attribute__((ext_vector_type(4))) float f32x4;

__device__ __forceinline__ float bf2f_lo(u32 u){
  union{u32 i; float f;} v; v.i = u<<16; return v.f;
}
__device__ __forceinline__ float bf2f_hi(u32 u){
  union{u32 i; float f;} v; v.i = u & 0xFFFF0000u; return v.f;
}
__device__ __forceinline__ float bf2f_s(ushort_t u){
  union{u32 i; float f;} v; v.i = ((u32)u)<<16; return v.f;
}
__device__ __forceinline__ u32 pack2bf(float a, float b){
  union{float f; u32 i;} va, vb; va.f=a; vb.f=b;
  u32 ra = (va.i + 0x7FFF + ((va.i>>16)&1)) >> 16;          // RNE
  u32 rb = (vb.i + 0x7FFF + ((vb.i>>16)&1)) & 0xFFFF0000u;
  return ra | rb;
}
__device__ __forceinline__ ushort_t f2bf1(float f){
  union{float f; u32 i;} v; v.f=f;
  u32 r = v.i + 0x7FFF + ((v.i>>16)&1);
  return (ushort_t)(r>>16);
}

// =============== x fp32 -> bf16 (RNE) ===============
__global__ __launch_bounds__(256) void to_bf16(const float* __restrict__ x, u32* __restrict__ xb, long n4){
  long i = (long)blockIdx.x*256 + threadIdx.x;
  if(i*4 >= n4*4) return;
  float4 v = ((const float4*)x)[i];
  uint2 o; o.x = pack2bf(v.x, v.y); o.y = pack2bf(v.z, v.w);
  ((uint2*)xb)[i] = o;
}

// =============== W[K x 256] fp32 -> Wt[256 x K] bf16 ===============
__global__ __launch_bounds__(256) void transpose_w(const float* __restrict__ W, ushort_t* __restrict__ Wt, int K){
  int n = blockIdx.x;
  for(int k = threadIdx.x; k < K; k += 256){
    Wt[(size_t)n*K + k] = f2bf1(W[(size_t)k*256 + n]);
  }
}

// =============== binned CSR build (counting sort by dst) ===============
__global__ __launch_bounds__(256) void hist_k(const int* __restrict__ dst, int* __restrict__ bcount,
                                              int E, int N, int NB){
  __shared__ int h[1024];
  for(int i=threadIdx.x; i<1024; i+=256) h[i]=0;
  __syncthreads();
  int e0 = blockIdx.x*8192;
  int e1 = min(e0+8192, E);
  for(int i=e0+threadIdx.x; i<e1; i+=256){
    int d = dst[i];
    if((u32)d >= (u32)N) d = 0;
    atomicAdd(&h[d>>6], 1);
  }
  __syncthreads();
  for(int i=threadIdx.x; i<NB; i+=256){
    int v = h[i];
    if(v) atomicAdd(&bcount[i], v);
  }
}

__global__ __launch_bounds__(256) void bucket_scan(const int* __restrict__ bcount, int* __restrict__ bstart,
                                                   int* __restrict__ bcursor, int* __restrict__ offs,
                                                   int NB, int N, int E){
  __shared__ int tsum[256];
  int t = threadIdx.x;
  int base = t*4;
  int a0 = (base+0<NB)?bcount[base+0]:0;
  int a1 = (base+1<NB)?bcount[base+1]:0;
  int a2 = (base+2<NB)?bcount[base+2]:0;
  int a3 = (base+3<NB)?bcount[base+3]:0;
  int s0=a0, s1=s0+a1, s2=s1+a2, s3=s2+a3;
  tsum[t]=s3; __syncthreads();
  #pragma unroll
  for(int d=1; d<256; d<<=1){
    int v = (t>=d)?tsum[t-d]:0;
    __syncthreads();
    tsum[t]+=v;
    __syncthreads();
  }
  int prev = (t>0)?tsum[t-1]:0;
  if(base+0<NB){ bstart[base+0]=prev;    bcursor[(base+0)*16]=0; }
  if(base+1<NB){ bstart[base+1]=prev+s0; bcursor[(base+1)*16]=0; }
  if(base+2<NB){ bstart[base+2]=prev+s1; bcursor[(base+2)*16]=0; }
  if(base+3<NB){ bstart[base+3]=prev+s2; bcursor[(base+3)*16]=0; }
  if(t==255){ bstart[NB]=prev+s3; offs[N]=E; }
}

__global__ __launch_bounds__(256) void binscatter2(const int* __restrict__ src, const int* __restrict__ dst,
                                                   const int* __restrict__ bstart, int* __restrict__ bcursor,
                                                   u32* __restrict__ pairs, int E, int N, int NB){
  __shared__ int hist[1024];
  __shared__ int base[1024];
  int e0 = blockIdx.x*8192;
  int e1 = min(e0+8192, E);
  for(int i=threadIdx.x; i<NB; i+=256) hist[i]=0;
  __syncthreads();
  for(int i=e0+threadIdx.x; i<e1; i+=256){
    int d = dst[i];
    if((u32)d >= (u32)N) d = 0;
    atomicAdd(&hist[d>>6], 1);
  }
  __syncthreads();
  for(int i=threadIdx.x; i<NB; i+=256){
    int c = hist[i];
    base[i] = c ? (bstart[i] + atomicAdd(&bcursor[i*16], c)) : 0;
    hist[i] = 0;
  }
  __syncthreads();
  for(int i=e0+threadIdx.x; i<e1; i+=256){
    int d = dst[i]; if((u32)d >= (u32)N) d = 0;
    int s = src[i]; if((u32)s >= (u32)N) s = 0;
    int b = d>>6;
    int loc = atomicAdd(&hist[b], 1);
    pairs[base[b]+loc] = (u32)s | (((u32)(d & 63))<<17);
  }
}

__global__ __launch_bounds__(256) void bucket_csr(const u32* __restrict__ pairs, const int* __restrict__ bstart,
                                                  int* __restrict__ offs, int* __restrict__ elist, int N){
  __shared__ int dcnt[64];
  __shared__ int dcur[64];
  int b = blockIdx.x;
  int p0 = bstart[b], p1 = bstart[b+1];
  if(threadIdx.x < 64) dcnt[threadIdx.x] = 0;
  __syncthreads();
  for(int i=p0+threadIdx.x; i<p1; i+=256){
    u32 u = pairs[i];
    atomicAdd(&dcnt[u>>17], 1);
  }
  __syncthreads();
  if(threadIdx.x == 0){
    int running = p0;
    #pragma unroll
    for(int j=0;j<64;j++){
      dcur[j] = running;
      int node = b*64 + j;
      if(node < N) offs[node] = running;
      running += dcnt[j];
    }
  }
  __syncthreads();
  for(int i=p0+threadIdx.x; i<p1; i+=256){
    u32 u = pairs[i];
    int pos = atomicAdd(&dcur[u>>17], 1);
    elist[pos] = (int)(u & 0x1FFFFu);
  }
}

// h0[i] = x[i] + sum_{j->i} x[j]  — bf16 gather, fp32 accumulate, bf16 out.
// 16 lanes per row chunk; edge loop unrolled x4 for memory-level parallelism.
__global__ __launch_bounds__(256) void gather_sum_bf(const u32* __restrict__ xb, const int* __restrict__ offs,
                                                     const int* __restrict__ elist, u32* __restrict__ h0b,
                                                     int N, int E){
  int slot = threadIdx.x >> 4;
  int c = threadIdx.x & 15;
  int i = blockIdx.x*16 + slot;
  if(i >= N) return;
  const uint4* xr = (const uint4*)xb;
  uint4 xv = xr[(size_t)i*16 + c];
  float acc[8] = {
    bf2f_lo(xv.x), bf2f_hi(xv.x), bf2f_lo(xv.y), bf2f_hi(xv.y),
    bf2f_lo(xv.z), bf2f_hi(xv.z), bf2f_lo(xv.w), bf2f_hi(xv.w) };
  int e0 = offs[i], e1 = offs[i+1];
  e0 = max(0, min(e0, E));
  e1 = max(e0, min(e1, E));
  int j = e0;
  for(; j+4 <= e1; j += 4){
    int s0 = elist[j+0]; if((u32)s0 >= (u32)N) s0 = 0;
    int s1 = elist[j+1]; if((u32)s1 >= (u32)N) s1 = 0;
    int s2 = elist[j+2]; if((u32)s2 >= (u32)N) s2 = 0;
    int s3 = elist[j+3]; if((u32)s3 >= (u32)N) s3 = 0;
    uint4 v0 = xr[(size_t)s0*16 + c];
    uint4 v1 = xr[(size_t)s1*16 + c];
    uint4 v2 = xr[(size_t)s2*16 + c];
    uint4 v3 = xr[(size_t)s3*16 + c];
    acc[0]+=bf2f_lo(v0.x); acc[1]+=bf2f_hi(v0.x); acc[2]+=bf2f_lo(v0.y); acc[3]+=bf2f_hi(v0.y);
    acc[4]+=bf2f_lo(v0.z); acc[5]+=bf2f_hi(v0.z); acc[6]+=bf2f_lo(v0.w); acc[7]+=bf2f_hi(v0.w);
    acc[0]+=bf2f_lo(v1.x); acc[1]+=bf2f_hi(v1.x); acc[2]+=bf2f_lo(v1.y); acc[3]+=bf2f_hi(v1.y);
    acc[4]+=bf2f_lo(v1.z); acc[5]+=bf2f_hi(v1.z); acc[6]+=bf2f_lo(v1.w); acc[7]+=bf2f_hi(v1.w);
    acc[0]+=bf2f_lo(v2.x); acc[1]+=bf2f_hi(v2.x); acc[2]+=bf2f_lo(v2.y); acc[3]+=bf2f_hi(v2.y);
    acc[4]+=bf2f_lo(v2.z); acc[5]+=bf2f_hi(v2.z); acc[6]+=bf2f_lo(v2.w); acc[7]+=bf2f_hi(v2.w);
    acc[0]+=bf2f_lo(v3.x); acc[1]+=bf2f_hi(v3.x); acc[2]+=bf2f_lo(v3.y); acc[3]+=bf2f_hi(v3.y);
    acc[4]+=bf2f_lo(v3.z); acc[5]+=bf2f_hi(v3.z); acc[6]+=bf2f_lo(v3.w); acc[7]+=bf2f_hi(v3.w);
  }
  for(; j < e1; j++){
    int s = elist[j];
    if((u32)s >= (u32)N) s = 0;
    uint4 v = xr[(size_t)s*16 + c];
    acc[0]+=bf2f_lo(v.x); acc[1]+=bf2f_hi(v.x);
    acc[2]+=bf2f_lo(v.y); acc[3]+=bf2f_hi(v.y);
    acc[4]+=bf2f_lo(v.z); acc[5]+=bf2f_hi(v.z);
    acc[6]+=bf2f_lo(v.w); acc[7]+=bf2f_hi(v.w);
  }
  uint4 o;
  o.x = pack2bf(acc[0],acc[1]); o.y = pack2bf(acc[2],acc[3]);
  o.z = pack2bf(acc[4],acc[5]); o.w = pack2bf(acc[6],acc[7]);
  ((uint4*)h0b)[(size_t)i*16 + c] = o;
}

// =============== MFMA bf16 GEMM: C[M,256] = op(A[M,K]) @ Wt^T + bias ===============
// Wt is [256][K] bf16 (B^T, k-contiguous). 512 threads = 8 waves; tile 128m x 256n, BK=64.
// OUTBF16: write C as bf16 (ushort) instead of fp32.
template<int K, bool BNA, bool RELUOUT, bool GATE, bool ABF16, bool OUTBF16>
__global__ __launch_bounds__(512) void gemm_mfma(const void* __restrict__ Ap, const ushort_t* __restrict__ Wt,
                                                 const float* __restrict__ bias,
                                                 const float* __restrict__ scale, const float* __restrict__ shift,
                                                 void* __restrict__ Cp, int M,
                                                 const float* __restrict__ Wg, const float* __restrict__ bg,
                                                 float* __restrict__ gate){
  __shared__ uint4 Al[8*128];   // 16 KB
  __shared__ uint4 Bl[8*256];   // 32 KB
  __shared__ float gacc[128];
  const int tid  = threadIdx.x;
  const int lane = tid & 63;
  const int wave = tid >> 6;
  const int lm   = lane & 15;
  const int q    = lane >> 4;
  const int mhalf= wave >> 2;
  const int nq   = wave & 3;
  const int m0   = blockIdx.x * 128;

  if(GATE && tid < 128) gacc[tid] = 0.f;

  f32x4 acc[4][4];
  #pragma unroll
  for(int i=0;i<4;i++)
    #pragma unroll
    for(int j=0;j<4;j++) acc[i][j] = (f32x4){0.f,0.f,0.f,0.f};

  for(int k0=0; k0<K; k0+=64){
    #pragma unroll
    for(int i=0;i<2;i++){
      int idx = tid*2 + i;
      int m = idx >> 3, c = idx & 7;
      int grow = m0 + m;
      int kk = k0 + c*8;
      uint4 v = make_uint4(0,0,0,0);
      if(ABF16){
        if(grow < M) v = *(const uint4*)((const ushort_t*)Ap + (size_t)grow*K + kk);
      } else {
        float4 u0 = make_float4(0,0,0,0), u1 = make_float4(0,0,0,0);
        if(grow < M){
          u0 = *(const float4*)((const float*)Ap + (size_t)grow*K + kk);
          u1 = *(const float4*)((const float*)Ap + (size_t)grow*K + kk + 4);
        }
        if(BNA){
          float4 s0 = *(const float4*)(scale+kk),  s1 = *(const float4*)(scale+kk+4);
          float4 t0 = *(const float4*)(shift+kk),  t1 = *(const float4*)(shift+kk+4);
          u0.x=fmaxf(fmaf(s0.x,u0.x,t0.x),0.f); u0.y=fmaxf(fmaf(s0.y,u0.y,t0.y),0.f);
          u0.z=fmaxf(fmaf(s0.z,u0.z,t0.z),0.f); u0.w=fmaxf(fmaf(s0.w,u0.w,t0.w),0.f);
          u1.x=fmaxf(fmaf(s1.x,u1.x,t1.x),0.f); u1.y=fmaxf(fmaf(s1.y,u1.y,t1.y),0.f);
          u1.z=fmaxf(fmaf(s1.z,u1.z,t1.z),0.f); u1.w=fmaxf(fmaf(s1.w,u1.w,t1.w),0.f);
        }
        v.x = pack2bf(u0.x,u0.y); v.y = pack2bf(u0.z,u0.w);
        v.z = pack2bf(u1.x,u1.y); v.w = pack2bf(u1.z,u1.w);
      }
      Al[c*128 + m] = v;
    }
    #pragma unroll
    for(int i=0;i<4;i++){
      int idx = tid*4 + i;
      int n = idx >> 3, c = idx & 7;
      Bl[c*256 + n] = *(const uint4*)(Wt + (size_t)n*K + k0 + c*8);
    }
    __syncthreads();
    #pragma unroll
    for(int ks=0; ks<2; ks++){
      int cc = ks*4 + q;
      bf16x8 af[4], bfr[4];
      #pragma unroll
      for(int mi=0; mi<4; mi++)
        af[mi] = *((const bf16x8*)&Al[cc*128 + mhalf*64 + mi*16 + lm]);
      #pragma unroll
      for(int ni=0; ni<4; ni++)
        bfr[ni] = *((const bf16x8*)&Bl[cc*256 + nq*64 + ni*16 + lm]);
      #pragma unroll
      for(int mi=0; mi<4; mi++)
        #pragma unroll
        for(int ni=0; ni<4; ni++)
          acc[mi][ni] = __builtin_amdgcn_mfma_f32_16x16x32_bf16(af[mi], bfr[ni], acc[mi][ni], 0, 0, 0);
    }
    __syncthreads();
  }

  // ---- epilogue ----
  float bb[4], wgv[4];
  #pragma unroll
  for(int ni=0; ni<4; ni++){
    int col = nq*64 + ni*16 + lm;
    bb[ni] = bias[col];
    if(GATE) wgv[ni] = Wg[col];
  }
  #pragma unroll
  for(int mi=0; mi<4; mi++){
    int rowloc0 = mhalf*64 + mi*16 + q*4;
    float gp[4] = {0.f,0.f,0.f,0.f};
    #pragma unroll
    for(int ni=0; ni<4; ni++){
      int col = nq*64 + ni*16 + lm;
      f32x4 o = acc[mi][ni];
      #pragma unroll
      for(int r=0; r<4; r++){
        float v = o[r] + bb[ni];
        if(RELUOUT) v = fmaxf(v, 0.f);
        int row = m0 + rowloc0 + r;
        if(row < M){
          if(OUTBF16) ((ushort_t*)Cp)[(size_t)row*256 + col] = f2bf1(v);
          else        ((float*)Cp)[(size_t)row*256 + col] = v;
        }
        if(GATE) gp[r] = fmaf(v, wgv[ni], gp[r]);
      }
    }
    if(GATE){
      #pragma unroll
      for(int r=0; r<4; r++){
        if(m0 + rowloc0 + r < M) atomicAdd(&gacc[rowloc0 + r], gp[r]);
      }
    }
  }
  if(GATE){
    __syncthreads();
    if(tid < 128){
      int row = m0 + tid;
      if(row < M) gate[row] = gacc[tid] + bg[0];
    }
  }
}

// =============== BN column stats: parallel partials ===============
__global__ __launch_bounds__(256) void col_stats2(const float* __restrict__ h, float* __restrict__ psum,
                                                  float* __restrict__ pq, int M, int rpb, int nblk){
  int b = blockIdx.x;
  int g = threadIdx.x >> 6;
  int lane = threadIdx.x & 63;
  int c0 = lane*4;
  int r0 = b*rpb;
  int r1 = min(r0+rpb, M);
  float4 s4 = make_float4(0.f,0.f,0.f,0.f);
  float4 q4 = make_float4(0.f,0.f,0.f,0.f);
  for(int r=r0+g; r<r1; r+=4){
    float4 v = *(const float4*)(h + (size_t)r*256 + c0);
    s4.x+=v.x; s4.y+=v.y; s4.z+=v.z; s4.w+=v.w;
    q4.x=fmaf(v.x,v.x,q4.x); q4.y=fmaf(v.y,v.y,q4.y);
    q4.z=fmaf(v.z,v.z,q4.z); q4.w=fmaf(v.w,v.w,q4.w);
  }
  __shared__ float ls[1024];
  __shared__ float lq[1024];
  *(float4*)&ls[g*256+c0] = s4;
  *(float4*)&lq[g*256+c0] = q4;
  __syncthreads();
  if(threadIdx.x < 64){
    #pragma unroll
    for(int j=0;j<4;j++){
      int c = c0+j;
      float s = ls[c]+ls[256+c]+ls[512+c]+ls[768+c];
      float q = lq[c]+lq[256+c]+lq[512+c]+lq[768+c];
      psum[(size_t)c*nblk + b] = s;
      pq[(size_t)c*nblk + b]   = q;
    }
  }
}

__global__ __launch_bounds__(512) void stats_fin(const float* __restrict__ psum, const float* __restrict__ pq,
                                                 const float* __restrict__ gamma, const float* __restrict__ beta,
                                                 float* __restrict__ scale, float* __restrict__ shift,
                                                 int nblk, float invM){
  __shared__ float red[512];
  int t = threadIdx.x;
  const float* src = (t<256) ? (psum + (size_t)t*nblk) : (pq + (size_t)(t-256)*nblk);
  float s = 0.f;
  for(int i=0;i<nblk;i+=4){
    float4 v = *(const float4*)(src+i);
    s += v.x+v.y+v.z+v.w;
  }
  red[t]=s; __syncthreads();
  if(t<256){
    float mu  = red[t]*invM;
    float var = fmaxf(red[256+t]*invM - mu*mu, 0.f);
    float sc  = gamma[t] * rsqrtf(var + 1e-5f);
    scale[t]=sc; shift[t]=fmaf(-mu, sc, beta[t]);
  }
}

// =============== attentional pool: one block per graph (batch sorted), h2 bf16 ===============
__global__ __launch_bounds__(256) void pool_k(const ushort_t* __restrict__ h2b, const float* __restrict__ gate,
                                              const int* __restrict__ batch, float* __restrict__ pooled, int N){
  int g = blockIdx.x;
  __shared__ int sb[2];
  __shared__ float red[4];
  __shared__ float s_m, s_inv;
  if(threadIdx.x < 2){
    int target = g + threadIdx.x;
    int lo=0, hi=N;
    while(lo<hi){ int mid=(lo+hi)>>1; if(batch[mid] < target) lo=mid+1; else hi=mid; }
    sb[threadIdx.x] = lo;
  }
  __syncthreads();
  int beg = sb[0], end = sb[1];
  float mx = -1e30f;
  for(int i=beg+threadIdx.x; i<end; i+=256) mx = fmaxf(mx, gate[i]);
  #pragma unroll
  for(int d=32; d>0; d>>=1) mx = fmaxf(mx, __shfl_down(mx, d, 64));
  if((threadIdx.x&63)==0) red[threadIdx.x>>6] = mx;
  __syncthreads();
  if(threadIdx.x==0) s_m = fmaxf(fmaxf(red[0],red[1]), fmaxf(red[2],red[3]));
  __syncthreads();
  float m = s_m;
  float s = 0.f;
  for(int i=beg+threadIdx.x; i<end; i+=256) s += expf(gate[i]-m);
  #pragma unroll
  for(int d=32; d>0; d>>=1) s += __shfl_down(s, d, 64);
  if((threadIdx.x&63)==0) red[threadIdx.x>>6] = s;
  __syncthreads();
  if(threadIdx.x==0){
    float tot = red[0]+red[1]+red[2]+red[3];
    s_inv = (tot > 0.f) ? 1.f/tot : 0.f;
  }
  __syncthreads();
  float inv = s_inv;
  int t = threadIdx.x;
  float acc = 0.f;
  int i = beg;
  for(; i+2 <= end; i += 2){
    float a0 = expf(gate[i]-m) * inv;
    float a1 = expf(gate[i+1]-m) * inv;
    float h0 = bf2f_s(h2b[(size_t)i*256 + t]);
    float h1 = bf2f_s(h2b[(size_t)(i+1)*256 + t]);
    acc = fmaf(a0, h0, acc);
    acc = fmaf(a1, h1, acc);
  }
  for(; i < end; i++){
    float a = expf(gate[i]-m) * inv;
    acc = fmaf(a, bf2f_s(h2b[(size_t)i*256 + t]), acc);
  }
  pooled[g*256 + t] = acc;
}

// =============== head linear + log_softmax: one wave per graph ===============
__global__ __launch_bounds__(256) void head_k(const float* __restrict__ pooled,
                                              const float* __restrict__ sc2, const float* __restrict__ sh2,
                                              const float* __restrict__ Wh, const float* __restrict__ bh,
                                              float* __restrict__ out, int G){
  int w = (blockIdx.x*256 + threadIdx.x) >> 6;
  int l = threadIdx.x & 63;
  if(w >= G) return;
  float4 v  = *(const float4*)(pooled + (size_t)w*256 + l*4);
  float4 sc = *(const float4*)(sc2 + l*4);
  float4 sh = *(const float4*)(sh2 + l*4);
  float vv[4] = { fmaf(sc.x,v.x,sh.x), fmaf(sc.y,v.y,sh.y), fmaf(sc.z,v.z,sh.z), fmaf(sc.w,v.w,sh.w) };
  float4 w0 = *(const float4*)(Wh + (size_t)l*8);
  float4 w1 = *(const float4*)(Wh + (size_t)l*8 + 4);
  float a0 = vv[0]*w0.x + vv[1]*w0.z + vv[2]*w1.x + vv[3]*w1.z;
  float a1 = vv[0]*w0.y + vv[1]*w0.w + vv[2]*w1.y + vv[3]*w1.w;
  #pragma unroll
  for(int d=32; d>0; d>>=1){ a0 += __shfl_down(a0,d,64); a1 += __shfl_down(a1,d,64); }
  if(l==0){
    float z0 = a0 + bh[0];
    float z1 = a1 + bh[1];
    float mz = fmaxf(z0,z1);
    float lse = mz + logf(expf(z0-mz) + expf(z1-mz));
    out[w*2]   = z0 - lse;
    out[w*2+1] = z1 - lse;
  }
}

extern "C" void kernel_launch(void* const* d_in, const int* in_sizes, int n_in,
                              void* d_out, int out_size, void* d_ws, size_t ws_size,
                              hipStream_t stream){
  const float* x   = (const float*)d_in[0];
  const int*   ei  = (const int*)d_in[1];
  const int*   bat = (const int*)d_in[2];
  const float* W1  = (const float*)d_in[3];
  const float* b1  = (const float*)d_in[4];
  const float* g1  = (const float*)d_in[5];
  const float* be1 = (const float*)d_in[6];
  const float* W2  = (const float*)d_in[7];
  const float* b2  = (const float*)d_in[8];
  const float* Wg  = (const float*)d_in[9];
  const float* bg  = (const float*)d_in[10];
  const float* g2  = (const float*)d_in[11];
  const float* be2 = (const float*)d_in[12];
  const float* Wh  = (const float*)d_in[13];
  const float* bh  = (const float*)d_in[14];

  const int N = in_sizes[0] / 128;   // 50000
  const int E = in_sizes[1] / 2;     // 1600000
  const int G = out_size / 2;        // 512
  const int NB = (N + 63) >> 6;
  const int NBLK1 = 512;
  const int NBLK2 = 64;

  // ---- workspace layout ----
  char* ws = (char*)d_ws;
  u32*   h0b    = (u32*)ws;                          // 12,800,000 B
  u32*   xb     = (u32*)(ws + 12800000);             // 12,800,000 B
  int*   elist  = (int*)(ws + 25600000);             //  6,400,000 B
  u32*   pairs  = (u32*)(ws + 32000000);             //  6,400,000 B
  int*   offs   = (int*)(ws + 38400000);             //    200,004 B
  int*   bcount = (int*)(ws + 38600192);             //      4,096 B
  int*   bstart = (int*)(ws + 38604288);             //      4,100 B
  int*   bcursor= (int*)(ws + 38608640);             //     65,536 B
  ushort_t* h2b = (ushort_t*)ws;                     // 25,600,000 B (phase2, overlays phase1)
  float* h1     = (float*)(ws + 51200000);           // 51,200,000 B
  char*  p2 = ws + 102400000;
  float* psum1 = (float*)p2;          p2 += 256*NBLK1*4;
  float* pq1   = (float*)p2;          p2 += 256*NBLK1*4;
  float* psum2 = (float*)p2;          p2 += 256*NBLK2*4;
  float* pq2   = (float*)p2;          p2 += 256*NBLK2*4;
  float* sc1   = (float*)p2;          p2 += 1024;
  float* sh1   = (float*)p2;          p2 += 1024;
  float* gate  = (float*)p2;          p2 += (size_t)N*4 + 256;
  float* pooled= (float*)p2;          p2 += (size_t)G*256*4;
  float* sc2   = (float*)p2;          p2 += 1024;
  float* sh2   = (float*)p2;          p2 += 1024;
  ushort_t* W1t = (ushort_t*)p2;      p2 += 256*128*2;
  ushort_t* W2t = (ushort_t*)p2;      p2 += 256*256*2;

  const int* src = ei;
  const int* dst = ei + E;

  hipMemsetAsync(bcount, 0, (size_t)NB*4, stream);

  transpose_w<<<256, 256, 0, stream>>>(W1, W1t, 128);
  transpose_w<<<256, 256, 0, stream>>>(W2, W2t, 256);
  long n4 = (long)N*128/4;
  to_bf16    <<<(int)((n4+255)/256), 256, 0, stream>>>(x, xb, n4);

  int nchunk = (E + 8191)/8192;
  hist_k     <<<nchunk, 256, 0, stream>>>(dst, bcount, E, N, NB);
  bucket_scan<<<1, 256, 0, stream>>>(bcount, bstart, bcursor, offs, NB, N, E);
  binscatter2<<<nchunk, 256, 0, stream>>>(src, dst, bstart, bcursor, pairs, E, N, NB);
  bucket_csr <<<NB, 256, 0, stream>>>(pairs, bstart, offs, elist, N);
  gather_sum_bf<<<(N+15)/16, 256, 0, stream>>>(xb, offs, elist, h0b, N, E);

  int gblocks = (N + 127)/128;
  gemm_mfma<128,false,false,false,true,false><<<gblocks, 512, 0, stream>>>(
      h0b, W1t, b1, nullptr, nullptr, h1, N, nullptr, nullptr, nullptr);
  int rpb1 = (N + NBLK1 - 1)/NBLK1;
  col_stats2 <<<NBLK1, 256, 0, stream>>>(h1, psum1, pq1, N, rpb1, NBLK1);
  stats_fin  <<<1, 512, 0, stream>>>(psum1, pq1, g1, be1, sc1, sh1, NBLK1, 1.0f/(float)N);
  gemm_mfma<256,true,true,true,false,true><<<gblocks, 512, 0, stream>>>(
      h1, W2t, b2, sc1, sh1, h2b, N, Wg, bg, gate);

  pool_k <<<G, 256, 0, stream>>>(h2b, gate, bat, pooled, N);
  int rpb2 = (G + NBLK2 - 1)/NBLK2;
  col_stats2 <<<NBLK2, 256, 0, stream>>>(pooled, psum2, pq2, G, rpb2, NBLK2);
  stats_fin  <<<1, 512, 0, stream>>>(psum2, pq2, g2, be2, sc2, sh2, NBLK2, 1.0f/(float)G);
  head_k <<<(G+3)/4, 256, 0, stream>>>(pooled, sc2, sh2, Wh, bh, (float*)d_out, G);
}

// Round 10
// 362.906 us; speedup vs baseline: 2.6180x; 1.0248x over previous
//
#include <hip/hip_runtime.h>

typedef unsigned int u32;
typedef unsigned short ushort_t;
typedef __attribute__((ext_vector_type(8))) short bf16x8;
typedef __attribute__((ext_vector_type(4))) float f32x4;

__device__ __forceinline__ float bf2f_lo(u32 u){
  union{u32 i; float f;} v; v.i = u<<16; return v.f;
}
__device__ __forceinline__ float bf2f_hi(u32 u){
  union{u32 i; float f;} v; v.i = u & 0xFFFF0000u; return v.f;
}
__device__ __forceinline__ float bf2f_s(ushort_t u){
  union{u32 i; float f;} v; v.i = ((u32)u)<<16; return v.f;
}
__device__ __forceinline__ u32 pack2bf(float a, float b){
  union{float f; u32 i;} va, vb; va.f=a; vb.f=b;
  u32 ra = (va.i + 0x7FFF + ((va.i>>16)&1)) >> 16;          // RNE
  u32 rb = (vb.i + 0x7FFF + ((vb.i>>16)&1)) & 0xFFFF0000u;
  return ra | rb;
}
__device__ __forceinline__ ushort_t f2bf1(float f){
  union{float f; u32 i;} v; v.f=f;
  u32 r = v.i + 0x7FFF + ((v.i>>16)&1);
  return (ushort_t)(r>>16);
}

// =============== x fp32 -> bf16 (RNE) ===============
__global__ __launch_bounds__(256) void to_bf16(const float* __restrict__ x, u32* __restrict__ xb, long n4){
  long i = (long)blockIdx.x*256 + threadIdx.x;
  if(i*4 >= n4*4) return;
  float4 v = ((const float4*)x)[i];
  uint2 o; o.x = pack2bf(v.x, v.y); o.y = pack2bf(v.z, v.w);
  ((uint2*)xb)[i] = o;
}

// =============== W[K x 256] fp32 -> Wt[256 x K] bf16 ===============
__global__ __launch_bounds__(256) void transpose_w(const float* __restrict__ W, ushort_t* __restrict__ Wt, int K){
  int n = blockIdx.x;
  for(int k = threadIdx.x; k < K; k += 256){
    Wt[(size_t)n*K + k] = f2bf1(W[(size_t)k*256 + n]);
  }
}

// =============== binned CSR build (counting sort by dst) ===============
__global__ __launch_bounds__(256) void hist_k(const int* __restrict__ dst, int* __restrict__ bcount,
                                              int E, int N, int NB){
  __shared__ int h[1024];
  for(int i=threadIdx.x; i<1024; i+=256) h[i]=0;
  __syncthreads();
  int e0 = blockIdx.x*8192;
  int e1 = min(e0+8192, E);
  for(int i=e0+threadIdx.x; i<e1; i+=256){
    int d = dst[i];
    if((u32)d >= (u32)N) d = 0;
    atomicAdd(&h[d>>6], 1);
  }
  __syncthreads();
  for(int i=threadIdx.x; i<NB; i+=256){
    int v = h[i];
    if(v) atomicAdd(&bcount[i], v);
  }
}

__global__ __launch_bounds__(256) void bucket_scan(const int* __restrict__ bcount, int* __restrict__ bstart,
                                                   int* __restrict__ bcursor, int* __restrict__ offs,
                                                   int NB, int N, int E){
  __shared__ int tsum[256];
  int t = threadIdx.x;
  int base = t*4;
  int a0 = (base+0<NB)?bcount[base+0]:0;
  int a1 = (base+1<NB)?bcount[base+1]:0;
  int a2 = (base+2<NB)?bcount[base+2]:0;
  int a3 = (base+3<NB)?bcount[base+3]:0;
  int s0=a0, s1=s0+a1, s2=s1+a2, s3=s2+a3;
  tsum[t]=s3; __syncthreads();
  #pragma unroll
  for(int d=1; d<256; d<<=1){
    int v = (t>=d)?tsum[t-d]:0;
    __syncthreads();
    tsum[t]+=v;
    __syncthreads();
  }
  int prev = (t>0)?tsum[t-1]:0;
  if(base+0<NB){ bstart[base+0]=prev;    bcursor[(base+0)*16]=0; }
  if(base+1<NB){ bstart[base+1]=prev+s0; bcursor[(base+1)*16]=0; }
  if(base+2<NB){ bstart[base+2]=prev+s1; bcursor[(base+2)*16]=0; }
  if(base+3<NB){ bstart[base+3]=prev+s2; bcursor[(base+3)*16]=0; }
  if(t==255){ bstart[NB]=prev+s3; offs[N]=E; }
}

__global__ __launch_bounds__(256) void binscatter2(const int* __restrict__ src, const int* __restrict__ dst,
                                                   const int* __restrict__ bstart, int* __restrict__ bcursor,
                                                   u32* __restrict__ pairs, int E, int N, int NB){
  __shared__ int hist[1024];
  __shared__ int base[1024];
  int e0 = blockIdx.x*8192;
  int e1 = min(e0+8192, E);
  for(int i=threadIdx.x; i<NB; i+=256) hist[i]=0;
  __syncthreads();
  for(int i=e0+threadIdx.x; i<e1; i+=256){
    int d = dst[i];
    if((u32)d >= (u32)N) d = 0;
    atomicAdd(&hist[d>>6], 1);
  }
  __syncthreads();
  for(int i=threadIdx.x; i<NB; i+=256){
    int c = hist[i];
    base[i] = c ? (bstart[i] + atomicAdd(&bcursor[i*16], c)) : 0;
    hist[i] = 0;
  }
  __syncthreads();
  for(int i=e0+threadIdx.x; i<e1; i+=256){
    int d = dst[i]; if((u32)d >= (u32)N) d = 0;
    int s = src[i]; if((u32)s >= (u32)N) s = 0;
    int b = d>>6;
    int loc = atomicAdd(&hist[b], 1);
    pairs[base[b]+loc] = (u32)s | (((u32)(d & 63))<<17);
  }
}

__global__ __launch_bounds__(256) void bucket_csr(const u32* __restrict__ pairs, const int* __restrict__ bstart,
                                                  int* __restrict__ offs, int* __restrict__ elist, int N){
  __shared__ int dcnt[64];
  __shared__ int dcur[64];
  int b = blockIdx.x;
  int p0 = bstart[b], p1 = bstart[b+1];
  if(threadIdx.x < 64) dcnt[threadIdx.x] = 0;
  __syncthreads();
  for(int i=p0+threadIdx.x; i<p1; i+=256){
    u32 u = pairs[i];
    atomicAdd(&dcnt[u>>17], 1);
  }
  __syncthreads();
  if(threadIdx.x == 0){
    int running = p0;
    #pragma unroll
    for(int j=0;j<64;j++){
      dcur[j] = running;
      int node = b*64 + j;
      if(node < N) offs[node] = running;
      running += dcnt[j];
    }
  }
  __syncthreads();
  for(int i=p0+threadIdx.x; i<p1; i+=256){
    u32 u = pairs[i];
    int pos = atomicAdd(&dcur[u>>17], 1);
    elist[pos] = (int)(u & 0x1FFFFu);
  }
}

// h0[i] = x[i] + sum_{j->i} x[j]  — bf16 gather, fp32 accumulate, bf16 out. Unroll x4.
__global__ __launch_bounds__(256) void gather_sum_bf(const u32* __restrict__ xb, const int* __restrict__ offs,
                                                     const int* __restrict__ elist, u32* __restrict__ h0b,
                                                     int N, int E){
  int slot = threadIdx.x >> 4;
  int c = threadIdx.x & 15;
  int i = blockIdx.x*16 + slot;
  if(i >= N) return;
  const uint4* xr = (const uint4*)xb;
  uint4 xv = xr[(size_t)i*16 + c];
  float acc[8] = {
    bf2f_lo(xv.x), bf2f_hi(xv.x), bf2f_lo(xv.y), bf2f_hi(xv.y),
    bf2f_lo(xv.z), bf2f_hi(xv.z), bf2f_lo(xv.w), bf2f_hi(xv.w) };
  int e0 = offs[i], e1 = offs[i+1];
  e0 = max(0, min(e0, E));
  e1 = max(e0, min(e1, E));
  int j = e0;
  for(; j+4 <= e1; j += 4){
    int s0 = elist[j+0]; if((u32)s0 >= (u32)N) s0 = 0;
    int s1 = elist[j+1]; if((u32)s1 >= (u32)N) s1 = 0;
    int s2 = elist[j+2]; if((u32)s2 >= (u32)N) s2 = 0;
    int s3 = elist[j+3]; if((u32)s3 >= (u32)N) s3 = 0;
    uint4 v0 = xr[(size_t)s0*16 + c];
    uint4 v1 = xr[(size_t)s1*16 + c];
    uint4 v2 = xr[(size_t)s2*16 + c];
    uint4 v3 = xr[(size_t)s3*16 + c];
    acc[0]+=bf2f_lo(v0.x); acc[1]+=bf2f_hi(v0.x); acc[2]+=bf2f_lo(v0.y); acc[3]+=bf2f_hi(v0.y);
    acc[4]+=bf2f_lo(v0.z); acc[5]+=bf2f_hi(v0.z); acc[6]+=bf2f_lo(v0.w); acc[7]+=bf2f_hi(v0.w);
    acc[0]+=bf2f_lo(v1.x); acc[1]+=bf2f_hi(v1.x); acc[2]+=bf2f_lo(v1.y); acc[3]+=bf2f_hi(v1.y);
    acc[4]+=bf2f_lo(v1.z); acc[5]+=bf2f_hi(v1.z); acc[6]+=bf2f_lo(v1.w); acc[7]+=bf2f_hi(v1.w);
    acc[0]+=bf2f_lo(v2.x); acc[1]+=bf2f_hi(v2.x); acc[2]+=bf2f_lo(v2.y); acc[3]+=bf2f_hi(v2.y);
    acc[4]+=bf2f_lo(v2.z); acc[5]+=bf2f_hi(v2.z); acc[6]+=bf2f_lo(v2.w); acc[7]+=bf2f_hi(v2.w);
    acc[0]+=bf2f_lo(v3.x); acc[1]+=bf2f_hi(v3.x); acc[2]+=bf2f_lo(v3.y); acc[3]+=bf2f_hi(v3.y);
    acc[4]+=bf2f_lo(v3.z); acc[5]+=bf2f_hi(v3.z); acc[6]+=bf2f_lo(v3.w); acc[7]+=bf2f_hi(v3.w);
  }
  for(; j < e1; j++){
    int s = elist[j];
    if((u32)s >= (u32)N) s = 0;
    uint4 v = xr[(size_t)s*16 + c];
    acc[0]+=bf2f_lo(v.x); acc[1]+=bf2f_hi(v.x);
    acc[2]+=bf2f_lo(v.y); acc[3]+=bf2f_hi(v.y);
    acc[4]+=bf2f_lo(v.z); acc[5]+=bf2f_hi(v.z);
    acc[6]+=bf2f_lo(v.w); acc[7]+=bf2f_hi(v.w);
  }
  uint4 o;
  o.x = pack2bf(acc[0],acc[1]); o.y = pack2bf(acc[2],acc[3]);
  o.z = pack2bf(acc[4],acc[5]); o.w = pack2bf(acc[6],acc[7]);
  ((uint4*)h0b)[(size_t)i*16 + c] = o;
}

// =============== MFMA bf16 GEMM: C[M,256] = op(A[M,K]) @ Wt^T + bias ===============
// Wt is [256][K] bf16 (B^T). 512 threads = 8 waves; tile 128m x 256n, BK=64.
// LDS slabs padded to odd uint4 strides (129 / 257) to kill bank aliasing.
template<int K, bool BNA, bool RELUOUT, bool GATE, bool ABF16, bool OUTBF16>
__global__ __launch_bounds__(512) void gemm_mfma(const void* __restrict__ Ap, const ushort_t* __restrict__ Wt,
                                                 const float* __restrict__ bias,
                                                 const float* __restrict__ scale, const float* __restrict__ shift,
                                                 void* __restrict__ Cp, int M,
                                                 const float* __restrict__ Wg, const float* __restrict__ bg,
                                                 float* __restrict__ gate){
  __shared__ uint4 Al[8*129];   // padded: slab stride 129 uint4
  __shared__ uint4 Bl[8*257];   // padded: slab stride 257 uint4
  __shared__ float gacc[128];
  const int tid  = threadIdx.x;
  const int lane = tid & 63;
  const int wave = tid >> 6;
  const int lm   = lane & 15;
  const int q    = lane >> 4;
  const int mhalf= wave >> 2;
  const int nq   = wave & 3;
  const int m0   = blockIdx.x * 128;

  if(GATE && tid < 128) gacc[tid] = 0.f;

  f32x4 acc[4][4];
  #pragma unroll
  for(int i=0;i<4;i++)
    #pragma unroll
    for(int j=0;j<4;j++) acc[i][j] = (f32x4){0.f,0.f,0.f,0.f};

  for(int k0=0; k0<K; k0+=64){
    // ---- stage A ----
    #pragma unroll
    for(int i=0;i<2;i++){
      int idx = tid*2 + i;
      int m = idx >> 3, c = idx & 7;
      int grow = m0 + m;
      int kk = k0 + c*8;
      uint4 v = make_uint4(0,0,0,0);
      if(ABF16){
        if(grow < M) v = *(const uint4*)((const ushort_t*)Ap + (size_t)grow*K + kk);
        if(BNA){
          float f0=bf2f_lo(v.x), f1=bf2f_hi(v.x), f2=bf2f_lo(v.y), f3=bf2f_hi(v.y);
          float f4=bf2f_lo(v.z), f5=bf2f_hi(v.z), f6=bf2f_lo(v.w), f7=bf2f_hi(v.w);
          float4 s0 = *(const float4*)(scale+kk),  s1 = *(const float4*)(scale+kk+4);
          float4 t0 = *(const float4*)(shift+kk),  t1 = *(const float4*)(shift+kk+4);
          f0=fmaxf(fmaf(s0.x,f0,t0.x),0.f); f1=fmaxf(fmaf(s0.y,f1,t0.y),0.f);
          f2=fmaxf(fmaf(s0.z,f2,t0.z),0.f); f3=fmaxf(fmaf(s0.w,f3,t0.w),0.f);
          f4=fmaxf(fmaf(s1.x,f4,t1.x),0.f); f5=fmaxf(fmaf(s1.y,f5,t1.y),0.f);
          f6=fmaxf(fmaf(s1.z,f6,t1.z),0.f); f7=fmaxf(fmaf(s1.w,f7,t1.w),0.f);
          v.x = pack2bf(f0,f1); v.y = pack2bf(f2,f3);
          v.z = pack2bf(f4,f5); v.w = pack2bf(f6,f7);
        }
      } else {
        float4 u0 = make_float4(0,0,0,0), u1 = make_float4(0,0,0,0);
        if(grow < M){
          u0 = *(const float4*)((const float*)Ap + (size_t)grow*K + kk);
          u1 = *(const float4*)((const float*)Ap + (size_t)grow*K + kk + 4);
        }
        if(BNA){
          float4 s0 = *(const float4*)(scale+kk),  s1 = *(const float4*)(scale+kk+4);
          float4 t0 = *(const float4*)(shift+kk),  t1 = *(const float4*)(shift+kk+4);
          u0.x=fmaxf(fmaf(s0.x,u0.x,t0.x),0.f); u0.y=fmaxf(fmaf(s0.y,u0.y,t0.y),0.f);
          u0.z=fmaxf(fmaf(s0.z,u0.z,t0.z),0.f); u0.w=fmaxf(fmaf(s0.w,u0.w,t0.w),0.f);
          u1.x=fmaxf(fmaf(s1.x,u1.x,t1.x),0.f); u1.y=fmaxf(fmaf(s1.y,u1.y,t1.y),0.f);
          u1.z=fmaxf(fmaf(s1.z,u1.z,t1.z),0.f); u1.w=fmaxf(fmaf(s1.w,u1.w,t1.w),0.f);
        }
        v.x = pack2bf(u0.x,u0.y); v.y = pack2bf(u0.z,u0.w);
        v.z = pack2bf(u1.x,u1.y); v.w = pack2bf(u1.z,u1.w);
      }
      Al[c*129 + m] = v;
    }
    // ---- stage B ----
    #pragma unroll
    for(int i=0;i<4;i++){
      int idx = tid*4 + i;
      int n = idx >> 3, c = idx & 7;
      Bl[c*257 + n] = *(const uint4*)(Wt + (size_t)n*K + k0 + c*8);
    }
    __syncthreads();
    #pragma unroll
    for(int ks=0; ks<2; ks++){
      int cc = ks*4 + q;
      bf16x8 af[4], bfr[4];
      #pragma unroll
      for(int mi=0; mi<4; mi++)
        af[mi] = *((const bf16x8*)&Al[cc*129 + mhalf*64 + mi*16 + lm]);
      #pragma unroll
      for(int ni=0; ni<4; ni++)
        bfr[ni] = *((const bf16x8*)&Bl[cc*257 + nq*64 + ni*16 + lm]);
      #pragma unroll
      for(int mi=0; mi<4; mi++)
        #pragma unroll
        for(int ni=0; ni<4; ni++)
          acc[mi][ni] = __builtin_amdgcn_mfma_f32_16x16x32_bf16(af[mi], bfr[ni], acc[mi][ni], 0, 0, 0);
    }
    __syncthreads();
  }

  // ---- epilogue ----
  float bb[4], wgv[4];
  #pragma unroll
  for(int ni=0; ni<4; ni++){
    int col = nq*64 + ni*16 + lm;
    bb[ni] = bias[col];
    if(GATE) wgv[ni] = Wg[col];
  }
  #pragma unroll
  for(int mi=0; mi<4; mi++){
    int rowloc0 = mhalf*64 + mi*16 + q*4;
    float gp[4] = {0.f,0.f,0.f,0.f};
    #pragma unroll
    for(int ni=0; ni<4; ni++){
      int col = nq*64 + ni*16 + lm;
      f32x4 o = acc[mi][ni];
      #pragma unroll
      for(int r=0; r<4; r++){
        float v = o[r] + bb[ni];
        if(RELUOUT) v = fmaxf(v, 0.f);
        int row = m0 + rowloc0 + r;
        if(row < M){
          if(OUTBF16) ((ushort_t*)Cp)[(size_t)row*256 + col] = f2bf1(v);
          else        ((float*)Cp)[(size_t)row*256 + col] = v;
        }
        if(GATE) gp[r] = fmaf(v, wgv[ni], gp[r]);
      }
    }
    if(GATE){
      #pragma unroll
      for(int r=0; r<4; r++){
        if(m0 + rowloc0 + r < M) atomicAdd(&gacc[rowloc0 + r], gp[r]);
      }
    }
  }
  if(GATE){
    __syncthreads();
    if(tid < 128){
      int row = m0 + tid;
      if(row < M) gate[row] = gacc[tid] + bg[0];
    }
  }
}

// =============== BN column stats over bf16 h (parallel partials) ===============
__global__ __launch_bounds__(256) void col_stats_bf(const u32* __restrict__ h, float* __restrict__ psum,
                                                    float* __restrict__ pq, int M, int rpb, int nblk){
  int b = blockIdx.x;
  int g = threadIdx.x >> 6;
  int lane = threadIdx.x & 63;
  int c0 = lane*4;
  int r0 = b*rpb;
  int r1 = min(r0+rpb, M);
  float4 s4 = make_float4(0.f,0.f,0.f,0.f);
  float4 q4 = make_float4(0.f,0.f,0.f,0.f);
  for(int r=r0+g; r<r1; r+=4){
    uint2 u = *(const uint2*)(h + (size_t)r*128 + lane*2);
    float v0=bf2f_lo(u.x), v1=bf2f_hi(u.x), v2=bf2f_lo(u.y), v3=bf2f_hi(u.y);
    s4.x+=v0; s4.y+=v1; s4.z+=v2; s4.w+=v3;
    q4.x=fmaf(v0,v0,q4.x); q4.y=fmaf(v1,v1,q4.y);
    q4.z=fmaf(v2,v2,q4.z); q4.w=fmaf(v3,v3,q4.w);
  }
  __shared__ float ls[1024];
  __shared__ float lq[1024];
  *(float4*)&ls[g*256+c0] = s4;
  *(float4*)&lq[g*256+c0] = q4;
  __syncthreads();
  if(threadIdx.x < 64){
    #pragma unroll
    for(int j=0;j<4;j++){
      int c = c0+j;
      float s = ls[c]+ls[256+c]+ls[512+c]+ls[768+c];
      float q = lq[c]+lq[256+c]+lq[512+c]+lq[768+c];
      psum[(size_t)c*nblk + b] = s;
      pq[(size_t)c*nblk + b]   = q;
    }
  }
}

// =============== fp32 col stats (for pooled) ===============
__global__ __launch_bounds__(256) void col_stats2(const float* __restrict__ h, float* __restrict__ psum,
                                                  float* __restrict__ pq, int M, int rpb, int nblk){
  int b = blockIdx.x;
  int g = threadIdx.x >> 6;
  int lane = threadIdx.x & 63;
  int c0 = lane*4;
  int r0 = b*rpb;
  int r1 = min(r0+rpb, M);
  float4 s4 = make_float4(0.f,0.f,0.f,0.f);
  float4 q4 = make_float4(0.f,0.f,0.f,0.f);
  for(int r=r0+g; r<r1; r+=4){
    float4 v = *(const float4*)(h + (size_t)r*256 + c0);
    s4.x+=v.x; s4.y+=v.y; s4.z+=v.z; s4.w+=v.w;
    q4.x=fmaf(v.x,v.x,q4.x); q4.y=fmaf(v.y,v.y,q4.y);
    q4.z=fmaf(v.z,v.z,q4.z); q4.w=fmaf(v.w,v.w,q4.w);
  }
  __shared__ float ls[1024];
  __shared__ float lq[1024];
  *(float4*)&ls[g*256+c0] = s4;
  *(float4*)&lq[g*256+c0] = q4;
  __syncthreads();
  if(threadIdx.x < 64){
    #pragma unroll
    for(int j=0;j<4;j++){
      int c = c0+j;
      float s = ls[c]+ls[256+c]+ls[512+c]+ls[768+c];
      float q = lq[c]+lq[256+c]+lq[512+c]+lq[768+c];
      psum[(size_t)c*nblk + b] = s;
      pq[(size_t)c*nblk + b]   = q;
    }
  }
}

__global__ __launch_bounds__(512) void stats_fin(const float* __restrict__ psum, const float* __restrict__ pq,
                                                 const float* __restrict__ gamma, const float* __restrict__ beta,
                                                 float* __restrict__ scale, float* __restrict__ shift,
                                                 int nblk, float invM){
  __shared__ float red[512];
  int t = threadIdx.x;
  const float* src = (t<256) ? (psum + (size_t)t*nblk) : (pq + (size_t)(t-256)*nblk);
  float s = 0.f;
  for(int i=0;i<nblk;i+=4){
    float4 v = *(const float4*)(src+i);
    s += v.x+v.y+v.z+v.w;
  }
  red[t]=s; __syncthreads();
  if(t<256){
    float mu  = red[t]*invM;
    float var = fmaxf(red[256+t]*invM - mu*mu, 0.f);
    float sc  = gamma[t] * rsqrtf(var + 1e-5f);
    scale[t]=sc; shift[t]=fmaf(-mu, sc, beta[t]);
  }
}

// =============== attentional pool: one block per graph (batch sorted), h2 bf16 ===============
__global__ __launch_bounds__(256) void pool_k(const ushort_t* __restrict__ h2b, const float* __restrict__ gate,
                                              const int* __restrict__ batch, float* __restrict__ pooled, int N){
  int g = blockIdx.x;
  __shared__ int sb[2];
  __shared__ float red[4];
  __shared__ float s_m, s_inv;
  if(threadIdx.x < 2){
    int target = g + threadIdx.x;
    int lo=0, hi=N;
    while(lo<hi){ int mid=(lo+hi)>>1; if(batch[mid] < target) lo=mid+1; else hi=mid; }
    sb[threadIdx.x] = lo;
  }
  __syncthreads();
  int beg = sb[0], end = sb[1];
  float mx = -1e30f;
  for(int i=beg+threadIdx.x; i<end; i+=256) mx = fmaxf(mx, gate[i]);
  #pragma unroll
  for(int d=32; d>0; d>>=1) mx = fmaxf(mx, __shfl_down(mx, d, 64));
  if((threadIdx.x&63)==0) red[threadIdx.x>>6] = mx;
  __syncthreads();
  if(threadIdx.x==0) s_m = fmaxf(fmaxf(red[0],red[1]), fmaxf(red[2],red[3]));
  __syncthreads();
  float m = s_m;
  float s = 0.f;
  for(int i=beg+threadIdx.x; i<end; i+=256) s += expf(gate[i]-m);
  #pragma unroll
  for(int d=32; d>0; d>>=1) s += __shfl_down(s, d, 64);
  if((threadIdx.x&63)==0) red[threadIdx.x>>6] = s;
  __syncthreads();
  if(threadIdx.x==0){
    float tot = red[0]+red[1]+red[2]+red[3];
    s_inv = (tot > 0.f) ? 1.f/tot : 0.f;
  }
  __syncthreads();
  float inv = s_inv;
  int t = threadIdx.x;
  float acc = 0.f;
  int i = beg;
  for(; i+2 <= end; i += 2){
    float a0 = expf(gate[i]-m) * inv;
    float a1 = expf(gate[i+1]-m) * inv;
    float h0 = bf2f_s(h2b[(size_t)i*256 + t]);
    float h1 = bf2f_s(h2b[(size_t)(i+1)*256 + t]);
    acc = fmaf(a0, h0, acc);
    acc = fmaf(a1, h1, acc);
  }
  for(; i < end; i++){
    float a = expf(gate[i]-m) * inv;
    acc = fmaf(a, bf2f_s(h2b[(size_t)i*256 + t]), acc);
  }
  pooled[g*256 + t] = acc;
}

// =============== head linear + log_softmax: one wave per graph ===============
__global__ __launch_bounds__(256) void head_k(const float* __restrict__ pooled,
                                              const float* __restrict__ sc2, const float* __restrict__ sh2,
                                              const float* __restrict__ Wh, const float* __restrict__ bh,
                                              float* __restrict__ out, int G){
  int w = (blockIdx.x*256 + threadIdx.x) >> 6;
  int l = threadIdx.x & 63;
  if(w >= G) return;
  float4 v  = *(const float4*)(pooled + (size_t)w*256 + l*4);
  float4 sc = *(const float4*)(sc2 + l*4);
  float4 sh = *(const float4*)(sh2 + l*4);
  float vv[4] = { fmaf(sc.x,v.x,sh.x), fmaf(sc.y,v.y,sh.y), fmaf(sc.z,v.z,sh.z), fmaf(sc.w,v.w,sh.w) };
  float4 w0 = *(const float4*)(Wh + (size_t)l*8);
  float4 w1 = *(const float4*)(Wh + (size_t)l*8 + 4);
  float a0 = vv[0]*w0.x + vv[1]*w0.z + vv[2]*w1.x + vv[3]*w1.z;
  float a1 = vv[0]*w0.y + vv[1]*w0.w + vv[2]*w1.y + vv[3]*w1.w;
  #pragma unroll
  for(int d=32; d>0; d>>=1){ a0 += __shfl_down(a0,d,64); a1 += __shfl_down(a1,d,64); }
  if(l==0){
    float z0 = a0 + bh[0];
    float z1 = a1 + bh[1];
    float mz = fmaxf(z0,z1);
    float lse = mz + logf(expf(z0-mz) + expf(z1-mz));
    out[w*2]   = z0 - lse;
    out[w*2+1] = z1 - lse;
  }
}

extern "C" void kernel_launch(void* const* d_in, const int* in_sizes, int n_in,
                              void* d_out, int out_size, void* d_ws, size_t ws_size,
                              hipStream_t stream){
  const float* x   = (const float*)d_in[0];
  const int*   ei  = (const int*)d_in[1];
  const int*   bat = (const int*)d_in[2];
  const float* W1  = (const float*)d_in[3];
  const float* b1  = (const float*)d_in[4];
  const float* g1  = (const float*)d_in[5];
  const float* be1 = (const float*)d_in[6];
  const float* W2  = (const float*)d_in[7];
  const float* b2  = (const float*)d_in[8];
  const float* Wg  = (const float*)d_in[9];
  const float* bg  = (const float*)d_in[10];
  const float* g2  = (const float*)d_in[11];
  const float* be2 = (const float*)d_in[12];
  const float* Wh  = (const float*)d_in[13];
  const float* bh  = (const float*)d_in[14];

  const int N = in_sizes[0] / 128;   // 50000
  const int E = in_sizes[1] / 2;     // 1600000
  const int G = out_size / 2;        // 512
  const int NB = (N + 63) >> 6;
  const int NBLK1 = 512;
  const int NBLK2 = 64;

  // ---- workspace layout ----
  char* ws = (char*)d_ws;
  u32*   h0b    = (u32*)ws;                          // 12,800,000 B
  u32*   xb     = (u32*)(ws + 12800000);             // 12,800,000 B
  int*   elist  = (int*)(ws + 25600000);             //  6,400,000 B
  u32*   pairs  = (u32*)(ws + 32000000);             //  6,400,000 B
  int*   offs   = (int*)(ws + 38400000);             //    200,004 B
  int*   bcount = (int*)(ws + 38600192);             //      4,096 B
  int*   bstart = (int*)(ws + 38604288);             //      4,100 B
  int*   bcursor= (int*)(ws + 38608640);             //     65,536 B
  ushort_t* h2b = (ushort_t*)ws;                     // 25,600,000 B (phase2, overlays phase1)
  u32*   h1b    = (u32*)(ws + 51200000);             // 25,600,000 B (bf16, as u32 pairs)
  char*  p2 = ws + 102400000;
  float* psum1 = (float*)p2;          p2 += 256*NBLK1*4;
  float* pq1   = (float*)p2;          p2 += 256*NBLK1*4;
  float* psum2 = (float*)p2;          p2 += 256*NBLK2*4;
  float* pq2   = (float*)p2;          p2 += 256*NBLK2*4;
  float* sc1   = (float*)p2;          p2 += 1024;
  float* sh1   = (float*)p2;          p2 += 1024;
  float* gate  = (float*)p2;          p2 += (size_t)N*4 + 256;
  float* pooled= (float*)p2;          p2 += (size_t)G*256*4;
  float* sc2   = (float*)p2;          p2 += 1024;
  float* sh2   = (float*)p2;          p2 += 1024;
  ushort_t* W1t = (ushort_t*)p2;      p2 += 256*128*2;
  ushort_t* W2t = (ushort_t*)p2;      p2 += 256*256*2;

  const int* src = ei;
  const int* dst = ei + E;

  hipMemsetAsync(bcount, 0, (size_t)NB*4, stream);

  transpose_w<<<256, 256, 0, stream>>>(W1, W1t, 128);
  transpose_w<<<256, 256, 0, stream>>>(W2, W2t, 256);
  long n4 = (long)N*128/4;
  to_bf16    <<<(int)((n4+255)/256), 256, 0, stream>>>(x, xb, n4);

  int nchunk = (E + 8191)/8192;
  hist_k     <<<nchunk, 256, 0, stream>>>(dst, bcount, E, N, NB);
  bucket_scan<<<1, 256, 0, stream>>>(bcount, bstart, bcursor, offs, NB, N, E);
  binscatter2<<<nchunk, 256, 0, stream>>>(src, dst, bstart, bcursor, pairs, E, N, NB);
  bucket_csr <<<NB, 256, 0, stream>>>(pairs, bstart, offs, elist, N);
  gather_sum_bf<<<(N+15)/16, 256, 0, stream>>>(xb, offs, elist, h0b, N, E);

  int gblocks = (N + 127)/128;
  // gemm1: A=h0b bf16, out h1b bf16
  gemm_mfma<128,false,false,false,true,true><<<gblocks, 512, 0, stream>>>(
      h0b, W1t, b1, nullptr, nullptr, h1b, N, nullptr, nullptr, nullptr);
  int rpb1 = (N + NBLK1 - 1)/NBLK1;
  col_stats_bf <<<NBLK1, 256, 0, stream>>>(h1b, psum1, pq1, N, rpb1, NBLK1);
  stats_fin  <<<1, 512, 0, stream>>>(psum1, pq1, g1, be1, sc1, sh1, NBLK1, 1.0f/(float)N);
  // gemm2: A=h1b bf16 + BN+ReLU staged, out h2b bf16, gate fused
  gemm_mfma<256,true,true,true,true,true><<<gblocks, 512, 0, stream>>>(
      h1b, W2t, b2, sc1, sh1, h2b, N, Wg, bg, gate);

  pool_k <<<G, 256, 0, stream>>>(h2b, gate, bat, pooled, N);
  int rpb2 = (G + NBLK2 - 1)/NBLK2;
  col_stats2 <<<NBLK2, 256, 0, stream>>>(pooled, psum2, pq2, G, rpb2, NBLK2);
  stats_fin  <<<1, 512, 0, stream>>>(psum2, pq2, g2, be2, sc2, sh2, NBLK2, 1.0f/(float)G);
  head_k <<<(G+3)/4, 256, 0, stream>>>(pooled, sc2, sh2, Wh, bh, (float*)d_out, G);
}

// Round 11
// 355.616 us; speedup vs baseline: 2.6716x; 1.0205x over previous
//
#include <hip/hip_runtime.h>

typedef unsigned int u32;
typedef unsigned short ushort_t;
typedef __attribute__((ext_vector_type(8))) short bf16x8;
typedef __attribute__((ext_vector_type(4))) float f32x4;

__device__ __forceinline__ float bf2f_lo(u32 u){
  union{u32 i; float f;} v; v.i = u<<16; return v.f;
}
__device__ __forceinline__ float bf2f_hi(u32 u){
  union{u32 i; float f;} v; v.i = u & 0xFFFF0000u; return v.f;
}
__device__ __forceinline__ float bf2f_s(ushort_t u){
  union{u32 i; float f;} v; v.i = ((u32)u)<<16; return v.f;
}
__device__ __forceinline__ u32 pack2bf(float a, float b){
  union{float f; u32 i;} va, vb; va.f=a; vb.f=b;
  u32 ra = (va.i + 0x7FFF + ((va.i>>16)&1)) >> 16;          // RNE
  u32 rb = (vb.i + 0x7FFF + ((vb.i>>16)&1)) & 0xFFFF0000u;
  return ra | rb;
}
__device__ __forceinline__ ushort_t f2bf1(float f){
  union{float f; u32 i;} v; v.f=f;
  u32 r = v.i + 0x7FFF + ((v.i>>16)&1);
  return (ushort_t)(r>>16);
}

// =============== x fp32 -> bf16 (RNE) ===============
__global__ __launch_bounds__(256) void to_bf16(const float* __restrict__ x, u32* __restrict__ xb, long n4){
  long i = (long)blockIdx.x*256 + threadIdx.x;
  if(i*4 >= n4*4) return;
  float4 v = ((const float4*)x)[i];
  uint2 o; o.x = pack2bf(v.x, v.y); o.y = pack2bf(v.z, v.w);
  ((uint2*)xb)[i] = o;
}

// =============== W[K x 256] fp32 -> Wt[256 x K] bf16 ===============
__global__ __launch_bounds__(256) void transpose_w(const float* __restrict__ W, ushort_t* __restrict__ Wt, int K){
  int n = blockIdx.x;
  for(int k = threadIdx.x; k < K; k += 256){
    Wt[(size_t)n*K + k] = f2bf1(W[(size_t)k*256 + n]);
  }
}

// =============== binned CSR build (counting sort by dst bucket) ===============
__global__ __launch_bounds__(256) void hist_k(const int* __restrict__ dst, int* __restrict__ bcount,
                                              int E, int N, int NB){
  __shared__ int h[1024];
  for(int i=threadIdx.x; i<1024; i+=256) h[i]=0;
  __syncthreads();
  int e0 = blockIdx.x*8192;
  int e1 = min(e0+8192, E);
  for(int i=e0+threadIdx.x; i<e1; i+=256){
    int d = dst[i];
    if((u32)d >= (u32)N) d = 0;
    atomicAdd(&h[d>>6], 1);
  }
  __syncthreads();
  for(int i=threadIdx.x; i<NB; i+=256){
    int v = h[i];
    if(v) atomicAdd(&bcount[i], v);
  }
}

__global__ __launch_bounds__(256) void bucket_scan(const int* __restrict__ bcount, int* __restrict__ bstart,
                                                   int* __restrict__ bcursor, int NB){
  __shared__ int tsum[256];
  int t = threadIdx.x;
  int base = t*4;
  int a0 = (base+0<NB)?bcount[base+0]:0;
  int a1 = (base+1<NB)?bcount[base+1]:0;
  int a2 = (base+2<NB)?bcount[base+2]:0;
  int a3 = (base+3<NB)?bcount[base+3]:0;
  int s0=a0, s1=s0+a1, s2=s1+a2, s3=s2+a3;
  tsum[t]=s3; __syncthreads();
  #pragma unroll
  for(int d=1; d<256; d<<=1){
    int v = (t>=d)?tsum[t-d]:0;
    __syncthreads();
    tsum[t]+=v;
    __syncthreads();
  }
  int prev = (t>0)?tsum[t-1]:0;
  if(base+0<NB){ bstart[base+0]=prev;    bcursor[(base+0)*16]=0; }
  if(base+1<NB){ bstart[base+1]=prev+s0; bcursor[(base+1)*16]=0; }
  if(base+2<NB){ bstart[base+2]=prev+s1; bcursor[(base+2)*16]=0; }
  if(base+3<NB){ bstart[base+3]=prev+s2; bcursor[(base+3)*16]=0; }
  if(t==255){ bstart[NB]=prev+s3; }
}

__global__ __launch_bounds__(256) void binscatter2(const int* __restrict__ src, const int* __restrict__ dst,
                                                   const int* __restrict__ bstart, int* __restrict__ bcursor,
                                                   u32* __restrict__ pairs, int E, int N, int NB){
  __shared__ int hist[1024];
  __shared__ int base[1024];
  int e0 = blockIdx.x*8192;
  int e1 = min(e0+8192, E);
  for(int i=threadIdx.x; i<NB; i+=256) hist[i]=0;
  __syncthreads();
  for(int i=e0+threadIdx.x; i<e1; i+=256){
    int d = dst[i];
    if((u32)d >= (u32)N) d = 0;
    atomicAdd(&hist[d>>6], 1);
  }
  __syncthreads();
  for(int i=threadIdx.x; i<NB; i+=256){
    int c = hist[i];
    base[i] = c ? (bstart[i] + atomicAdd(&bcursor[i*16], c)) : 0;
    hist[i] = 0;
  }
  __syncthreads();
  for(int i=e0+threadIdx.x; i<e1; i+=256){
    int d = dst[i]; if((u32)d >= (u32)N) d = 0;
    int s = src[i]; if((u32)s >= (u32)N) s = 0;
    int b = d>>6;
    int loc = atomicAdd(&hist[b], 1);
    pairs[base[b]+loc] = (u32)s | (((u32)(d & 63))<<17);
  }
}

// =============== fused bucket-CSR + gather: one block per 64-node bucket ===============
// pairs slice read twice (count, LDS scatter) -> edge indices served from LDS.
// h0[i] = x[i] + sum_{j->i} x[j]; bf16 in/out, fp32 accumulate; 8-deep load pipelining.
#define BCAP 4096
__global__ __launch_bounds__(256) void gather_bucket(const u32* __restrict__ xb,
                                                     const u32* __restrict__ pairs,
                                                     const int* __restrict__ bstart,
                                                     u32* __restrict__ h0b, int N){
  __shared__ int lsrc[BCAP];
  __shared__ int dcnt[64];
  __shared__ int dstart[65];
  __shared__ int dcur[64];
  int b = blockIdx.x;
  int p0 = bstart[b], p1 = bstart[b+1];
  int cnt = p1 - p0;
  int tid = threadIdx.x;
  if(tid < 64) dcnt[tid] = 0;
  __syncthreads();
  bool fits = (cnt <= BCAP) && (cnt >= 0);
  if(fits){
    for(int i=tid; i<cnt; i+=256){
      u32 u = pairs[p0+i];
      atomicAdd(&dcnt[(u>>17)&63], 1);
    }
    __syncthreads();
    if(tid==0){
      int run=0;
      #pragma unroll
      for(int j=0;j<64;j++){ dstart[j]=run; dcur[j]=run; run+=dcnt[j]; }
      dstart[64]=run;
    }
    __syncthreads();
    for(int i=tid; i<cnt; i+=256){
      u32 u = pairs[p0+i];
      int pos = atomicAdd(&dcur[(u>>17)&63], 1);
      lsrc[pos] = (int)(u & 0x1FFFFu);
    }
    __syncthreads();
  }
  const uint4* xr = (const uint4*)xb;
  int slot = tid >> 4;   // 0..15
  int c = tid & 15;      // 16B chunk of 256B row
  for(int pass=0; pass<4; pass++){
    int r = pass*16 + slot;
    int node = b*64 + r;
    if(node >= N) continue;
    uint4 xv = xr[(size_t)node*16 + c];
    float acc[8] = {
      bf2f_lo(xv.x), bf2f_hi(xv.x), bf2f_lo(xv.y), bf2f_hi(xv.y),
      bf2f_lo(xv.z), bf2f_hi(xv.z), bf2f_lo(xv.w), bf2f_hi(xv.w) };
    if(fits){
      int ds = dstart[r], de = dstart[r+1];
      int j = ds;
      for(; j+8 <= de; j += 8){
        int s0=lsrc[j+0], s1=lsrc[j+1], s2=lsrc[j+2], s3=lsrc[j+3];
        int s4=lsrc[j+4], s5=lsrc[j+5], s6=lsrc[j+6], s7=lsrc[j+7];
        uint4 v0 = xr[(size_t)s0*16 + c];
        uint4 v1 = xr[(size_t)s1*16 + c];
        uint4 v2 = xr[(size_t)s2*16 + c];
        uint4 v3 = xr[(size_t)s3*16 + c];
        uint4 v4 = xr[(size_t)s4*16 + c];
        uint4 v5 = xr[(size_t)s5*16 + c];
        uint4 v6 = xr[(size_t)s6*16 + c];
        uint4 v7 = xr[(size_t)s7*16 + c];
        acc[0]+=bf2f_lo(v0.x)+bf2f_lo(v1.x)+bf2f_lo(v2.x)+bf2f_lo(v3.x)
               +bf2f_lo(v4.x)+bf2f_lo(v5.x)+bf2f_lo(v6.x)+bf2f_lo(v7.x);
        acc[1]+=bf2f_hi(v0.x)+bf2f_hi(v1.x)+bf2f_hi(v2.x)+bf2f_hi(v3.x)
               +bf2f_hi(v4.x)+bf2f_hi(v5.x)+bf2f_hi(v6.x)+bf2f_hi(v7.x);
        acc[2]+=bf2f_lo(v0.y)+bf2f_lo(v1.y)+bf2f_lo(v2.y)+bf2f_lo(v3.y)
               +bf2f_lo(v4.y)+bf2f_lo(v5.y)+bf2f_lo(v6.y)+bf2f_lo(v7.y);
        acc[3]+=bf2f_hi(v0.y)+bf2f_hi(v1.y)+bf2f_hi(v2.y)+bf2f_hi(v3.y)
               +bf2f_hi(v4.y)+bf2f_hi(v5.y)+bf2f_hi(v6.y)+bf2f_hi(v7.y);
        acc[4]+=bf2f_lo(v0.z)+bf2f_lo(v1.z)+bf2f_lo(v2.z)+bf2f_lo(v3.z)
               +bf2f_lo(v4.z)+bf2f_lo(v5.z)+bf2f_lo(v6.z)+bf2f_lo(v7.z);
        acc[5]+=bf2f_hi(v0.z)+bf2f_hi(v1.z)+bf2f_hi(v2.z)+bf2f_hi(v3.z)
               +bf2f_hi(v4.z)+bf2f_hi(v5.z)+bf2f_hi(v6.z)+bf2f_hi(v7.z);
        acc[6]+=bf2f_lo(v0.w)+bf2f_lo(v1.w)+bf2f_lo(v2.w)+bf2f_lo(v3.w)
               +bf2f_lo(v4.w)+bf2f_lo(v5.w)+bf2f_lo(v6.w)+bf2f_lo(v7.w);
        acc[7]+=bf2f_hi(v0.w)+bf2f_hi(v1.w)+bf2f_hi(v2.w)+bf2f_hi(v3.w)
               +bf2f_hi(v4.w)+bf2f_hi(v5.w)+bf2f_hi(v6.w)+bf2f_hi(v7.w);
      }
      for(; j < de; j++){
        int s = lsrc[j];
        uint4 v = xr[(size_t)s*16 + c];
        acc[0]+=bf2f_lo(v.x); acc[1]+=bf2f_hi(v.x);
        acc[2]+=bf2f_lo(v.y); acc[3]+=bf2f_hi(v.y);
        acc[4]+=bf2f_lo(v.z); acc[5]+=bf2f_hi(v.z);
        acc[6]+=bf2f_lo(v.w); acc[7]+=bf2f_hi(v.w);
      }
    } else {
      // fallback (bucket overflow — never for this distribution): scan global slice
      for(int i=0;i<cnt;i++){
        u32 u = pairs[p0+i];
        if((int)((u>>17)&63) == r){
          int s = (int)(u & 0x1FFFFu);
          uint4 v = xr[(size_t)s*16 + c];
          acc[0]+=bf2f_lo(v.x); acc[1]+=bf2f_hi(v.x);
          acc[2]+=bf2f_lo(v.y); acc[3]+=bf2f_hi(v.y);
          acc[4]+=bf2f_lo(v.z); acc[5]+=bf2f_hi(v.z);
          acc[6]+=bf2f_lo(v.w); acc[7]+=bf2f_hi(v.w);
        }
      }
    }
    uint4 o;
    o.x = pack2bf(acc[0],acc[1]); o.y = pack2bf(acc[2],acc[3]);
    o.z = pack2bf(acc[4],acc[5]); o.w = pack2bf(acc[6],acc[7]);
    ((uint4*)h0b)[(size_t)node*16 + c] = o;
  }
}

// =============== MFMA bf16 GEMM: C[M,256] = op(A[M,K]) @ Wt^T + bias ===============
// Wt is [256][K] bf16 (B^T). 512 threads = 8 waves; tile 128m x 256n, BK=64.
// LDS slabs padded to odd uint4 strides (129 / 257) to kill bank aliasing.
template<int K, bool BNA, bool RELUOUT, bool GATE, bool ABF16, bool OUTBF16>
__global__ __launch_bounds__(512) void gemm_mfma(const void* __restrict__ Ap, const ushort_t* __restrict__ Wt,
                                                 const float* __restrict__ bias,
                                                 const float* __restrict__ scale, const float* __restrict__ shift,
                                                 void* __restrict__ Cp, int M,
                                                 const float* __restrict__ Wg, const float* __restrict__ bg,
                                                 float* __restrict__ gate){
  __shared__ uint4 Al[8*129];
  __shared__ uint4 Bl[8*257];
  __shared__ float gacc[128];
  const int tid  = threadIdx.x;
  const int lane = tid & 63;
  const int wave = tid >> 6;
  const int lm   = lane & 15;
  const int q    = lane >> 4;
  const int mhalf= wave >> 2;
  const int nq   = wave & 3;
  const int m0   = blockIdx.x * 128;

  if(GATE && tid < 128) gacc[tid] = 0.f;

  f32x4 acc[4][4];
  #pragma unroll
  for(int i=0;i<4;i++)
    #pragma unroll
    for(int j=0;j<4;j++) acc[i][j] = (f32x4){0.f,0.f,0.f,0.f};

  for(int k0=0; k0<K; k0+=64){
    #pragma unroll
    for(int i=0;i<2;i++){
      int idx = tid*2 + i;
      int m = idx >> 3, c = idx & 7;
      int grow = m0 + m;
      int kk = k0 + c*8;
      uint4 v = make_uint4(0,0,0,0);
      if(ABF16){
        if(grow < M) v = *(const uint4*)((const ushort_t*)Ap + (size_t)grow*K + kk);
        if(BNA){
          float f0=bf2f_lo(v.x), f1=bf2f_hi(v.x), f2=bf2f_lo(v.y), f3=bf2f_hi(v.y);
          float f4=bf2f_lo(v.z), f5=bf2f_hi(v.z), f6=bf2f_lo(v.w), f7=bf2f_hi(v.w);
          float4 s0 = *(const float4*)(scale+kk),  s1 = *(const float4*)(scale+kk+4);
          float4 t0 = *(const float4*)(shift+kk),  t1 = *(const float4*)(shift+kk+4);
          f0=fmaxf(fmaf(s0.x,f0,t0.x),0.f); f1=fmaxf(fmaf(s0.y,f1,t0.y),0.f);
          f2=fmaxf(fmaf(s0.z,f2,t0.z),0.f); f3=fmaxf(fmaf(s0.w,f3,t0.w),0.f);
          f4=fmaxf(fmaf(s1.x,f4,t1.x),0.f); f5=fmaxf(fmaf(s1.y,f5,t1.y),0.f);
          f6=fmaxf(fmaf(s1.z,f6,t1.z),0.f); f7=fmaxf(fmaf(s1.w,f7,t1.w),0.f);
          v.x = pack2bf(f0,f1); v.y = pack2bf(f2,f3);
          v.z = pack2bf(f4,f5); v.w = pack2bf(f6,f7);
        }
      } else {
        float4 u0 = make_float4(0,0,0,0), u1 = make_float4(0,0,0,0);
        if(grow < M){
          u0 = *(const float4*)((const float*)Ap + (size_t)grow*K + kk);
          u1 = *(const float4*)((const float*)Ap + (size_t)grow*K + kk + 4);
        }
        if(BNA){
          float4 s0 = *(const float4*)(scale+kk),  s1 = *(const float4*)(scale+kk+4);
          float4 t0 = *(const float4*)(shift+kk),  t1 = *(const float4*)(shift+kk+4);
          u0.x=fmaxf(fmaf(s0.x,u0.x,t0.x),0.f); u0.y=fmaxf(fmaf(s0.y,u0.y,t0.y),0.f);
          u0.z=fmaxf(fmaf(s0.z,u0.z,t0.z),0.f); u0.w=fmaxf(fmaf(s0.w,u0.w,t0.w),0.f);
          u1.x=fmaxf(fmaf(s1.x,u1.x,t1.x),0.f); u1.y=fmaxf(fmaf(s1.y,u1.y,t1.y),0.f);
          u1.z=fmaxf(fmaf(s1.z,u1.z,t1.z),0.f); u1.w=fmaxf(fmaf(s1.w,u1.w,t1.w),0.f);
        }
        v.x = pack2bf(u0.x,u0.y); v.y = pack2bf(u0.z,u0.w);
        v.z = pack2bf(u1.x,u1.y); v.w = pack2bf(u1.z,u1.w);
      }
      Al[c*129 + m] = v;
    }
    #pragma unroll
    for(int i=0;i<4;i++){
      int idx = tid*4 + i;
      int n = idx >> 3, c = idx & 7;
      Bl[c*257 + n] = *(const uint4*)(Wt + (size_t)n*K + k0 + c*8);
    }
    __syncthreads();
    #pragma unroll
    for(int ks=0; ks<2; ks++){
      int cc = ks*4 + q;
      bf16x8 af[4], bfr[4];
      #pragma unroll
      for(int mi=0; mi<4; mi++)
        af[mi] = *((const bf16x8*)&Al[cc*129 + mhalf*64 + mi*16 + lm]);
      #pragma unroll
      for(int ni=0; ni<4; ni++)
        bfr[ni] = *((const bf16x8*)&Bl[cc*257 + nq*64 + ni*16 + lm]);
      #pragma unroll
      for(int mi=0; mi<4; mi++)
        #pragma unroll
        for(int ni=0; ni<4; ni++)
          acc[mi][ni] = __builtin_amdgcn_mfma_f32_16x16x32_bf16(af[mi], bfr[ni], acc[mi][ni], 0, 0, 0);
    }
    __syncthreads();
  }

  float bb[4], wgv[4];
  #pragma unroll
  for(int ni=0; ni<4; ni++){
    int col = nq*64 + ni*16 + lm;
    bb[ni] = bias[col];
    if(GATE) wgv[ni] = Wg[col];
  }
  #pragma unroll
  for(int mi=0; mi<4; mi++){
    int rowloc0 = mhalf*64 + mi*16 + q*4;
    float gp[4] = {0.f,0.f,0.f,0.f};
    #pragma unroll
    for(int ni=0; ni<4; ni++){
      int col = nq*64 + ni*16 + lm;
      f32x4 o = acc[mi][ni];
      #pragma unroll
      for(int r=0; r<4; r++){
        float v = o[r] + bb[ni];
        if(RELUOUT) v = fmaxf(v, 0.f);
        int row = m0 + rowloc0 + r;
        if(row < M){
          if(OUTBF16) ((ushort_t*)Cp)[(size_t)row*256 + col] = f2bf1(v);
          else        ((float*)Cp)[(size_t)row*256 + col] = v;
        }
        if(GATE) gp[r] = fmaf(v, wgv[ni], gp[r]);
      }
    }
    if(GATE){
      #pragma unroll
      for(int r=0; r<4; r++){
        if(m0 + rowloc0 + r < M) atomicAdd(&gacc[rowloc0 + r], gp[r]);
      }
    }
  }
  if(GATE){
    __syncthreads();
    if(tid < 128){
      int row = m0 + tid;
      if(row < M) gate[row] = gacc[tid] + bg[0];
    }
  }
}

// =============== BN column stats over bf16 h (parallel partials) ===============
__global__ __launch_bounds__(256) void col_stats_bf(const u32* __restrict__ h, float* __restrict__ psum,
                                                    float* __restrict__ pq, int M, int rpb, int nblk){
  int b = blockIdx.x;
  int g = threadIdx.x >> 6;
  int lane = threadIdx.x & 63;
  int c0 = lane*4;
  int r0 = b*rpb;
  int r1 = min(r0+rpb, M);
  float4 s4 = make_float4(0.f,0.f,0.f,0.f);
  float4 q4 = make_float4(0.f,0.f,0.f,0.f);
  for(int r=r0+g; r<r1; r+=4){
    uint2 u = *(const uint2*)(h + (size_t)r*128 + lane*2);
    float v0=bf2f_lo(u.x), v1=bf2f_hi(u.x), v2=bf2f_lo(u.y), v3=bf2f_hi(u.y);
    s4.x+=v0; s4.y+=v1; s4.z+=v2; s4.w+=v3;
    q4.x=fmaf(v0,v0,q4.x); q4.y=fmaf(v1,v1,q4.y);
    q4.z=fmaf(v2,v2,q4.z); q4.w=fmaf(v3,v3,q4.w);
  }
  __shared__ float ls[1024];
  __shared__ float lq[1024];
  *(float4*)&ls[g*256+c0] = s4;
  *(float4*)&lq[g*256+c0] = q4;
  __syncthreads();
  if(threadIdx.x < 64){
    #pragma unroll
    for(int j=0;j<4;j++){
      int c = c0+j;
      float s = ls[c]+ls[256+c]+ls[512+c]+ls[768+c];
      float q = lq[c]+lq[256+c]+lq[512+c]+lq[768+c];
      psum[(size_t)c*nblk + b] = s;
      pq[(size_t)c*nblk + b]   = q;
    }
  }
}

// =============== fp32 col stats (for pooled) ===============
__global__ __launch_bounds__(256) void col_stats2(const float* __restrict__ h, float* __restrict__ psum,
                                                  float* __restrict__ pq, int M, int rpb, int nblk){
  int b = blockIdx.x;
  int g = threadIdx.x >> 6;
  int lane = threadIdx.x & 63;
  int c0 = lane*4;
  int r0 = b*rpb;
  int r1 = min(r0+rpb, M);
  float4 s4 = make_float4(0.f,0.f,0.f,0.f);
  float4 q4 = make_float4(0.f,0.f,0.f,0.f);
  for(int r=r0+g; r<r1; r+=4){
    float4 v = *(const float4*)(h + (size_t)r*256 + c0);
    s4.x+=v.x; s4.y+=v.y; s4.z+=v.z; s4.w+=v.w;
    q4.x=fmaf(v.x,v.x,q4.x); q4.y=fmaf(v.y,v.y,q4.y);
    q4.z=fmaf(v.z,v.z,q4.z); q4.w=fmaf(v.w,v.w,q4.w);
  }
  __shared__ float ls[1024];
  __shared__ float lq[1024];
  *(float4*)&ls[g*256+c0] = s4;
  *(float4*)&lq[g*256+c0] = q4;
  __syncthreads();
  if(threadIdx.x < 64){
    #pragma unroll
    for(int j=0;j<4;j++){
      int c = c0+j;
      float s = ls[c]+ls[256+c]+ls[512+c]+ls[768+c];
      float q = lq[c]+lq[256+c]+lq[512+c]+lq[768+c];
      psum[(size_t)c*nblk + b] = s;
      pq[(size_t)c*nblk + b]   = q;
    }
  }
}

__global__ __launch_bounds__(512) void stats_fin(const float* __restrict__ psum, const float* __restrict__ pq,
                                                 const float* __restrict__ gamma, const float* __restrict__ beta,
                                                 float* __restrict__ scale, float* __restrict__ shift,
                                                 int nblk, float invM){
  __shared__ float red[512];
  int t = threadIdx.x;
  const float* src = (t<256) ? (psum + (size_t)t*nblk) : (pq + (size_t)(t-256)*nblk);
  float s = 0.f;
  for(int i=0;i<nblk;i+=4){
    float4 v = *(const float4*)(src+i);
    s += v.x+v.y+v.z+v.w;
  }
  red[t]=s; __syncthreads();
  if(t<256){
    float mu  = red[t]*invM;
    float var = fmaxf(red[256+t]*invM - mu*mu, 0.f);
    float sc  = gamma[t] * rsqrtf(var + 1e-5f);
    scale[t]=sc; shift[t]=fmaf(-mu, sc, beta[t]);
  }
}

// =============== attentional pool: one block(512) per graph; alpha cached in LDS ===============
__global__ __launch_bounds__(512) void pool_k(const ushort_t* __restrict__ h2b, const float* __restrict__ gate,
                                              const int* __restrict__ batch, float* __restrict__ pooled, int N){
  int g = blockIdx.x;
  __shared__ int sb[2];
  __shared__ float red[8];
  __shared__ float s_m, s_inv;
  __shared__ float la[256];
  __shared__ float facc[512];
  int t = threadIdx.x;
  if(t < 2){
    int target = g + t;
    int lo=0, hi=N;
    while(lo<hi){ int mid=(lo+hi)>>1; if(batch[mid] < target) lo=mid+1; else hi=mid; }
    sb[t] = lo;
  }
  __syncthreads();
  int beg = sb[0], end = sb[1];
  float mx = -1e30f;
  for(int i=beg+t; i<end; i+=512) mx = fmaxf(mx, gate[i]);
  #pragma unroll
  for(int d=32; d>0; d>>=1) mx = fmaxf(mx, __shfl_down(mx, d, 64));
  if((t&63)==0) red[t>>6] = mx;
  __syncthreads();
  if(t==0){
    float m = red[0];
    #pragma unroll
    for(int w=1; w<8; w++) m = fmaxf(m, red[w]);
    s_m = m;
  }
  __syncthreads();
  float m = s_m;
  float s = 0.f;
  for(int i=beg+t; i<end; i+=512) s += expf(gate[i]-m);
  #pragma unroll
  for(int d=32; d>0; d>>=1) s += __shfl_down(s, d, 64);
  if((t&63)==0) red[t>>6] = s;
  __syncthreads();
  if(t==0){
    float tot = 0.f;
    #pragma unroll
    for(int w=0; w<8; w++) tot += red[w];
    s_inv = (tot > 0.f) ? 1.f/tot : 0.f;
  }
  __syncthreads();
  float inv = s_inv;
  int col = t & 255;
  int half = t >> 8;
  float acc = 0.f;
  for(int ci=beg; ci<end; ci+=256){
    int chunk = min(256, end-ci);
    if(t < 256) la[t] = (t < chunk) ? expf(gate[ci+t]-m)*inv : 0.f;
    __syncthreads();
    for(int j=half; j<chunk; j+=2){
      acc = fmaf(la[j], bf2f_s(h2b[(size_t)(ci+j)*256 + col]), acc);
    }
    __syncthreads();
  }
  facc[t] = acc;
  __syncthreads();
  if(t < 256) pooled[g*256 + t] = facc[t] + facc[t+256];
}

// =============== head linear + log_softmax: one wave per graph ===============
__global__ __launch_bounds__(256) void head_k(const float* __restrict__ pooled,
                                              const float* __restrict__ sc2, const float* __restrict__ sh2,
                                              const float* __restrict__ Wh, const float* __restrict__ bh,
                                              float* __restrict__ out, int G){
  int w = (blockIdx.x*256 + threadIdx.x) >> 6;
  int l = threadIdx.x & 63;
  if(w >= G) return;
  float4 v  = *(const float4*)(pooled + (size_t)w*256 + l*4);
  float4 sc = *(const float4*)(sc2 + l*4);
  float4 sh = *(const float4*)(sh2 + l*4);
  float vv[4] = { fmaf(sc.x,v.x,sh.x), fmaf(sc.y,v.y,sh.y), fmaf(sc.z,v.z,sh.z), fmaf(sc.w,v.w,sh.w) };
  float4 w0 = *(const float4*)(Wh + (size_t)l*8);
  float4 w1 = *(const float4*)(Wh + (size_t)l*8 + 4);
  float a0 = vv[0]*w0.x + vv[1]*w0.z + vv[2]*w1.x + vv[3]*w1.z;
  float a1 = vv[0]*w0.y + vv[1]*w0.w + vv[2]*w1.y + vv[3]*w1.w;
  #pragma unroll
  for(int d=32; d>0; d>>=1){ a0 += __shfl_down(a0,d,64); a1 += __shfl_down(a1,d,64); }
  if(l==0){
    float z0 = a0 + bh[0];
    float z1 = a1 + bh[1];
    float mz = fmaxf(z0,z1);
    float lse = mz + logf(expf(z0-mz) + expf(z1-mz));
    out[w*2]   = z0 - lse;
    out[w*2+1] = z1 - lse;
  }
}

extern "C" void kernel_launch(void* const* d_in, const int* in_sizes, int n_in,
                              void* d_out, int out_size, void* d_ws, size_t ws_size,
                              hipStream_t stream){
  const float* x   = (const float*)d_in[0];
  const int*   ei  = (const int*)d_in[1];
  const int*   bat = (const int*)d_in[2];
  const float* W1  = (const float*)d_in[3];
  const float* b1  = (const float*)d_in[4];
  const float* g1  = (const float*)d_in[5];
  const float* be1 = (const float*)d_in[6];
  const float* W2  = (const float*)d_in[7];
  const float* b2  = (const float*)d_in[8];
  const float* Wg  = (const float*)d_in[9];
  const float* bg  = (const float*)d_in[10];
  const float* g2  = (const float*)d_in[11];
  const float* be2 = (const float*)d_in[12];
  const float* Wh  = (const float*)d_in[13];
  const float* bh  = (const float*)d_in[14];

  const int N = in_sizes[0] / 128;   // 50000
  const int E = in_sizes[1] / 2;     // 1600000
  const int G = out_size / 2;        // 512
  const int NB = (N + 63) >> 6;      // 782
  const int NBLK1 = 512;
  const int NBLK2 = 64;

  // ---- workspace layout ----
  char* ws = (char*)d_ws;
  u32*   h0b    = (u32*)ws;                          // 12,800,000 B
  u32*   xb     = (u32*)(ws + 12800000);             // 12,800,000 B
  u32*   pairs  = (u32*)(ws + 25600000);             //  6,400,000 B
  int*   bcount = (int*)(ws + 32000000);             //      4,096 B
  int*   bstart = (int*)(ws + 32004352);             //      4,100 B
  int*   bcursor= (int*)(ws + 32008704);             //     65,536 B
  ushort_t* h2b = (ushort_t*)ws;                     // 25,600,000 B (phase2, overlays phase1)
  u32*   h1b    = (u32*)(ws + 51200000);             // 25,600,000 B (bf16 pairs)
  char*  p2 = ws + 102400000;
  float* psum1 = (float*)p2;          p2 += 256*NBLK1*4;
  float* pq1   = (float*)p2;          p2 += 256*NBLK1*4;
  float* psum2 = (float*)p2;          p2 += 256*NBLK2*4;
  float* pq2   = (float*)p2;          p2 += 256*NBLK2*4;
  float* sc1   = (float*)p2;          p2 += 1024;
  float* sh1   = (float*)p2;          p2 += 1024;
  float* gate  = (float*)p2;          p2 += (size_t)N*4 + 4096;
  float* pooled= (float*)p2;          p2 += (size_t)G*256*4;
  float* sc2   = (float*)p2;          p2 += 1024;
  float* sh2   = (float*)p2;          p2 += 1024;
  ushort_t* W1t = (ushort_t*)p2;      p2 += 256*128*2;
  ushort_t* W2t = (ushort_t*)p2;      p2 += 256*256*2;

  const int* src = ei;
  const int* dst = ei + E;

  hipMemsetAsync(bcount, 0, (size_t)NB*4, stream);

  transpose_w<<<256, 256, 0, stream>>>(W1, W1t, 128);
  transpose_w<<<256, 256, 0, stream>>>(W2, W2t, 256);
  long n4 = (long)N*128/4;
  to_bf16    <<<(int)((n4+255)/256), 256, 0, stream>>>(x, xb, n4);

  int nchunk = (E + 8191)/8192;
  hist_k     <<<nchunk, 256, 0, stream>>>(dst, bcount, E, N, NB);
  bucket_scan<<<1, 256, 0, stream>>>(bcount, bstart, bcursor, NB);
  binscatter2<<<nchunk, 256, 0, stream>>>(src, dst, bstart, bcursor, pairs, E, N, NB);
  gather_bucket<<<NB, 256, 0, stream>>>(xb, pairs, bstart, h0b, N);

  int gblocks = (N + 127)/128;
  gemm_mfma<128,false,false,false,true,true><<<gblocks, 512, 0, stream>>>(
      h0b, W1t, b1, nullptr, nullptr, h1b, N, nullptr, nullptr, nullptr);
  int rpb1 = (N + NBLK1 - 1)/NBLK1;
  col_stats_bf <<<NBLK1, 256, 0, stream>>>(h1b, psum1, pq1, N, rpb1, NBLK1);
  stats_fin  <<<1, 512, 0, stream>>>(psum1, pq1, g1, be1, sc1, sh1, NBLK1, 1.0f/(float)N);
  gemm_mfma<256,true,true,true,true,true><<<gblocks, 512, 0, stream>>>(
      h1b, W2t, b2, sc1, sh1, h2b, N, Wg, bg, gate);

  pool_k <<<G, 512, 0, stream>>>(h2b, gate, bat, pooled, N);
  int rpb2 = (G + NBLK2 - 1)/NBLK2;
  col_stats2 <<<NBLK2, 256, 0, stream>>>(pooled, psum2, pq2, G, rpb2, NBLK2);
  stats_fin  <<<1, 512, 0, stream>>>(psum2, pq2, g2, be2, sc2, sh2, NBLK2, 1.0f/(float)G);
  head_k <<<(G+3)/4, 256, 0, stream>>>(pooled, sc2, sh2, Wh, bh, (float*)d_out, G);
}